// Round 5
// baseline (1424.991 us; speedup 1.0000x reference)
//
#include <hip/hip_runtime.h>
#include <math.h>

// Model constants
#define BL   2048   // B*L = 4*512
#define LSEQ 512
#define NB   4
#define DMOD 256
#define DIN  512
#define NST  16
#define DFF  682
#define NCH  (NB * DIN)   // 2048 channels

typedef __attribute__((ext_vector_type(4))) float f32x4;
typedef __attribute__((ext_vector_type(8))) _Float16 f16x8;

__device__ __forceinline__ float sigmoidf_(float x) { return 1.f / (1.f + __expf(-x)); }
__device__ __forceinline__ float siluf_(float x) { return x / (1.f + __expf(-x)); }

// ---------------- DAIN stats (single block) ----------------
__global__ __launch_bounds__(1024) void dain_k(
    const float* __restrict__ src, const float* __restrict__ Wm,
    const float* __restrict__ Ws, const float* __restrict__ Wg,
    const float* __restrict__ bg, float* __restrict__ stats) {
  __shared__ float part[1024];
  __shared__ float avg_s[128], sub_s[128], std_s[128], mn_s[128], inv_s[128];
  int tid = threadIdx.x;
  int p = tid >> 3, j = tid & 7;
  int b = p >> 5, f = p & 31;
  float s = 0.f;
  for (int l = j * 64; l < j * 64 + 64; ++l) s += src[((size_t)b * LSEQ + l) * 32 + f];
  part[tid] = s;
  __syncthreads();
  if (tid < 128) { float a = 0; for (int k = 0; k < 8; k++) a += part[tid * 8 + k]; avg_s[tid] = a * (1.f / 512.f); }
  __syncthreads();
  if (tid < 128) {
    int bb = tid >> 5, ff = tid & 31;
    float a = 0; for (int g = 0; g < 32; g++) a += avg_s[bb * 32 + g] * Wm[ff * 32 + g];
    sub_s[tid] = a;
  }
  __syncthreads();
  float sub = sub_s[p];
  s = 0.f;
  for (int l = j * 64; l < j * 64 + 64; ++l) {
    float v = src[((size_t)b * LSEQ + l) * 32 + f] - sub; s += v * v;
  }
  part[tid] = s;
  __syncthreads();
  if (tid < 128) { float a = 0; for (int k = 0; k < 8; k++) a += part[tid * 8 + k]; std_s[tid] = sqrtf(a * (1.f / 512.f)); }
  __syncthreads();
  if (tid < 128) {
    int bb = tid >> 5, ff = tid & 31;
    float a = 0; for (int g = 0; g < 32; g++) a += std_s[bb * 32 + g] * Ws[ff * 32 + g];
    if (a <= 1e-8f) a = 1.f;
    inv_s[tid] = 1.f / a;
    mn_s[tid] = (avg_s[tid] - sub_s[tid]) / a;
  }
  __syncthreads();
  if (tid < 128) {
    int bb = tid >> 5, ff = tid & 31;
    float a = bg[ff]; for (int g = 0; g < 32; g++) a += mn_s[bb * 32 + g] * Wg[ff * 32 + g];
    float gate = sigmoidf_(a);
    float scl = gate * inv_s[tid];
    stats[tid] = scl;
    stats[128 + tid] = sub_s[tid] * scl;
  }
}

// ---------------- embed: market + tproj -> h_hf (f16) ----------------
__global__ __launch_bounds__(256) void embed_k(
    const float* __restrict__ src, const float* __restrict__ tau,
    const float* __restrict__ stats, const float* __restrict__ membW,
    const float* __restrict__ membB, const float* __restrict__ tw0,
    const float* __restrict__ tb0, const float* __restrict__ tw,
    const float* __restrict__ tb, const float* __restrict__ tprojW,
    const float* __restrict__ tprojB, _Float16* __restrict__ h_hf) {
  int token = blockIdx.x;
  int b = token >> 9;
  int t = threadIdx.x;
  __shared__ float xs[32], te[32];
  if (t < 32) {
    float scl = stats[b * 32 + t], shf = stats[128 + b * 32 + t];
    xs[t] = src[(size_t)token * 32 + t] * scl - shf;
  } else if (t < 64) {
    int j = t - 32;
    const float* tr = tau + (size_t)token * 8;
    float a;
    if (j < 31) { a = tb[j]; for (int k = 0; k < 8; k++) a += tr[k] * tw[k * 31 + j]; a = sinf(a); }
    else        { a = tb0[0]; for (int k = 0; k < 8; k++) a += tr[k] * tw0[k]; }
    te[j] = a;
  }
  __syncthreads();
  float acc;
  if (t < 128) {
    acc = membB[t];
    for (int f = 0; f < 32; f++) acc += xs[f] * membW[f * 128 + t];
  } else {
    int d = t - 128;
    acc = tprojB[d];
    for (int j = 0; j < 32; j++) acc += te[j] * tprojW[j * 128 + d];
  }
  h_hf[(size_t)token * DMOD + t] = (_Float16)acc;
}

// ---------------- weight transpose-convert: fp32 [K][N] -> f16 [Nout][Kout] (padded zeros)
__global__ __launch_bounds__(256) void convT_k(const float* __restrict__ W, _Float16* __restrict__ WT,
                                               int K, int N, int Kout, int Nout) {
  int l = blockIdx.y;
  const float* Wl = W + (size_t)l * K * N;
  _Float16* WTl = WT + (size_t)l * Nout * Kout;
  int i = blockIdx.x * 256 + threadIdx.x;
  if (i >= Nout * Kout) return;
  int n = i / Kout, k = i - n * Kout;
  float v = (k < K && n < N) ? Wl[(size_t)k * N + n] : 0.f;
  WTl[i] = (_Float16)v;
}

// ---------------- plain f16 MFMA GEMM 64x64 tile (A stride == K) ----------------
__global__ __launch_bounds__(256) void gemm_hf_k(
    const _Float16* __restrict__ A, const _Float16* __restrict__ WT,
    const float* __restrict__ bias, float* __restrict__ C,
    int M, int Nstore, int K, int ldc, int flags) {
  __shared__ _Float16 As[64][40];
  __shared__ _Float16 Bs[64][40];
  int bm = blockIdx.y * 64, bn = blockIdx.x * 64;
  int t = threadIdx.x;
  int w = t >> 6, l = t & 63;
  int wm = w >> 1, wn = w & 1;
  int srow = t >> 2, sk = (t & 3) * 8;
  f32x4 acc[2][2] = {};
  int lr = l & 15, lk = (l >> 4) * 8;
  for (int k0 = 0; k0 < K; k0 += 32) {
    *(uint4*)&As[srow][sk] = *(const uint4*)&A[(size_t)(bm + srow) * K + k0 + sk];
    *(uint4*)&Bs[srow][sk] = *(const uint4*)&WT[(size_t)(bn + srow) * K + k0 + sk];
    __syncthreads();
    f16x8 a0 = *(const f16x8*)&As[wm * 32 + lr][lk];
    f16x8 a1 = *(const f16x8*)&As[wm * 32 + 16 + lr][lk];
    f16x8 b0 = *(const f16x8*)&Bs[wn * 32 + lr][lk];
    f16x8 b1 = *(const f16x8*)&Bs[wn * 32 + 16 + lr][lk];
    acc[0][0] = __builtin_amdgcn_mfma_f32_16x16x32_f16(a0, b0, acc[0][0], 0, 0, 0);
    acc[0][1] = __builtin_amdgcn_mfma_f32_16x16x32_f16(a0, b1, acc[0][1], 0, 0, 0);
    acc[1][0] = __builtin_amdgcn_mfma_f32_16x16x32_f16(a1, b0, acc[1][0], 0, 0, 0);
    acc[1][1] = __builtin_amdgcn_mfma_f32_16x16x32_f16(a1, b1, acc[1][1], 0, 0, 0);
    __syncthreads();
  }
  int lq = l >> 4;
#pragma unroll
  for (int i = 0; i < 2; i++) {
#pragma unroll
    for (int j = 0; j < 2; j++) {
      int col = bn + wn * 32 + j * 16 + lr;
      if (col >= Nstore) continue;
      float bv = bias ? bias[col] : 0.f;
#pragma unroll
      for (int r = 0; r < 4; r++) {
        int row = bm + wm * 32 + i * 16 + lq * 4 + r;
        float v = acc[i][j][r] + bv;
        size_t idx = (size_t)row * ldc + col;
        if (flags & 1) v += C[idx];
        C[idx] = v;
      }
    }
  }
}

// ---------------- fused GEMM (N=256) + bias + residual + LayerNorm -> h fp32, hn f16 ----------------
// AOP 0: A = Af16 [M][lda] f16.  AOP 1: A[r][k] = silu(B[r][k])*B[r][lda/2+k].
// AOP 2: A[r][k] = B[r][k]*gelu(B[r][lda/2+k]) with k<lda/2 guard (B fp32 stride lda).
// Tile 32 rows x 256 cols, grid 64 blocks, 4 waves (wave w = cols w*64..).
template<int AOP>
__global__ __launch_bounds__(256) void gemm_ln_k(
    const _Float16* __restrict__ Af16, const float* __restrict__ Abig, int lda,
    const _Float16* __restrict__ WT, const float* __restrict__ bias,
    float* __restrict__ h, const float* __restrict__ lnw, const float* __restrict__ lnb,
    _Float16* __restrict__ hn, int K, int res) {
  __shared__ _Float16 As[32][40];
  __shared__ _Float16 Bs[256][40];
  __shared__ float rsum[32][4], rsq[32][4];
  int bm = blockIdx.x * 32;
  int t = threadIdx.x;
  int w = t >> 6, l = t & 63;
  int lr = l & 15, lq = l >> 4, lk = lq * 8;
  int half = lda >> 1;
  f32x4 acc[2][4] = {};
  int brow = t >> 2, kb = (t & 3) * 8;
  for (int k0 = 0; k0 < K; k0 += 32) {
    if (t < 128) {
      int ar = t >> 2;
      int row = bm + ar;
      if (AOP == 0) {
        *(uint4*)&As[ar][kb] = *(const uint4*)&Af16[(size_t)row * lda + k0 + kb];
      } else if (AOP == 1) {
        const float* rp = Abig + (size_t)row * lda;
        float4 g1a = *(const float4*)&rp[k0 + kb];
        float4 g1b = *(const float4*)&rp[k0 + kb + 4];
        float4 g2a = *(const float4*)&rp[half + k0 + kb];
        float4 g2b = *(const float4*)&rp[half + k0 + kb + 4];
        f16x8 av;
        av[0] = (_Float16)(siluf_(g1a.x) * g2a.x); av[1] = (_Float16)(siluf_(g1a.y) * g2a.y);
        av[2] = (_Float16)(siluf_(g1a.z) * g2a.z); av[3] = (_Float16)(siluf_(g1a.w) * g2a.w);
        av[4] = (_Float16)(siluf_(g1b.x) * g2b.x); av[5] = (_Float16)(siluf_(g1b.y) * g2b.y);
        av[6] = (_Float16)(siluf_(g1b.z) * g2b.z); av[7] = (_Float16)(siluf_(g1b.w) * g2b.w);
        *(f16x8*)&As[ar][kb] = av;
      } else {
        const float* rp = Abig + (size_t)row * lda;
        f16x8 av;
#pragma unroll
        for (int e = 0; e < 8; e++) {
          int k = k0 + kb + e;
          float r = 0.f;
          if (k < half) {
            float a = rp[k], g = rp[half + k];
            r = a * 0.5f * g * (1.f + erff(g * 0.70710678118654752f));
          }
          av[e] = (_Float16)r;
        }
        *(f16x8*)&As[ar][kb] = av;
      }
    }
#pragma unroll
    for (int r2 = 0; r2 < 4; r2++)
      *(uint4*)&Bs[brow + 64 * r2][kb] = *(const uint4*)&WT[(size_t)(brow + 64 * r2) * K + k0 + kb];
    __syncthreads();
    f16x8 a0 = *(const f16x8*)&As[lr][lk];
    f16x8 a1 = *(const f16x8*)&As[16 + lr][lk];
#pragma unroll
    for (int j = 0; j < 4; j++) {
      f16x8 bj = *(const f16x8*)&Bs[w * 64 + j * 16 + lr][lk];
      acc[0][j] = __builtin_amdgcn_mfma_f32_16x16x32_f16(a0, bj, acc[0][j], 0, 0, 0);
      acc[1][j] = __builtin_amdgcn_mfma_f32_16x16x32_f16(a1, bj, acc[1][j], 0, 0, 0);
    }
    __syncthreads();
  }
  // epilogue: bias + residual + store h + (optional) LN -> hn
  float vals[2][4][4];
#pragma unroll
  for (int i = 0; i < 2; i++)
#pragma unroll
    for (int j = 0; j < 4; j++) {
      int col = w * 64 + j * 16 + lr;
      float bv = bias ? bias[col] : 0.f;
#pragma unroll
      for (int r = 0; r < 4; r++) {
        int row = bm + i * 16 + lq * 4 + r;
        float v = acc[i][j][r] + bv;
        size_t idx = (size_t)row * 256 + col;
        if (res) v += h[idx];
        h[idx] = v;
        vals[i][j][r] = v;
      }
    }
  if (lnw) {
#pragma unroll
    for (int i = 0; i < 2; i++)
#pragma unroll
      for (int r = 0; r < 4; r++) {
        float s = 0.f, ss = 0.f;
#pragma unroll
        for (int j = 0; j < 4; j++) { float v = vals[i][j][r]; s += v; ss += v * v; }
#pragma unroll
        for (int o = 1; o < 16; o <<= 1) { s += __shfl_xor(s, o, 64); ss += __shfl_xor(ss, o, 64); }
        if (lr == 0) { rsum[i * 16 + lq * 4 + r][w] = s; rsq[i * 16 + lq * 4 + r][w] = ss; }
      }
    __syncthreads();
#pragma unroll
    for (int i = 0; i < 2; i++)
#pragma unroll
      for (int r = 0; r < 4; r++) {
        int row16 = i * 16 + lq * 4 + r;
        float S = rsum[row16][0] + rsum[row16][1] + rsum[row16][2] + rsum[row16][3];
        float SS = rsq[row16][0] + rsq[row16][1] + rsq[row16][2] + rsq[row16][3];
        float mu = S * (1.f / 256.f);
        float var = SS * (1.f / 256.f) - mu * mu;
        float rs = rsqrtf(var + 1e-5f);
        int row = bm + row16;
#pragma unroll
        for (int j = 0; j < 4; j++) {
          int col = w * 64 + j * 16 + lr;
          hn[(size_t)row * 256 + col] = (_Float16)((vals[i][j][r] - mu) * rs * lnw[col] + lnb[col]);
        }
      }
  }
}

// ---------------- fused conv4+silu -> xproj -> dtproj+softplus (one block per token) ----------------
__global__ __launch_bounds__(128) void convxdt_k(
    const float* __restrict__ big, const float* __restrict__ cw, const float* __restrict__ cb,
    const float* __restrict__ xW, const float* __restrict__ dW, const float* __restrict__ dbias,
    float* __restrict__ ucv, float* __restrict__ xd, float* __restrict__ dt) {
  __shared__ float us[512];
  __shared__ float xs[48];
  int token = blockIdx.x;
  int b = token >> 9, l = token & 511;
  int t = threadIdx.x;
  for (int c = t; c < 512; c += 128) {
    float acc = cb[c];
#pragma unroll
    for (int k = 0; k < 4; k++) {
      int l2 = l - 3 + k;
      if (l2 >= 0) acc += big[((size_t)(b * LSEQ + l2)) * 1024 + c] * cw[c * 4 + k];
    }
    float u = siluf_(acc);
    us[c] = u;
    ucv[(size_t)token * 512 + c] = u;
  }
  __syncthreads();
  float part = 0.f;
  int j = t >> 1, p = t & 1;
  if (t < 96) {
    for (int c = p * 256; c < p * 256 + 256; c++) part += us[c] * xW[c * 48 + j];
  }
  part += __shfl_xor(part, 1, 64);
  if (t < 96 && p == 0) {
    xs[j] = part;
    xd[(size_t)token * 48 + j] = part;
  }
  __syncthreads();
  for (int c = t; c < 512; c += 128) {
    float acc = dbias[c];
#pragma unroll
    for (int r = 0; r < 16; r++) acc += xs[r] * dW[r * 512 + c];
    dt[(size_t)token * 512 + c] = (acc > 20.f) ? acc : log1pf(__expf(acc));
  }
}

// ---------------- fused chunked scan (one block per channel) ----------------
__global__ __launch_bounds__(256) void scan_k(
    const float* __restrict__ dt, const float* __restrict__ ucv, const float* __restrict__ xd,
    const float* __restrict__ zbuf, const float* __restrict__ A_log, const float* __restrict__ D_p,
    _Float16* __restrict__ gout) {
  __shared__ float Ps[16][17], Hs[16][17], Hi[16][17];
  int ch = blockIdx.x;
  int b = ch >> 9, d = ch & 511;
  int t = threadIdx.x;
  int c = t >> 4, n = t & 15;
  float An = -__expf(A_log[d * 16 + n]);
  float P = 1.f, h = 0.f;
  int t0 = b * LSEQ + c * 32;
  for (int tt = 0; tt < 32; tt++) {
    int token = t0 + tt;
    float dtv = dt[(size_t)token * 512 + d];
    float uv = ucv[(size_t)token * 512 + d];
    float Bn = xd[(size_t)token * 48 + 16 + n];
    float dA = __expf(dtv * An);
    P *= dA;
    h = dA * h + dtv * uv * Bn;
  }
  Ps[c][n] = P; Hs[c][n] = h;
  __syncthreads();
  if (t < 16) {
    float hr = 0.f;
    for (int cc = 0; cc < 16; cc++) { Hi[cc][t] = hr; hr = Ps[cc][t] * hr + Hs[cc][t]; }
  }
  __syncthreads();
  h = Hi[c][n];
  float Dd = D_p[d];
  for (int tt = 0; tt < 32; tt++) {
    int token = t0 + tt;
    float dtv = dt[(size_t)token * 512 + d];
    float uv = ucv[(size_t)token * 512 + d];
    float Bn = xd[(size_t)token * 48 + 16 + n];
    float Cn = xd[(size_t)token * 48 + 32 + n];
    float dA = __expf(dtv * An);
    h = dA * h + dtv * uv * Bn;
    float y = h * Cn;
    y += __shfl_xor(y, 1, 64);
    y += __shfl_xor(y, 2, 64);
    y += __shfl_xor(y, 4, 64);
    y += __shfl_xor(y, 8, 64);
    if (n == 0) {
      float z = zbuf[(size_t)token * 1024 + 512 + d];
      gout[(size_t)token * 512 + d] = (_Float16)((y + uv * Dd) * siluf_(z));
    }
  }
}

// ---------------- dueling head: grid 8 = (batch, head), 1024 threads, K-split ----------------
__device__ __forceinline__ float bredK(float v, float* red) {
  int lane = threadIdx.x & 63, wid = threadIdx.x >> 6;
#pragma unroll
  for (int o = 32; o; o >>= 1) v += __shfl_xor(v, o, 64);
  __syncthreads();
  if (lane == 0) red[wid] = v;
  __syncthreads();
  float s = 0.f;
#pragma unroll
  for (int k = 0; k < 16; k++) s += red[k];
  return s;
}

__global__ __launch_bounds__(1024) void head_k(
    const float* __restrict__ h, const float* __restrict__ nfw, const float* __restrict__ nfb,
    const float* vW1, const float* vb1, const float* vl1w, const float* vl1b,
    const float* vW2, const float* vb2, const float* vl2w, const float* vl2b,
    const float* vW3, const float* vb3,
    const float* aW1, const float* ab1, const float* al1w, const float* al1b,
    const float* aW2, const float* ab2, const float* al2w, const float* al2b,
    const float* aW3, const float* ab3, float* __restrict__ houts) {
  __shared__ float f[256], t1[512], t2[256], red[16];
  int b = blockIdx.x >> 1, p = blockIdx.x & 1;
  int t = threadIdx.x;
  const float* W1 = p ? aW1 : vW1; const float* b1 = p ? ab1 : vb1;
  const float* l1w = p ? al1w : vl1w; const float* l1b = p ? al1b : vl1b;
  const float* W2 = p ? aW2 : vW2; const float* b2 = p ? ab2 : vb2;
  const float* l2w = p ? al2w : vl2w; const float* l2b = p ? al2b : vl2b;
  const float* W3 = p ? aW3 : vW3; const float* b3 = p ? ab3 : vb3;
  int nout = p ? 5 : 1;
  // final LN of last-token row
  const float* hr = h + ((size_t)b * LSEQ + (LSEQ - 1)) * DMOD;
  float v = (t < 256) ? hr[t] : 0.f;
  float mu = bredK(v, red) * (1.f / 256.f);
  float dv = (t < 256) ? (v - mu) : 0.f;
  float var = bredK(dv * dv, red) * (1.f / 256.f);
  if (t < 256) f[t] = dv * rsqrtf(var + 1e-5f) * nfw[t] + nfb[t];
  __syncthreads();
  // L1: 512 outputs, K=256, 2-way split
  int j1 = t >> 1, p2 = t & 1;
  float a1 = 0.f;
  for (int k = p2 * 128; k < p2 * 128 + 128; k++) a1 += f[k] * W1[k * 512 + j1];
  a1 += __shfl_xor(a1, 1, 64);
  a1 += b1[j1];
  mu = bredK(a1, red) * (1.f / 1024.f);
  dv = a1 - mu;
  var = bredK(dv * dv, red) * (1.f / 1024.f);
  t1[j1] = fmaxf(dv * rsqrtf(var + 1e-5f) * l1w[j1] + l1b[j1], 0.f);
  __syncthreads();
  // L2: 256 outputs, K=512, 4-way split
  int j2 = t >> 2, p4 = t & 3;
  float a2 = 0.f;
  for (int k = p4 * 128; k < p4 * 128 + 128; k++) a2 += t1[k] * W2[k * 256 + j2];
  a2 += __shfl_xor(a2, 1, 64);
  a2 += __shfl_xor(a2, 2, 64);
  a2 += b2[j2];
  mu = bredK(a2, red) * (1.f / 1024.f);
  dv = a2 - mu;
  var = bredK(dv * dv, red) * (1.f / 1024.f);
  t2[j2] = fmaxf(dv * rsqrtf(var + 1e-5f) * l2w[j2] + l2b[j2], 0.f);
  __syncthreads();
  // L3: nout outputs, one wave each
  int wid = t >> 6, lane = t & 63;
  if (wid < nout) {
    float a3 = 0.f;
    for (int k = lane; k < 256; k += 64) a3 += t2[k] * W3[k * nout + wid];
#pragma unroll
    for (int o = 32; o; o >>= 1) a3 += __shfl_xor(a3, o, 64);
    if (lane == 0) houts[(b * 2 + p) * 8 + wid] = a3 + b3[wid];
  }
}

__global__ __launch_bounds__(64) void comb_k(const float* __restrict__ houts, float* __restrict__ q) {
  int t = threadIdx.x;
  if (t < 20) {
    int b = t / 5, a = t - b * 5;
    float val = houts[b * 16];
    float am = 0.f;
#pragma unroll
    for (int k = 0; k < 5; k++) am += houts[b * 16 + 8 + k];
    am *= 0.2f;
    q[b * 5 + a] = val + houts[b * 16 + 8 + a] - am;
  }
}

extern "C" void kernel_launch(void* const* d_in, const int* in_sizes, int n_in,
                              void* d_out, int out_size, void* d_ws, size_t ws_size,
                              hipStream_t stream) {
  const float* src = (const float*)d_in[0];
  const float* tau = (const float*)d_in[1];
  const float* dain_Wm = (const float*)d_in[2];
  const float* dain_Ws = (const float*)d_in[3];
  const float* dain_Wg = (const float*)d_in[4];
  const float* dain_bg = (const float*)d_in[5];
  const float* memb_W = (const float*)d_in[6];
  const float* memb_b = (const float*)d_in[7];
  const float* t_w0 = (const float*)d_in[8];
  const float* t_b0 = (const float*)d_in[9];
  const float* t_w = (const float*)d_in[10];
  const float* t_b = (const float*)d_in[11];
  const float* tproj_W = (const float*)d_in[12];
  const float* tproj_b = (const float*)d_in[13];
  const float* ffn_W1 = (const float*)d_in[14];
  const float* ffn_b1 = (const float*)d_in[15];
  const float* ffn_W2 = (const float*)d_in[16];
  const float* ffn_b2 = (const float*)d_in[17];
  const float* n1_w = (const float*)d_in[18];
  const float* n1_b = (const float*)d_in[19];
  const float* inproj_W = (const float*)d_in[20];
  const float* conv_w = (const float*)d_in[21];
  const float* conv_b = (const float*)d_in[22];
  const float* xproj_W = (const float*)d_in[23];
  const float* dtproj_W = (const float*)d_in[24];
  const float* dt_bias = (const float*)d_in[25];
  const float* A_log = (const float*)d_in[26];
  const float* D_p = (const float*)d_in[27];
  const float* outproj_W = (const float*)d_in[28];
  const float* n2_w = (const float*)d_in[29];
  const float* n2_b = (const float*)d_in[30];
  const float* mlp_W1 = (const float*)d_in[31];
  const float* mlp_W2 = (const float*)d_in[32];
  const float* nf_w = (const float*)d_in[33];
  const float* nf_b = (const float*)d_in[34];
  const float* vW1 = (const float*)d_in[35]; const float* vb1 = (const float*)d_in[36];
  const float* vl1w = (const float*)d_in[37]; const float* vl1b = (const float*)d_in[38];
  const float* vW2 = (const float*)d_in[39]; const float* vb2 = (const float*)d_in[40];
  const float* vl2w = (const float*)d_in[41]; const float* vl2b = (const float*)d_in[42];
  const float* vW3 = (const float*)d_in[43]; const float* vb3 = (const float*)d_in[44];
  const float* aW1 = (const float*)d_in[45]; const float* ab1 = (const float*)d_in[46];
  const float* al1w = (const float*)d_in[47]; const float* al1b = (const float*)d_in[48];
  const float* aW2 = (const float*)d_in[49]; const float* ab2 = (const float*)d_in[50];
  const float* al2w = (const float*)d_in[51]; const float* al2b = (const float*)d_in[52];
  const float* aW3 = (const float*)d_in[53]; const float* ab3 = (const float*)d_in[54];
  float* out = (float*)d_out;

  float* ws = (float*)d_ws;
  float* stats = ws;                       // 256
  float* h    = stats + 256;               // BL*256
  float* big  = h + (size_t)BL * DMOD;     // BL*1408 (max row stride 1364)
  float* ucv  = big + (size_t)BL * 1408;   // BL*512
  float* xd   = ucv + (size_t)BL * DIN;    // BL*48
  float* dt   = xd + (size_t)BL * 48;      // BL*512
  float* houts = dt + (size_t)BL * DIN;    // 64
  float* fp_end = houts + 64;
  _Float16* h_hf   = (_Float16*)fp_end;             // BL*256
  _Float16* hn_hf  = h_hf + (size_t)BL * DMOD;      // BL*256
  _Float16* gout_hf = hn_hf + (size_t)BL * DMOD;    // BL*512
  _Float16* ffn1T  = gout_hf + (size_t)BL * DIN;    // 1408*256
  _Float16* ffn2T  = ffn1T + (size_t)1408 * 256;    // 256*704
  _Float16* inprojT = ffn2T + (size_t)256 * 704;    // 8*1024*256
  _Float16* outprojT = inprojT + (size_t)8 * 1024 * 256; // 8*256*512
  _Float16* mlp1T  = outprojT + (size_t)8 * 256 * 512;   // 8*512*256
  _Float16* mlp2T  = mlp1T + (size_t)8 * 512 * 256;      // 8*256*256

  // ---- weight transpose-converts (L2/L3-resident, ~11MB) ----
  convT_k<<<dim3(1408, 1), 256, 0, stream>>>(ffn_W1, ffn1T, 256, 1364, 256, 1408);
  convT_k<<<dim3(704, 1), 256, 0, stream>>>(ffn_W2, ffn2T, 682, 256, 704, 256);
  convT_k<<<dim3(1024, 8), 256, 0, stream>>>(inproj_W, inprojT, 256, 1024, 256, 1024);
  convT_k<<<dim3(512, 8), 256, 0, stream>>>(outproj_W, outprojT, 512, 256, 512, 256);
  convT_k<<<dim3(512, 8), 256, 0, stream>>>(mlp_W1, mlp1T, 256, 512, 256, 512);
  convT_k<<<dim3(256, 8), 256, 0, stream>>>(mlp_W2, mlp2T, 256, 256, 256, 256);

  dain_k<<<1, 1024, 0, stream>>>(src, dain_Wm, dain_Ws, dain_Wg, dain_bg, stats);
  embed_k<<<BL, 256, 0, stream>>>(src, tau, stats, memb_W, memb_b, t_w0, t_b0, t_w, t_b, tproj_W, tproj_b, h_hf);
  gemm_hf_k<<<dim3(22, 32), 256, 0, stream>>>(h_hf, ffn1T, ffn_b1, big, BL, 1364, 256, 1364, 0);
  // ffn2 + bias + LN(n1[0]) fused; A = a*gelu(g) from big (stride 1364)
  gemm_ln_k<2><<<64, 256, 0, stream>>>(nullptr, big, 1364, ffn2T, ffn_b2, h, n1_w, n1_b, hn_hf, 704, 0);

  for (int i = 0; i < 8; i++) {
    gemm_hf_k<<<dim3(16, 32), 256, 0, stream>>>(hn_hf, inprojT + (size_t)i * 1024 * 256, nullptr, big,
                                                BL, 1024, 256, 1024, 0);
    convxdt_k<<<BL, 128, 0, stream>>>(big, conv_w + (size_t)i * 512 * 4, conv_b + i * 512,
                                      xproj_W + (size_t)i * 512 * 48, dtproj_W + (size_t)i * 16 * 512,
                                      dt_bias + i * 512, ucv, xd, dt);
    scan_k<<<NCH, 256, 0, stream>>>(dt, ucv, xd, big, A_log + (size_t)i * 512 * 16, D_p + i * 512, gout_hf);
    gemm_ln_k<0><<<64, 256, 0, stream>>>(gout_hf, nullptr, 512, outprojT + (size_t)i * 256 * 512, nullptr,
                                         h, n2_w + i * 256, n2_b + i * 256, hn_hf, 512, 1);
    gemm_hf_k<<<dim3(8, 32), 256, 0, stream>>>(hn_hf, mlp1T + (size_t)i * 512 * 256, nullptr, big,
                                               BL, 512, 256, 512, 0);
    const float* lw = (i < 7) ? n1_w + (i + 1) * 256 : nullptr;
    const float* lb = (i < 7) ? n1_b + (i + 1) * 256 : nullptr;
    gemm_ln_k<1><<<64, 256, 0, stream>>>(nullptr, big, 512, mlp2T + (size_t)i * 256 * 256, nullptr,
                                         h, lw, lb, hn_hf, 256, 1);
  }

  head_k<<<8, 1024, 0, stream>>>(h, nf_w, nf_b,
                                 vW1, vb1, vl1w, vl1b, vW2, vb2, vl2w, vl2b, vW3, vb3,
                                 aW1, ab1, al1w, al1b, aW2, ab2, al2w, al2b, aW3, ab3, houts);
  comb_k<<<1, 64, 0, stream>>>(houts, out);
  (void)in_sizes; (void)n_in; (void)out_size; (void)ws_size;
}

// Round 6
// 1375.728 us; speedup vs baseline: 1.0358x; 1.0358x over previous
//
#include <hip/hip_runtime.h>
#include <math.h>

// Model constants
#define BL   2048   // B*L = 4*512
#define LSEQ 512
#define NB   4
#define DMOD 256
#define DIN  512
#define DFF  682
#define NCH  (NB * DIN)

typedef __attribute__((ext_vector_type(4))) float f32x4;
typedef __attribute__((ext_vector_type(8))) _Float16 f16x8;

__device__ __forceinline__ float sigmoidf_(float x) { return 1.f / (1.f + __expf(-x)); }
__device__ __forceinline__ float siluf_(float x) { return x / (1.f + __expf(-x)); }

// ---------------- DAIN stats (single block) ----------------
__global__ __launch_bounds__(1024) void dain_k(
    const float* __restrict__ src, const float* __restrict__ Wm,
    const float* __restrict__ Ws, const float* __restrict__ Wg,
    const float* __restrict__ bg, float* __restrict__ stats) {
  __shared__ float part[1024];
  __shared__ float avg_s[128], sub_s[128], std_s[128], mn_s[128], inv_s[128];
  int tid = threadIdx.x;
  int p = tid >> 3, j = tid & 7;
  int b = p >> 5, f = p & 31;
  float s = 0.f;
  for (int l = j * 64; l < j * 64 + 64; ++l) s += src[((size_t)b * LSEQ + l) * 32 + f];
  part[tid] = s;
  __syncthreads();
  if (tid < 128) { float a = 0; for (int k = 0; k < 8; k++) a += part[tid * 8 + k]; avg_s[tid] = a * (1.f / 512.f); }
  __syncthreads();
  if (tid < 128) {
    int bb = tid >> 5, ff = tid & 31;
    float a = 0; for (int g = 0; g < 32; g++) a += avg_s[bb * 32 + g] * Wm[ff * 32 + g];
    sub_s[tid] = a;
  }
  __syncthreads();
  float sub = sub_s[p];
  s = 0.f;
  for (int l = j * 64; l < j * 64 + 64; ++l) {
    float v = src[((size_t)b * LSEQ + l) * 32 + f] - sub; s += v * v;
  }
  part[tid] = s;
  __syncthreads();
  if (tid < 128) { float a = 0; for (int k = 0; k < 8; k++) a += part[tid * 8 + k]; std_s[tid] = sqrtf(a * (1.f / 512.f)); }
  __syncthreads();
  if (tid < 128) {
    int bb = tid >> 5, ff = tid & 31;
    float a = 0; for (int g = 0; g < 32; g++) a += std_s[bb * 32 + g] * Ws[ff * 32 + g];
    if (a <= 1e-8f) a = 1.f;
    inv_s[tid] = 1.f / a;
    mn_s[tid] = (avg_s[tid] - sub_s[tid]) / a;
  }
  __syncthreads();
  if (tid < 128) {
    int bb = tid >> 5, ff = tid & 31;
    float a = bg[ff]; for (int g = 0; g < 32; g++) a += mn_s[bb * 32 + g] * Wg[ff * 32 + g];
    float gate = sigmoidf_(a);
    float scl = gate * inv_s[tid];
    stats[tid] = scl;
    stats[128 + tid] = sub_s[tid] * scl;
  }
}

// ---------------- embed -> h_hf (f16) ----------------
__global__ __launch_bounds__(256) void embed_k(
    const float* __restrict__ src, const float* __restrict__ tau,
    const float* __restrict__ stats, const float* __restrict__ membW,
    const float* __restrict__ membB, const float* __restrict__ tw0,
    const float* __restrict__ tb0, const float* __restrict__ tw,
    const float* __restrict__ tb, const float* __restrict__ tprojW,
    const float* __restrict__ tprojB, _Float16* __restrict__ h_hf) {
  int token = blockIdx.x;
  int b = token >> 9;
  int t = threadIdx.x;
  __shared__ float xs[32], te[32];
  if (t < 32) {
    float scl = stats[b * 32 + t], shf = stats[128 + b * 32 + t];
    xs[t] = src[(size_t)token * 32 + t] * scl - shf;
  } else if (t < 64) {
    int j = t - 32;
    const float* tr = tau + (size_t)token * 8;
    float a;
    if (j < 31) { a = tb[j]; for (int k = 0; k < 8; k++) a += tr[k] * tw[k * 31 + j]; a = sinf(a); }
    else        { a = tb0[0]; for (int k = 0; k < 8; k++) a += tr[k] * tw0[k]; }
    te[j] = a;
  }
  __syncthreads();
  float acc;
  if (t < 128) {
    acc = membB[t];
    for (int f = 0; f < 32; f++) acc += xs[f] * membW[f * 128 + t];
  } else {
    int d = t - 128;
    acc = tprojB[d];
    for (int j = 0; j < 32; j++) acc += te[j] * tprojW[j * 128 + d];
  }
  h_hf[(size_t)token * DMOD + t] = (_Float16)acc;
}

// ---------------- all weight transpose-converts in ONE launch ----------------
__device__ __forceinline__ void convT_one(const float* __restrict__ W, _Float16* __restrict__ WT,
                                          int K, int N, int Kout, int Nout, int idx) {
  int per = Nout * Kout;
  int l = idx / per; int rem = idx - l * per;
  int n = rem / Kout; int k = rem - n * Kout;
  const float* Wl = W + (size_t)l * K * N;
  float v = (k < K && n < N) ? Wl[(size_t)k * N + n] : 0.f;
  WT[(size_t)l * per + rem] = (_Float16)v;
}

__global__ __launch_bounds__(256) void convall_k(
    const float* ffn_W1, const float* ffn_W2, const float* inproj_W,
    const float* outproj_W, const float* mlp_W1, const float* mlp_W2,
    _Float16* ffn1T, _Float16* ffn2T, _Float16* inprojT,
    _Float16* outprojT, _Float16* mlp1T, _Float16* mlp2T) {
  int g = blockIdx.x, t = threadIdx.x;
  if (g < 1408)            convT_one(ffn_W1, ffn1T, 256, 1364, 256, 1408, g * 256 + t);
  else if (g < 2112)       convT_one(ffn_W2, ffn2T, 682, 256, 704, 256, (g - 1408) * 256 + t);
  else if (g < 10304)      convT_one(inproj_W, inprojT, 256, 1024, 256, 1024, (g - 2112) * 256 + t);
  else if (g < 14400)      convT_one(outproj_W, outprojT, 512, 256, 512, 256, (g - 10304) * 256 + t);
  else if (g < 18496)      convT_one(mlp_W1, mlp1T, 256, 512, 256, 512, (g - 14400) * 256 + t);
  else                     convT_one(mlp_W2, mlp2T, 256, 256, 256, 256, (g - 18496) * 256 + t);
}

// ---------------- per-row LN stats for AOP3 ----------------
__global__ __launch_bounds__(256) void rowstat_k(const float* __restrict__ h, float* __restrict__ rstat) {
  int row = blockIdx.x * 4 + (threadIdx.x >> 6);
  int lane = threadIdx.x & 63;
  const float* rp = h + (size_t)row * 256;
  float4 v = *(const float4*)&rp[lane * 4];
  float s = v.x + v.y + v.z + v.w;
  float ss = v.x * v.x + v.y * v.y + v.z * v.z + v.w * v.w;
#pragma unroll
  for (int o = 32; o; o >>= 1) { s += __shfl_xor(s, o, 64); ss += __shfl_xor(ss, o, 64); }
  if (lane == 0) {
    float mu = s * (1.f / 256.f);
    float var = ss * (1.f / 256.f) - mu * mu;
    rstat[row * 2] = mu;
    rstat[row * 2 + 1] = rsqrtf(var + 1e-5f);
  }
}

// ---------------- f16 MFMA GEMM 64x64 tile with fused A-operand ----------------
// AOP0: A = Ah f16 [row][K].   AOP1: A[r][k] = silu(Af[r][k]) * Af[r][lda/2+k].
// AOP2: A[r][k] = Af[r][k] * gelu(Af[r][682+k]), guard k<682 (lda given).
// AOP3: A[r][k] = (Af[r][k]-mu_r)*rs_r*lnw[k]+lnb[k]  (lda=256, rstat).
template<int AOP>
__global__ __launch_bounds__(256) void gemm_k(
    const _Float16* __restrict__ Ah, const float* __restrict__ Af, int lda,
    const float* __restrict__ rstat, const float* __restrict__ lnw, const float* __restrict__ lnb,
    const _Float16* __restrict__ WT, const float* __restrict__ bias, float* __restrict__ C,
    int Nstore, int K, int ldc, int flags) {
  __shared__ _Float16 As[64][40];
  __shared__ _Float16 Bs[64][40];
  int bm = blockIdx.y * 64, bn = blockIdx.x * 64;
  int t = threadIdx.x;
  int w = t >> 6, l = t & 63;
  int wm = w >> 1, wn = w & 1;
  int srow = t >> 2, sk = (t & 3) * 8;
  int arow = bm + srow;
  f32x4 acc[2][2] = {};
  int lr = l & 15, lk = (l >> 4) * 8;
  float mu = 0.f, rs = 0.f;
  if (AOP == 3) { mu = rstat[arow * 2]; rs = rstat[arow * 2 + 1]; }
  for (int k0 = 0; k0 < K; k0 += 32) {
    if (AOP == 0) {
      *(uint4*)&As[srow][sk] = *(const uint4*)&Ah[(size_t)arow * K + k0 + sk];
    } else if (AOP == 1) {
      const float* rp = Af + (size_t)arow * lda;
      int half = lda >> 1;
      float4 g1a = *(const float4*)&rp[k0 + sk];
      float4 g1b = *(const float4*)&rp[k0 + sk + 4];
      float4 g2a = *(const float4*)&rp[half + k0 + sk];
      float4 g2b = *(const float4*)&rp[half + k0 + sk + 4];
      f16x8 av;
      av[0] = (_Float16)(siluf_(g1a.x) * g2a.x); av[1] = (_Float16)(siluf_(g1a.y) * g2a.y);
      av[2] = (_Float16)(siluf_(g1a.z) * g2a.z); av[3] = (_Float16)(siluf_(g1a.w) * g2a.w);
      av[4] = (_Float16)(siluf_(g1b.x) * g2b.x); av[5] = (_Float16)(siluf_(g1b.y) * g2b.y);
      av[6] = (_Float16)(siluf_(g1b.z) * g2b.z); av[7] = (_Float16)(siluf_(g1b.w) * g2b.w);
      *(f16x8*)&As[srow][sk] = av;
    } else if (AOP == 2) {
      const float* rp = Af + (size_t)arow * lda;
      f16x8 av;
#pragma unroll
      for (int e = 0; e < 8; e++) {
        int k = k0 + sk + e;
        float r = 0.f;
        if (k < 682) {
          float a = rp[k], g = rp[682 + k];
          r = a * 0.5f * g * (1.f + erff(g * 0.70710678118654752f));
        }
        av[e] = (_Float16)r;
      }
      *(f16x8*)&As[srow][sk] = av;
    } else {
      const float* rp = Af + (size_t)arow * 256;
      float4 xa = *(const float4*)&rp[k0 + sk];
      float4 xb = *(const float4*)&rp[k0 + sk + 4];
      float4 wa = *(const float4*)&lnw[k0 + sk];
      float4 wb = *(const float4*)&lnw[k0 + sk + 4];
      float4 ba = *(const float4*)&lnb[k0 + sk];
      float4 bb2 = *(const float4*)&lnb[k0 + sk + 4];
      f16x8 av;
      av[0] = (_Float16)((xa.x - mu) * rs * wa.x + ba.x);
      av[1] = (_Float16)((xa.y - mu) * rs * wa.y + ba.y);
      av[2] = (_Float16)((xa.z - mu) * rs * wa.z + ba.z);
      av[3] = (_Float16)((xa.w - mu) * rs * wa.w + ba.w);
      av[4] = (_Float16)((xb.x - mu) * rs * wb.x + bb2.x);
      av[5] = (_Float16)((xb.y - mu) * rs * wb.y + bb2.y);
      av[6] = (_Float16)((xb.z - mu) * rs * wb.z + bb2.z);
      av[7] = (_Float16)((xb.w - mu) * rs * wb.w + bb2.w);
      *(f16x8*)&As[srow][sk] = av;
    }
    *(uint4*)&Bs[srow][sk] = *(const uint4*)&WT[(size_t)(bn + srow) * K + k0 + sk];
    __syncthreads();
    f16x8 a0 = *(const f16x8*)&As[wm * 32 + lr][lk];
    f16x8 a1 = *(const f16x8*)&As[wm * 32 + 16 + lr][lk];
    f16x8 b0 = *(const f16x8*)&Bs[wn * 32 + lr][lk];
    f16x8 b1 = *(const f16x8*)&Bs[wn * 32 + 16 + lr][lk];
    acc[0][0] = __builtin_amdgcn_mfma_f32_16x16x32_f16(a0, b0, acc[0][0], 0, 0, 0);
    acc[0][1] = __builtin_amdgcn_mfma_f32_16x16x32_f16(a0, b1, acc[0][1], 0, 0, 0);
    acc[1][0] = __builtin_amdgcn_mfma_f32_16x16x32_f16(a1, b0, acc[1][0], 0, 0, 0);
    acc[1][1] = __builtin_amdgcn_mfma_f32_16x16x32_f16(a1, b1, acc[1][1], 0, 0, 0);
    __syncthreads();
  }
  int lq = l >> 4;
#pragma unroll
  for (int i = 0; i < 2; i++) {
#pragma unroll
    for (int j = 0; j < 2; j++) {
      int col = bn + wn * 32 + j * 16 + lr;
      if (col >= Nstore) continue;
      float bv = bias ? bias[col] : 0.f;
#pragma unroll
      for (int r = 0; r < 4; r++) {
        int row = bm + wm * 32 + i * 16 + lq * 4 + r;
        float v = acc[i][j][r] + bv;
        size_t idx = (size_t)row * ldc + col;
        if (flags & 1) v += C[idx];
        C[idx] = v;
      }
    }
  }
}

// ---------------- fused conv4+silu -> xproj -> dtproj+softplus (one block per token) ----------------
__global__ __launch_bounds__(128) void convxdt_k(
    const float* __restrict__ big, const float* __restrict__ cw, const float* __restrict__ cb,
    const float* __restrict__ xW, const float* __restrict__ dW, const float* __restrict__ dbias,
    float* __restrict__ ucv, float* __restrict__ xd, float* __restrict__ dt) {
  __shared__ float us[512];
  __shared__ float xs[48];
  int token = blockIdx.x;
  int b = token >> 9, l = token & 511;
  int t = threadIdx.x;
  for (int c = t; c < 512; c += 128) {
    float acc = cb[c];
#pragma unroll
    for (int k = 0; k < 4; k++) {
      int l2 = l - 3 + k;
      if (l2 >= 0) acc += big[((size_t)(b * LSEQ + l2)) * 1024 + c] * cw[c * 4 + k];
    }
    float u = siluf_(acc);
    us[c] = u;
    ucv[(size_t)token * 512 + c] = u;
  }
  __syncthreads();
  float part = 0.f;
  int j = t >> 1, p = t & 1;
  if (t < 96) {
    for (int c = p * 256; c < p * 256 + 256; c++) part += us[c] * xW[c * 48 + j];
  }
  part += __shfl_xor(part, 1, 64);
  if (t < 96 && p == 0) {
    xs[j] = part;
    xd[(size_t)token * 48 + j] = part;
  }
  __syncthreads();
  for (int c = t; c < 512; c += 128) {
    float acc = dbias[c];
#pragma unroll
    for (int r = 0; r < 16; r++) acc += xs[r] * dW[r * 512 + c];
    dt[(size_t)token * 512 + c] = (acc > 20.f) ? acc : log1pf(__expf(acc));
  }
}

// ---------------- fused chunked scan (one block per channel) ----------------
__global__ __launch_bounds__(256) void scan_k(
    const float* __restrict__ dt, const float* __restrict__ ucv, const float* __restrict__ xd,
    const float* __restrict__ zbuf, const float* __restrict__ A_log, const float* __restrict__ D_p,
    _Float16* __restrict__ gout) {
  __shared__ float Ps[16][17], Hs[16][17], Hi[16][17];
  int ch = blockIdx.x;
  int b = ch >> 9, d = ch & 511;
  int t = threadIdx.x;
  int c = t >> 4, n = t & 15;
  float An = -__expf(A_log[d * 16 + n]);
  float P = 1.f, h = 0.f;
  int t0 = b * LSEQ + c * 32;
  for (int tt = 0; tt < 32; tt++) {
    int token = t0 + tt;
    float dtv = dt[(size_t)token * 512 + d];
    float uv = ucv[(size_t)token * 512 + d];
    float Bn = xd[(size_t)token * 48 + 16 + n];
    float dA = __expf(dtv * An);
    P *= dA;
    h = dA * h + dtv * uv * Bn;
  }
  Ps[c][n] = P; Hs[c][n] = h;
  __syncthreads();
  if (t < 16) {
    float hr = 0.f;
    for (int cc = 0; cc < 16; cc++) { Hi[cc][t] = hr; hr = Ps[cc][t] * hr + Hs[cc][t]; }
  }
  __syncthreads();
  h = Hi[c][n];
  float Dd = D_p[d];
  for (int tt = 0; tt < 32; tt++) {
    int token = t0 + tt;
    float dtv = dt[(size_t)token * 512 + d];
    float uv = ucv[(size_t)token * 512 + d];
    float Bn = xd[(size_t)token * 48 + 16 + n];
    float Cn = xd[(size_t)token * 48 + 32 + n];
    float dA = __expf(dtv * An);
    h = dA * h + dtv * uv * Bn;
    float y = h * Cn;
    y += __shfl_xor(y, 1, 64);
    y += __shfl_xor(y, 2, 64);
    y += __shfl_xor(y, 4, 64);
    y += __shfl_xor(y, 8, 64);
    if (n == 0) {
      float z = zbuf[(size_t)token * 1024 + 512 + d];
      gout[(size_t)token * 512 + d] = (_Float16)((y + uv * Dd) * siluf_(z));
    }
  }
}

// ---------------- head: 6 wide kernels ----------------
__global__ __launch_bounds__(256) void lnf_k(const float* __restrict__ h, const float* __restrict__ nfw,
                                             const float* __restrict__ nfb, float* __restrict__ f) {
  __shared__ float red[4];
  int b = blockIdx.x, t = threadIdx.x;
  int lane = t & 63, wid = t >> 6;
  float v = h[((size_t)b * LSEQ + (LSEQ - 1)) * DMOD + t];
  float s = v;
#pragma unroll
  for (int o = 32; o; o >>= 1) s += __shfl_xor(s, o, 64);
  if (lane == 0) red[wid] = s;
  __syncthreads();
  float mu = (red[0] + red[1] + red[2] + red[3]) * (1.f / 256.f);
  float dv = v - mu;
  s = dv * dv;
#pragma unroll
  for (int o = 32; o; o >>= 1) s += __shfl_xor(s, o, 64);
  __syncthreads();
  if (lane == 0) red[wid] = s;
  __syncthreads();
  float var = (red[0] + red[1] + red[2] + red[3]) * (1.f / 256.f);
  f[b * 256 + t] = dv * rsqrtf(var + 1e-5f) * nfw[t] + nfb[t];
}

__global__ __launch_bounds__(256) void hgemm1_k(const float* __restrict__ f,
    const float* vW1, const float* vb1, const float* aW1, const float* ab1,
    float* __restrict__ a1) {
  int cb = blockIdx.x, b = blockIdx.y, p = blockIdx.z;
  const float* W1 = p ? aW1 : vW1;
  const float* b1 = p ? ab1 : vb1;
  __shared__ float fs[256];
  int t = threadIdx.x;
  fs[t] = f[b * 256 + t];
  __syncthreads();
  int col = cb * 256 + t;
  float acc = b1[col];
#pragma unroll 4
  for (int k = 0; k < 256; k++) acc += fs[k] * W1[k * 512 + col];
  a1[((b * 2 + p) * 512) + col] = acc;
}

__global__ __launch_bounds__(512) void hln1_k(const float* __restrict__ a1,
    const float* vl1w, const float* vl1b, const float* al1w, const float* al1b,
    float* __restrict__ t1) {
  __shared__ float red[8];
  int b = blockIdx.x, p = blockIdx.y, t = threadIdx.x;
  const float* lw = p ? al1w : vl1w;
  const float* lb = p ? al1b : vl1b;
  int lane = t & 63, wid = t >> 6;
  int idx = (b * 2 + p) * 512 + t;
  float v = a1[idx];
  float s = v;
#pragma unroll
  for (int o = 32; o; o >>= 1) s += __shfl_xor(s, o, 64);
  if (lane == 0) red[wid] = s;
  __syncthreads();
  float S = 0.f;
#pragma unroll
  for (int k = 0; k < 8; k++) S += red[k];
  float mu = S * (1.f / 512.f);
  float dv = v - mu;
  s = dv * dv;
#pragma unroll
  for (int o = 32; o; o >>= 1) s += __shfl_xor(s, o, 64);
  __syncthreads();
  if (lane == 0) red[wid] = s;
  __syncthreads();
  S = 0.f;
#pragma unroll
  for (int k = 0; k < 8; k++) S += red[k];
  float var = S * (1.f / 512.f);
  t1[idx] = fmaxf(dv * rsqrtf(var + 1e-5f) * lw[t] + lb[t], 0.f);
}

__global__ __launch_bounds__(256) void hgemm2_k(const float* __restrict__ t1,
    const float* vW2, const float* vb2, const float* aW2, const float* ab2,
    float* __restrict__ a2) {
  int b = blockIdx.x, p = blockIdx.y;
  const float* W2 = p ? aW2 : vW2;
  const float* b2 = p ? ab2 : vb2;
  __shared__ float ts[512];
  int t = threadIdx.x;
  ts[t] = t1[(b * 2 + p) * 512 + t];
  ts[256 + t] = t1[(b * 2 + p) * 512 + 256 + t];
  __syncthreads();
  float acc = b2[t];
#pragma unroll 4
  for (int k = 0; k < 512; k++) acc += ts[k] * W2[k * 256 + t];
  a2[(b * 2 + p) * 256 + t] = acc;
}

__global__ __launch_bounds__(256) void hln2_k(const float* __restrict__ a2,
    const float* vl2w, const float* vl2b, const float* al2w, const float* al2b,
    float* __restrict__ t2) {
  __shared__ float red[4];
  int b = blockIdx.x, p = blockIdx.y, t = threadIdx.x;
  const float* lw = p ? al2w : vl2w;
  const float* lb = p ? al2b : vl2b;
  int lane = t & 63, wid = t >> 6;
  int idx = (b * 2 + p) * 256 + t;
  float v = a2[idx];
  float s = v;
#pragma unroll
  for (int o = 32; o; o >>= 1) s += __shfl_xor(s, o, 64);
  if (lane == 0) red[wid] = s;
  __syncthreads();
  float mu = (red[0] + red[1] + red[2] + red[3]) * (1.f / 256.f);
  float dv = v - mu;
  s = dv * dv;
#pragma unroll
  for (int o = 32; o; o >>= 1) s += __shfl_xor(s, o, 64);
  __syncthreads();
  if (lane == 0) red[wid] = s;
  __syncthreads();
  float var = (red[0] + red[1] + red[2] + red[3]) * (1.f / 256.f);
  t2[idx] = fmaxf(dv * rsqrtf(var + 1e-5f) * lw[t] + lb[t], 0.f);
}

__global__ __launch_bounds__(256) void hfinal_k(const float* __restrict__ t2,
    const float* vW3, const float* vb3, const float* aW3, const float* ab3,
    float* __restrict__ q) {
  __shared__ float a3s[24];
  int t = threadIdx.x;
  int g = t >> 3, ln8 = t & 7;
  if (g < 24) {
    int b = g / 6, r = g - b * 6;
    int p = r ? 1 : 0;
    int o = r ? r - 1 : 0;
    const float* W3 = p ? aW3 : vW3;
    const float* b3 = p ? ab3 : vb3;
    int nout = p ? 5 : 1;
    const float* t2r = t2 + (b * 2 + p) * 256;
    float acc = 0.f;
    for (int k = ln8; k < 256; k += 8) acc += t2r[k] * W3[k * nout + o];
    acc += __shfl_xor(acc, 1, 64);
    acc += __shfl_xor(acc, 2, 64);
    acc += __shfl_xor(acc, 4, 64);
    if (ln8 == 0) a3s[g] = acc + b3[o];
  }
  __syncthreads();
  if (t < 20) {
    int b = t / 5, a = t - b * 5;
    float val = a3s[b * 6];
    float m = 0.f;
#pragma unroll
    for (int j = 0; j < 5; j++) m += a3s[b * 6 + 1 + j];
    m *= 0.2f;
    q[b * 5 + a] = val + a3s[b * 6 + 1 + a] - m;
  }
}

extern "C" void kernel_launch(void* const* d_in, const int* in_sizes, int n_in,
                              void* d_out, int out_size, void* d_ws, size_t ws_size,
                              hipStream_t stream) {
  const float* src = (const float*)d_in[0];
  const float* tau = (const float*)d_in[1];
  const float* dain_Wm = (const float*)d_in[2];
  const float* dain_Ws = (const float*)d_in[3];
  const float* dain_Wg = (const float*)d_in[4];
  const float* dain_bg = (const float*)d_in[5];
  const float* memb_W = (const float*)d_in[6];
  const float* memb_b = (const float*)d_in[7];
  const float* t_w0 = (const float*)d_in[8];
  const float* t_b0 = (const float*)d_in[9];
  const float* t_w = (const float*)d_in[10];
  const float* t_b = (const float*)d_in[11];
  const float* tproj_W = (const float*)d_in[12];
  const float* tproj_b = (const float*)d_in[13];
  const float* ffn_W1 = (const float*)d_in[14];
  const float* ffn_b1 = (const float*)d_in[15];
  const float* ffn_W2 = (const float*)d_in[16];
  const float* ffn_b2 = (const float*)d_in[17];
  const float* n1_w = (const float*)d_in[18];
  const float* n1_b = (const float*)d_in[19];
  const float* inproj_W = (const float*)d_in[20];
  const float* conv_w = (const float*)d_in[21];
  const float* conv_b = (const float*)d_in[22];
  const float* xproj_W = (const float*)d_in[23];
  const float* dtproj_W = (const float*)d_in[24];
  const float* dt_bias = (const float*)d_in[25];
  const float* A_log = (const float*)d_in[26];
  const float* D_p = (const float*)d_in[27];
  const float* outproj_W = (const float*)d_in[28];
  const float* n2_w = (const float*)d_in[29];
  const float* n2_b = (const float*)d_in[30];
  const float* mlp_W1 = (const float*)d_in[31];
  const float* mlp_W2 = (const float*)d_in[32];
  const float* nf_w = (const float*)d_in[33];
  const float* nf_b = (const float*)d_in[34];
  const float* vW1 = (const float*)d_in[35]; const float* vb1 = (const float*)d_in[36];
  const float* vl1w = (const float*)d_in[37]; const float* vl1b = (const float*)d_in[38];
  const float* vW2 = (const float*)d_in[39]; const float* vb2 = (const float*)d_in[40];
  const float* vl2w = (const float*)d_in[41]; const float* vl2b = (const float*)d_in[42];
  const float* vW3 = (const float*)d_in[43]; const float* vb3 = (const float*)d_in[44];
  const float* aW1 = (const float*)d_in[45]; const float* ab1 = (const float*)d_in[46];
  const float* al1w = (const float*)d_in[47]; const float* al1b = (const float*)d_in[48];
  const float* aW2 = (const float*)d_in[49]; const float* ab2 = (const float*)d_in[50];
  const float* al2w = (const float*)d_in[51]; const float* al2b = (const float*)d_in[52];
  const float* aW3 = (const float*)d_in[53]; const float* ab3 = (const float*)d_in[54];
  float* out = (float*)d_out;

  float* ws = (float*)d_ws;
  float* dstats = ws;                      // 256
  float* h    = dstats + 256;              // BL*256
  float* big  = h + (size_t)BL * DMOD;     // BL*1408
  float* ucv  = big + (size_t)BL * 1408;   // BL*512
  float* xd   = ucv + (size_t)BL * DIN;    // BL*48
  float* dt   = xd + (size_t)BL * 48;      // BL*512
  float* rstat = dt + (size_t)BL * DIN;    // BL*2
  float* fh   = rstat + (size_t)BL * 2;    // 1024
  float* a1   = fh + 1024;                 // 4096
  float* t1   = a1 + 4096;                 // 4096
  float* a2   = t1 + 4096;                 // 2048
  float* t2   = a2 + 2048;                 // 2048
  float* fp_end = t2 + 2048;
  _Float16* h_hf    = (_Float16*)fp_end;            // BL*256
  _Float16* gout_hf = h_hf + (size_t)BL * DMOD;     // BL*512
  _Float16* ffn1T   = gout_hf + (size_t)BL * DIN;   // 1408*256
  _Float16* ffn2T   = ffn1T + (size_t)1408 * 256;   // 256*704
  _Float16* inprojT = ffn2T + (size_t)256 * 704;    // 8*1024*256
  _Float16* outprojT = inprojT + (size_t)8 * 1024 * 256;
  _Float16* mlp1T   = outprojT + (size_t)8 * 256 * 512;
  _Float16* mlp2T   = mlp1T + (size_t)8 * 512 * 256;

  convall_k<<<20544, 256, 0, stream>>>(ffn_W1, ffn_W2, inproj_W, outproj_W, mlp_W1, mlp_W2,
                                       ffn1T, ffn2T, inprojT, outprojT, mlp1T, mlp2T);
  dain_k<<<1, 1024, 0, stream>>>(src, dain_Wm, dain_Ws, dain_Wg, dain_bg, dstats);
  embed_k<<<BL, 256, 0, stream>>>(src, tau, dstats, memb_W, memb_b, t_w0, t_b0, t_w, t_b, tproj_W, tproj_b, h_hf);
  // ffn1: h_hf @ ffn1T -> big (fp32, stride 1364)
  gemm_k<0><<<dim3(22, 32), 256, 0, stream>>>(h_hf, nullptr, 0, nullptr, nullptr, nullptr,
                                              ffn1T, ffn_b1, big, 1364, 256, 1364, 0);
  // ffn2: A = a*gelu(g) from big -> h (fp32)
  gemm_k<2><<<dim3(4, 32), 256, 0, stream>>>(nullptr, big, 1364, nullptr, nullptr, nullptr,
                                             ffn2T, ffn_b2, h, 256, 704, 256, 0);

  for (int i = 0; i < 8; i++) {
    rowstat_k<<<BL / 4, 256, 0, stream>>>(h, rstat);
    gemm_k<3><<<dim3(16, 32), 256, 0, stream>>>(nullptr, h, 256, rstat, n1_w + i * 256, n1_b + i * 256,
                                                inprojT + (size_t)i * 1024 * 256, nullptr, big,
                                                1024, 256, 1024, 0);
    convxdt_k<<<BL, 128, 0, stream>>>(big, conv_w + (size_t)i * 512 * 4, conv_b + i * 512,
                                      xproj_W + (size_t)i * 512 * 48, dtproj_W + (size_t)i * 16 * 512,
                                      dt_bias + i * 512, ucv, xd, dt);
    scan_k<<<NCH, 256, 0, stream>>>(dt, ucv, xd, big, A_log + (size_t)i * 512 * 16, D_p + i * 512, gout_hf);
    gemm_k<0><<<dim3(4, 32), 256, 0, stream>>>(gout_hf, nullptr, 0, nullptr, nullptr, nullptr,
                                               outprojT + (size_t)i * 256 * 512, nullptr, h,
                                               256, 512, 256, 1);
    rowstat_k<<<BL / 4, 256, 0, stream>>>(h, rstat);
    gemm_k<3><<<dim3(8, 32), 256, 0, stream>>>(nullptr, h, 256, rstat, n2_w + i * 256, n2_b + i * 256,
                                               mlp1T + (size_t)i * 512 * 256, nullptr, big,
                                               512, 256, 512, 0);
    gemm_k<1><<<dim3(4, 32), 256, 0, stream>>>(nullptr, big, 512, nullptr, nullptr, nullptr,
                                               mlp2T + (size_t)i * 256 * 256, nullptr, h,
                                               256, 256, 256, 1);
  }

  lnf_k<<<NB, 256, 0, stream>>>(h, nf_w, nf_b, fh);
  hgemm1_k<<<dim3(2, 4, 2), 256, 0, stream>>>(fh, vW1, vb1, aW1, ab1, a1);
  hln1_k<<<dim3(4, 2), 512, 0, stream>>>(a1, vl1w, vl1b, al1w, al1b, t1);
  hgemm2_k<<<dim3(4, 2), 256, 0, stream>>>(t1, vW2, vb2, aW2, ab2, a2);
  hln2_k<<<dim3(4, 2), 256, 0, stream>>>(a2, vl2w, vl2b, al2w, al2b, t2);
  hfinal_k<<<1, 256, 0, stream>>>(t2, vW3, vb3, aW3, ab3, out);
  (void)in_sizes; (void)n_in; (void)out_size; (void)ws_size;
}

// Round 8
// 1257.481 us; speedup vs baseline: 1.1332x; 1.0940x over previous
//
#include <hip/hip_runtime.h>
#include <math.h>

// Model constants
#define BL   2048   // B*L = 4*512
#define LSEQ 512
#define NB   4
#define DMOD 256
#define DIN  512
#define NCH  (NB * DIN)

typedef __attribute__((ext_vector_type(4))) float f32x4;
typedef __attribute__((ext_vector_type(8))) _Float16 f16x8;
typedef __attribute__((ext_vector_type(4))) _Float16 f16x4;

__device__ __forceinline__ float sigmoidf_(float x) { return 1.f / (1.f + __expf(-x)); }
__device__ __forceinline__ float siluf_(float x) { return x / (1.f + __expf(-x)); }

// ---------------- DAIN stats (single block) ----------------
__global__ __launch_bounds__(1024) void dain_k(
    const float* __restrict__ src, const float* __restrict__ Wm,
    const float* __restrict__ Ws, const float* __restrict__ Wg,
    const float* __restrict__ bg, float* __restrict__ stats) {
  __shared__ float part[1024];
  __shared__ float avg_s[128], sub_s[128], std_s[128], mn_s[128], inv_s[128];
  int tid = threadIdx.x;
  int p = tid >> 3, j = tid & 7;
  int b = p >> 5, f = p & 31;
  float s = 0.f;
  for (int l = j * 64; l < j * 64 + 64; ++l) s += src[((size_t)b * LSEQ + l) * 32 + f];
  part[tid] = s;
  __syncthreads();
  if (tid < 128) { float a = 0; for (int k = 0; k < 8; k++) a += part[tid * 8 + k]; avg_s[tid] = a * (1.f / 512.f); }
  __syncthreads();
  if (tid < 128) {
    int bb = tid >> 5, ff = tid & 31;
    float a = 0; for (int g = 0; g < 32; g++) a += avg_s[bb * 32 + g] * Wm[ff * 32 + g];
    sub_s[tid] = a;
  }
  __syncthreads();
  float sub = sub_s[p];
  s = 0.f;
  for (int l = j * 64; l < j * 64 + 64; ++l) {
    float v = src[((size_t)b * LSEQ + l) * 32 + f] - sub; s += v * v;
  }
  part[tid] = s;
  __syncthreads();
  if (tid < 128) { float a = 0; for (int k = 0; k < 8; k++) a += part[tid * 8 + k]; std_s[tid] = sqrtf(a * (1.f / 512.f)); }
  __syncthreads();
  if (tid < 128) {
    int bb = tid >> 5, ff = tid & 31;
    float a = 0; for (int g = 0; g < 32; g++) a += std_s[bb * 32 + g] * Ws[ff * 32 + g];
    if (a <= 1e-8f) a = 1.f;
    inv_s[tid] = 1.f / a;
    mn_s[tid] = (avg_s[tid] - sub_s[tid]) / a;
  }
  __syncthreads();
  if (tid < 128) {
    int bb = tid >> 5, ff = tid & 31;
    float a = bg[ff]; for (int g = 0; g < 32; g++) a += mn_s[bb * 32 + g] * Wg[ff * 32 + g];
    float gate = sigmoidf_(a);
    float scl = gate * inv_s[tid];
    stats[tid] = scl;
    stats[128 + tid] = sub_s[tid] * scl;
  }
}

// ---------------- embed -> h_hf (f16) ----------------
__global__ __launch_bounds__(256) void embed_k(
    const float* __restrict__ src, const float* __restrict__ tau,
    const float* __restrict__ stats, const float* __restrict__ membW,
    const float* __restrict__ membB, const float* __restrict__ tw0,
    const float* __restrict__ tb0, const float* __restrict__ tw,
    const float* __restrict__ tb, const float* __restrict__ tprojW,
    const float* __restrict__ tprojB, _Float16* __restrict__ h_hf) {
  int token = blockIdx.x;
  int b = token >> 9;
  int t = threadIdx.x;
  __shared__ float xs[32], te[32];
  if (t < 32) {
    float scl = stats[b * 32 + t], shf = stats[128 + b * 32 + t];
    xs[t] = src[(size_t)token * 32 + t] * scl - shf;
  } else if (t < 64) {
    int j = t - 32;
    const float* tr = tau + (size_t)token * 8;
    float a;
    if (j < 31) { a = tb[j]; for (int k = 0; k < 8; k++) a += tr[k] * tw[k * 31 + j]; a = sinf(a); }
    else        { a = tb0[0]; for (int k = 0; k < 8; k++) a += tr[k] * tw0[k]; }
    te[j] = a;
  }
  __syncthreads();
  float acc;
  if (t < 128) {
    acc = membB[t];
    for (int f = 0; f < 32; f++) acc += xs[f] * membW[f * 128 + t];
  } else {
    int d = t - 128;
    acc = tprojB[d];
    for (int j = 0; j < 32; j++) acc += te[j] * tprojW[j * 128 + d];
  }
  h_hf[(size_t)token * DMOD + t] = (_Float16)acc;
}

// ---------------- all weight transpose-converts in ONE launch ----------------
__device__ __forceinline__ void convT_one(const float* __restrict__ W, _Float16* __restrict__ WT,
                                          int K, int N, int Kout, int Nout, int idx) {
  int per = Nout * Kout;
  int l = idx / per; int rem = idx - l * per;
  int n = rem / Kout; int k = rem - n * Kout;
  const float* Wl = W + (size_t)l * K * N;
  float v = (k < K && n < N) ? Wl[(size_t)k * N + n] : 0.f;
  WT[(size_t)l * per + rem] = (_Float16)v;
}

__global__ __launch_bounds__(256) void convall_k(
    const float* ffn_W1, const float* ffn_W2, const float* inproj_W,
    const float* outproj_W, const float* mlp_W1, const float* mlp_W2,
    _Float16* ffn1T, _Float16* ffn2T, _Float16* inprojT,
    _Float16* outprojT, _Float16* mlp1T, _Float16* mlp2T) {
  int g = blockIdx.x, t = threadIdx.x;
  if (g < 1408)            convT_one(ffn_W1, ffn1T, 256, 1364, 256, 1408, g * 256 + t);
  else if (g < 2112)       convT_one(ffn_W2, ffn2T, 682, 256, 704, 256, (g - 1408) * 256 + t);
  else if (g < 10304)      convT_one(inproj_W, inprojT, 256, 1024, 256, 1024, (g - 2112) * 256 + t);
  else if (g < 14400)      convT_one(outproj_W, outprojT, 512, 256, 512, 256, (g - 10304) * 256 + t);
  else if (g < 18496)      convT_one(mlp_W1, mlp1T, 256, 512, 256, 512, (g - 14400) * 256 + t);
  else                     convT_one(mlp_W2, mlp2T, 256, 256, 256, 256, (g - 18496) * 256 + t);
}

// ---------------- plain f16 MFMA GEMM 64x64 tile (A stride == K) ----------------
__global__ __launch_bounds__(256) void gemm_hf_k(
    const _Float16* __restrict__ A, const _Float16* __restrict__ WT,
    const float* __restrict__ bias, float* __restrict__ C,
    int M, int Nstore, int K, int ldc, int flags) {
  __shared__ _Float16 As[64][40];
  __shared__ _Float16 Bs[64][40];
  int bm = blockIdx.y * 64, bn = blockIdx.x * 64;
  int t = threadIdx.x;
  int w = t >> 6, l = t & 63;
  int wm = w >> 1, wn = w & 1;
  int srow = t >> 2, sk = (t & 3) * 8;
  f32x4 acc[2][2] = {};
  int lr = l & 15, lk = (l >> 4) * 8;
  for (int k0 = 0; k0 < K; k0 += 32) {
    *(uint4*)&As[srow][sk] = *(const uint4*)&A[(size_t)(bm + srow) * K + k0 + sk];
    *(uint4*)&Bs[srow][sk] = *(const uint4*)&WT[(size_t)(bn + srow) * K + k0 + sk];
    __syncthreads();
    f16x8 a0 = *(const f16x8*)&As[wm * 32 + lr][lk];
    f16x8 a1 = *(const f16x8*)&As[wm * 32 + 16 + lr][lk];
    f16x8 b0 = *(const f16x8*)&Bs[wn * 32 + lr][lk];
    f16x8 b1 = *(const f16x8*)&Bs[wn * 32 + 16 + lr][lk];
    acc[0][0] = __builtin_amdgcn_mfma_f32_16x16x32_f16(a0, b0, acc[0][0], 0, 0, 0);
    acc[0][1] = __builtin_amdgcn_mfma_f32_16x16x32_f16(a0, b1, acc[0][1], 0, 0, 0);
    acc[1][0] = __builtin_amdgcn_mfma_f32_16x16x32_f16(a1, b0, acc[1][0], 0, 0, 0);
    acc[1][1] = __builtin_amdgcn_mfma_f32_16x16x32_f16(a1, b1, acc[1][1], 0, 0, 0);
    __syncthreads();
  }
  int lq = l >> 4;
#pragma unroll
  for (int i = 0; i < 2; i++) {
#pragma unroll
    for (int j = 0; j < 2; j++) {
      int col = bn + wn * 32 + j * 16 + lr;
      if (col >= Nstore) continue;
      float bv = bias ? bias[col] : 0.f;
#pragma unroll
      for (int r = 0; r < 4; r++) {
        int row = bm + wm * 32 + i * 16 + lq * 4 + r;
        float v = acc[i][j][r] + bv;
        size_t idx = (size_t)row * ldc + col;
        if (flags & 1) v += C[idx];
        C[idx] = v;
      }
    }
  }
}

// ---------------- FFN GLU (a * gelu_exact(g)) -> f16 padded to 704 ----------------
__global__ __launch_bounds__(256) void glugelu_k(const float* __restrict__ big, _Float16* __restrict__ out) {
  int i = blockIdx.x * 256 + threadIdx.x; // BL*704
  int token = i / 704, j = i - token * 704;
  float r = 0.f;
  if (j < 682) {
    float a = big[(size_t)token * 1364 + j];
    float g = big[(size_t)token * 1364 + 682 + j];
    r = a * 0.5f * g * (1.f + erff(g * 0.70710678118654752f));
  }
  out[i] = (_Float16)r;
}

// ---------------- LayerNorm, 4 rows/block (wave per row) -> f16 ----------------
__global__ __launch_bounds__(256) void ln4_k(const float* __restrict__ x, const float* __restrict__ w,
                                             const float* __restrict__ b, _Float16* __restrict__ out) {
  int row = blockIdx.x * 4 + (threadIdx.x >> 6), lane = threadIdx.x & 63;
  const float* rp = x + (size_t)row * 256;
  float4 v = *(const float4*)&rp[lane * 4];
  float s = v.x + v.y + v.z + v.w;
  float ss = v.x * v.x + v.y * v.y + v.z * v.z + v.w * v.w;
#pragma unroll
  for (int o = 32; o; o >>= 1) { s += __shfl_xor(s, o, 64); ss += __shfl_xor(ss, o, 64); }
  float mu = s * (1.f / 256.f);
  float var = ss * (1.f / 256.f) - mu * mu;
  float rs = rsqrtf(var + 1e-5f);
  float4 wv = *(const float4*)&w[lane * 4];
  float4 bv = *(const float4*)&b[lane * 4];
  f16x4 o4;
  o4[0] = (_Float16)((v.x - mu) * rs * wv.x + bv.x);
  o4[1] = (_Float16)((v.y - mu) * rs * wv.y + bv.y);
  o4[2] = (_Float16)((v.z - mu) * rs * wv.z + bv.z);
  o4[3] = (_Float16)((v.w - mu) * rs * wv.w + bv.w);
  *(f16x4*)&out[(size_t)row * 256 + lane * 4] = o4;
}

// ---------------- fused conv4+silu -> xproj -> dtproj+softplus ----------------
__global__ __launch_bounds__(128) void convxdt_k(
    const float* __restrict__ big, const float* __restrict__ cw, const float* __restrict__ cb,
    const float* __restrict__ xW, const float* __restrict__ dW, const float* __restrict__ dbias,
    float* __restrict__ ucv, float* __restrict__ xd, float* __restrict__ dt) {
  __shared__ float us[512];
  __shared__ float xs[48];
  int token = blockIdx.x;
  int b = token >> 9, l = token & 511;
  int t = threadIdx.x;
  for (int c = t; c < 512; c += 128) {
    float acc = cb[c];
#pragma unroll
    for (int k = 0; k < 4; k++) {
      int l2 = l - 3 + k;
      if (l2 >= 0) acc += big[((size_t)(b * LSEQ + l2)) * 1024 + c] * cw[c * 4 + k];
    }
    float u = siluf_(acc);
    us[c] = u;
    ucv[(size_t)token * 512 + c] = u;
  }
  __syncthreads();
  float part = 0.f;
  int j = t >> 1, p = t & 1;
  if (t < 96) {
    for (int c = p * 256; c < p * 256 + 256; c++) part += us[c] * xW[c * 48 + j];
  }
  part += __shfl_xor(part, 1, 64);
  if (t < 96 && p == 0) {
    xs[j] = part;
    xd[(size_t)token * 48 + j] = part;
  }
  __syncthreads();
  for (int c = t; c < 512; c += 128) {
    float acc = dbias[c];
#pragma unroll
    for (int r = 0; r < 16; r++) acc += xs[r] * dW[r * 512 + c];
    dt[(size_t)token * 512 + c] = (acc > 20.f) ? acc : log1pf(__expf(acc));
  }
}

// ---------------- fused chunked scan (one block per channel) ----------------
__global__ __launch_bounds__(256) void scan_k(
    const float* __restrict__ dt, const float* __restrict__ ucv, const float* __restrict__ xd,
    const float* __restrict__ zbuf, const float* __restrict__ A_log, const float* __restrict__ D_p,
    _Float16* __restrict__ gout) {
  __shared__ float Ps[16][17], Hs[16][17], Hi[16][17];
  int ch = blockIdx.x;
  int b = ch >> 9, d = ch & 511;
  int t = threadIdx.x;
  int c = t >> 4, n = t & 15;
  float An = -__expf(A_log[d * 16 + n]);
  float P = 1.f, h = 0.f;
  int t0 = b * LSEQ + c * 32;
  for (int tt = 0; tt < 32; tt++) {
    int token = t0 + tt;
    float dtv = dt[(size_t)token * 512 + d];
    float uv = ucv[(size_t)token * 512 + d];
    float Bn = xd[(size_t)token * 48 + 16 + n];
    float dA = __expf(dtv * An);
    P *= dA;
    h = dA * h + dtv * uv * Bn;
  }
  Ps[c][n] = P; Hs[c][n] = h;
  __syncthreads();
  if (t < 16) {
    float hr = 0.f;
    for (int cc = 0; cc < 16; cc++) { Hi[cc][t] = hr; hr = Ps[cc][t] * hr + Hs[cc][t]; }
  }
  __syncthreads();
  h = Hi[c][n];
  float Dd = D_p[d];
  for (int tt = 0; tt < 32; tt++) {
    int token = t0 + tt;
    float dtv = dt[(size_t)token * 512 + d];
    float uv = ucv[(size_t)token * 512 + d];
    float Bn = xd[(size_t)token * 48 + 16 + n];
    float Cn = xd[(size_t)token * 48 + 32 + n];
    float dA = __expf(dtv * An);
    h = dA * h + dtv * uv * Bn;
    float y = h * Cn;
    y += __shfl_xor(y, 1, 64);
    y += __shfl_xor(y, 2, 64);
    y += __shfl_xor(y, 4, 64);
    y += __shfl_xor(y, 8, 64);
    if (n == 0) {
      float z = zbuf[(size_t)token * 1024 + 512 + d];
      gout[(size_t)token * 512 + d] = (_Float16)((y + uv * Dd) * siluf_(z));
    }
  }
}

// ---------------- SwiGLU for mlp: silu(g1)*g2 -> f16 ----------------
__global__ __launch_bounds__(256) void silumul_k(const float* __restrict__ big, _Float16* __restrict__ out) {
  int i = blockIdx.x * 256 + threadIdx.x; // BL*256
  int token = i >> 8, j = i & 255;
  float g1 = big[(size_t)token * 512 + j];
  float g2 = big[(size_t)token * 512 + 256 + j];
  out[i] = (_Float16)(siluf_(g1) * g2);
}

// ---------------- head: 6 wide kernels ----------------
__global__ __launch_bounds__(256) void lnf_k(const float* __restrict__ h, const float* __restrict__ nfw,
                                             const float* __restrict__ nfb, float* __restrict__ f) {
  __shared__ float red[4];
  int b = blockIdx.x, t = threadIdx.x;
  int lane = t & 63, wid = t >> 6;
  float v = h[((size_t)b * LSEQ + (LSEQ - 1)) * DMOD + t];
  float s = v;
#pragma unroll
  for (int o = 32; o; o >>= 1) s += __shfl_xor(s, o, 64);
  if (lane == 0) red[wid] = s;
  __syncthreads();
  float mu = (red[0] + red[1] + red[2] + red[3]) * (1.f / 256.f);
  float dv = v - mu;
  s = dv * dv;
#pragma unroll
  for (int o = 32; o; o >>= 1) s += __shfl_xor(s, o, 64);
  __syncthreads();
  if (lane == 0) red[wid] = s;
  __syncthreads();
  float var = (red[0] + red[1] + red[2] + red[3]) * (1.f / 256.f);
  f[b * 256 + t] = dv * rsqrtf(var + 1e-5f) * nfw[t] + nfb[t];
}

__global__ __launch_bounds__(256) void hgemm1_k(const float* __restrict__ f,
    const float* vW1, const float* vb1, const float* aW1, const float* ab1,
    float* __restrict__ a1) {
  int cb = blockIdx.x, b = blockIdx.y, p = blockIdx.z;
  const float* W1 = p ? aW1 : vW1;
  const float* b1 = p ? ab1 : vb1;
  __shared__ float fs[256];
  int t = threadIdx.x;
  fs[t] = f[b * 256 + t];
  __syncthreads();
  int col = cb * 256 + t;
  float acc = b1[col];
#pragma unroll 4
  for (int k = 0; k < 256; k++) acc += fs[k] * W1[k * 512 + col];
  a1[((b * 2 + p) * 512) + col] = acc;
}

__global__ __launch_bounds__(512) void hln1_k(const float* __restrict__ a1,
    const float* vl1w, const float* vl1b, const float* al1w, const float* al1b,
    float* __restrict__ t1) {
  __shared__ float red[8];
  int b = blockIdx.x, p = blockIdx.y, t = threadIdx.x;
  const float* lw = p ? al1w : vl1w;
  const float* lb = p ? al1b : vl1b;
  int lane = t & 63, wid = t >> 6;
  int idx = (b * 2 + p) * 512 + t;
  float v = a1[idx];
  float s = v;
#pragma unroll
  for (int o = 32; o; o >>= 1) s += __shfl_xor(s, o, 64);
  if (lane == 0) red[wid] = s;
  __syncthreads();
  float S = 0.f;
#pragma unroll
  for (int k = 0; k < 8; k++) S += red[k];
  float mu = S * (1.f / 512.f);
  float dv = v - mu;
  s = dv * dv;
#pragma unroll
  for (int o = 32; o; o >>= 1) s += __shfl_xor(s, o, 64);
  __syncthreads();
  if (lane == 0) red[wid] = s;
  __syncthreads();
  S = 0.f;
#pragma unroll
  for (int k = 0; k < 8; k++) S += red[k];
  float var = S * (1.f / 512.f);
  t1[idx] = fmaxf(dv * rsqrtf(var + 1e-5f) * lw[t] + lb[t], 0.f);
}

__global__ __launch_bounds__(256) void hgemm2_k(const float* __restrict__ t1,
    const float* vW2, const float* vb2, const float* aW2, const float* ab2,
    float* __restrict__ a2) {
  int b = blockIdx.x, p = blockIdx.y;
  const float* W2 = p ? aW2 : vW2;
  const float* b2 = p ? ab2 : vb2;
  __shared__ float ts[512];
  int t = threadIdx.x;
  ts[t] = t1[(b * 2 + p) * 512 + t];
  ts[256 + t] = t1[(b * 2 + p) * 512 + 256 + t];
  __syncthreads();
  float acc = b2[t];
#pragma unroll 4
  for (int k = 0; k < 512; k++) acc += ts[k] * W2[k * 256 + t];
  a2[(b * 2 + p) * 256 + t] = acc;
}

__global__ __launch_bounds__(256) void hln2_k(const float* __restrict__ a2,
    const float* vl2w, const float* vl2b, const float* al2w, const float* al2b,
    float* __restrict__ t2) {
  __shared__ float red[4];
  int b = blockIdx.x, p = blockIdx.y, t = threadIdx.x;
  const float* lw = p ? al2w : vl2w;
  const float* lb = p ? al2b : vl2b;
  int lane = t & 63, wid = t >> 6;
  int idx = (b * 2 + p) * 256 + t;
  float v = a2[idx];
  float s = v;
#pragma unroll
  for (int o = 32; o; o >>= 1) s += __shfl_xor(s, o, 64);
  if (lane == 0) red[wid] = s;
  __syncthreads();
  float mu = (red[0] + red[1] + red[2] + red[3]) * (1.f / 256.f);
  float dv = v - mu;
  s = dv * dv;
#pragma unroll
  for (int o = 32; o; o >>= 1) s += __shfl_xor(s, o, 64);
  __syncthreads();
  if (lane == 0) red[wid] = s;
  __syncthreads();
  float var = (red[0] + red[1] + red[2] + red[3]) * (1.f / 256.f);
  t2[idx] = fmaxf(dv * rsqrtf(var + 1e-5f) * lw[t] + lb[t], 0.f);
}

__global__ __launch_bounds__(256) void hfinal_k(const float* __restrict__ t2,
    const float* vW3, const float* vb3, const float* aW3, const float* ab3,
    float* __restrict__ q) {
  __shared__ float a3s[24];
  int t = threadIdx.x;
  int g = t >> 3, ln8 = t & 7;
  if (g < 24) {
    int b = g / 6, r = g - b * 6;
    int p = r ? 1 : 0;
    int o = r ? r - 1 : 0;
    const float* W3 = p ? aW3 : vW3;
    const float* b3 = p ? ab3 : vb3;
    int nout = p ? 5 : 1;
    const float* t2r = t2 + (b * 2 + p) * 256;
    float acc = 0.f;
    for (int k = ln8; k < 256; k += 8) acc += t2r[k] * W3[k * nout + o];
    acc += __shfl_xor(acc, 1, 64);
    acc += __shfl_xor(acc, 2, 64);
    acc += __shfl_xor(acc, 4, 64);
    if (ln8 == 0) a3s[g] = acc + b3[o];
  }
  __syncthreads();
  if (t < 20) {
    int b = t / 5, a = t - b * 5;
    float val = a3s[b * 6];
    float m = 0.f;
#pragma unroll
    for (int j = 0; j < 5; j++) m += a3s[b * 6 + 1 + j];
    m *= 0.2f;
    q[b * 5 + a] = val + a3s[b * 6 + 1 + a] - m;
  }
}

extern "C" void kernel_launch(void* const* d_in, const int* in_sizes, int n_in,
                              void* d_out, int out_size, void* d_ws, size_t ws_size,
                              hipStream_t stream) {
  const float* src = (const float*)d_in[0];
  const float* tau = (const float*)d_in[1];
  const float* dain_Wm = (const float*)d_in[2];
  const float* dain_Ws = (const float*)d_in[3];
  const float* dain_Wg = (const float*)d_in[4];
  const float* dain_bg = (const float*)d_in[5];
  const float* memb_W = (const float*)d_in[6];
  const float* memb_b = (const float*)d_in[7];
  const float* t_w0 = (const float*)d_in[8];
  const float* t_b0 = (const float*)d_in[9];
  const float* t_w = (const float*)d_in[10];
  const float* t_b = (const float*)d_in[11];
  const float* tproj_W = (const float*)d_in[12];
  const float* tproj_b = (const float*)d_in[13];
  const float* ffn_W1 = (const float*)d_in[14];
  const float* ffn_b1 = (const float*)d_in[15];
  const float* ffn_W2 = (const float*)d_in[16];
  const float* ffn_b2 = (const float*)d_in[17];
  const float* n1_w = (const float*)d_in[18];
  const float* n1_b = (const float*)d_in[19];
  const float* inproj_W = (const float*)d_in[20];
  const float* conv_w = (const float*)d_in[21];
  const float* conv_b = (const float*)d_in[22];
  const float* xproj_W = (const float*)d_in[23];
  const float* dtproj_W = (const float*)d_in[24];
  const float* dt_bias = (const float*)d_in[25];
  const float* A_log = (const float*)d_in[26];
  const float* D_p = (const float*)d_in[27];
  const float* outproj_W = (const float*)d_in[28];
  const float* n2_w = (const float*)d_in[29];
  const float* n2_b = (const float*)d_in[30];
  const float* mlp_W1 = (const float*)d_in[31];
  const float* mlp_W2 = (const float*)d_in[32];
  const float* nf_w = (const float*)d_in[33];
  const float* nf_b = (const float*)d_in[34];
  const float* vW1 = (const float*)d_in[35]; const float* vb1 = (const float*)d_in[36];
  const float* vl1w = (const float*)d_in[37]; const float* vl1b = (const float*)d_in[38];
  const float* vW2 = (const float*)d_in[39]; const float* vb2 = (const float*)d_in[40];
  const float* vl2w = (const float*)d_in[41]; const float* vl2b = (const float*)d_in[42];
  const float* vW3 = (const float*)d_in[43]; const float* vb3 = (const float*)d_in[44];
  const float* aW1 = (const float*)d_in[45]; const float* ab1 = (const float*)d_in[46];
  const float* al1w = (const float*)d_in[47]; const float* al1b = (const float*)d_in[48];
  const float* aW2 = (const float*)d_in[49]; const float* ab2 = (const float*)d_in[50];
  const float* al2w = (const float*)d_in[51]; const float* al2b = (const float*)d_in[52];
  const float* aW3 = (const float*)d_in[53]; const float* ab3 = (const float*)d_in[54];
  float* out = (float*)d_out;

  float* ws = (float*)d_ws;
  float* dstats = ws;                      // 256
  float* h    = dstats + 256;              // BL*256
  float* big  = h + (size_t)BL * DMOD;     // BL*1408
  float* ucv  = big + (size_t)BL * 1408;   // BL*512
  float* xd   = ucv + (size_t)BL * DIN;    // BL*48
  float* dt   = xd + (size_t)BL * 48;      // BL*512
  float* fh   = dt + (size_t)BL * DIN;     // 1024
  float* a1   = fh + 1024;                 // 4096
  float* t1   = a1 + 4096;                 // 4096
  float* a2   = t1 + 4096;                 // 2048
  float* t2   = a2 + 2048;                 // 2048
  float* fp_end = t2 + 2048;
  _Float16* h_hf    = (_Float16*)fp_end;            // BL*256
  _Float16* hn_hf   = h_hf + (size_t)BL * DMOD;     // BL*256
  _Float16* mid_hf  = hn_hf + (size_t)BL * DMOD;    // BL*704
  _Float16* gout_hf = mid_hf + (size_t)BL * 704;    // BL*512
  _Float16* ffn1T   = gout_hf + (size_t)BL * DIN;   // 1408*256
  _Float16* ffn2T   = ffn1T + (size_t)1408 * 256;   // 256*704
  _Float16* inprojT = ffn2T + (size_t)256 * 704;    // 8*1024*256
  _Float16* outprojT = inprojT + (size_t)8 * 1024 * 256;
  _Float16* mlp1T   = outprojT + (size_t)8 * 256 * 512;
  _Float16* mlp2T   = mlp1T + (size_t)8 * 512 * 256;

  convall_k<<<20544, 256, 0, stream>>>(ffn_W1, ffn_W2, inproj_W, outproj_W, mlp_W1, mlp_W2,
                                       ffn1T, ffn2T, inprojT, outprojT, mlp1T, mlp2T);
  dain_k<<<1, 1024, 0, stream>>>(src, dain_Wm, dain_Ws, dain_Wg, dain_bg, dstats);
  embed_k<<<BL, 256, 0, stream>>>(src, tau, dstats, memb_W, memb_b, t_w0, t_b0, t_w, t_b, tproj_W, tproj_b, h_hf);
  gemm_hf_k<<<dim3(22, 32), 256, 0, stream>>>(h_hf, ffn1T, ffn_b1, big, BL, 1364, 256, 1364, 0);
  glugelu_k<<<BL * 704 / 256, 256, 0, stream>>>(big, mid_hf);
  gemm_hf_k<<<dim3(4, 32), 256, 0, stream>>>(mid_hf, ffn2T, ffn_b2, h, BL, 256, 704, 256, 0);

  for (int i = 0; i < 8; i++) {
    ln4_k<<<BL / 4, 256, 0, stream>>>(h, n1_w + i * 256, n1_b + i * 256, hn_hf);
    gemm_hf_k<<<dim3(16, 32), 256, 0, stream>>>(hn_hf, inprojT + (size_t)i * 1024 * 256, nullptr, big,
                                                BL, 1024, 256, 1024, 0);
    convxdt_k<<<BL, 128, 0, stream>>>(big, conv_w + (size_t)i * 512 * 4, conv_b + i * 512,
                                      xproj_W + (size_t)i * 512 * 48, dtproj_W + (size_t)i * 16 * 512,
                                      dt_bias + i * 512, ucv, xd, dt);
    scan_k<<<NCH, 256, 0, stream>>>(dt, ucv, xd, big, A_log + (size_t)i * 512 * 16, D_p + i * 512, gout_hf);
    gemm_hf_k<<<dim3(4, 32), 256, 0, stream>>>(gout_hf, outprojT + (size_t)i * 256 * 512, nullptr, h,
                                               BL, 256, 512, 256, 1);
    ln4_k<<<BL / 4, 256, 0, stream>>>(h, n2_w + i * 256, n2_b + i * 256, hn_hf);
    gemm_hf_k<<<dim3(8, 32), 256, 0, stream>>>(hn_hf, mlp1T + (size_t)i * 512 * 256, nullptr, big,
                                               BL, 512, 256, 512, 0);
    silumul_k<<<BL, 256, 0, stream>>>(big, mid_hf);
    gemm_hf_k<<<dim3(4, 32), 256, 0, stream>>>(mid_hf, mlp2T + (size_t)i * 256 * 256, nullptr, h,
                                               BL, 256, 256, 256, 1);
  }

  lnf_k<<<NB, 256, 0, stream>>>(h, nf_w, nf_b, fh);
  hgemm1_k<<<dim3(2, 4, 2), 256, 0, stream>>>(fh, vW1, vb1, aW1, ab1, a1);
  hln1_k<<<dim3(4, 2), 512, 0, stream>>>(a1, vl1w, vl1b, al1w, al1b, t1);
  hgemm2_k<<<dim3(4, 2), 256, 0, stream>>>(t1, vW2, vb2, aW2, ab2, a2);
  hln2_k<<<dim3(4, 2), 256, 0, stream>>>(a2, vl2w, vl2b, al2w, al2b, t2);
  hfinal_k<<<1, 256, 0, stream>>>(t2, vW3, vb3, aW3, ab3, out);
  (void)in_sizes; (void)n_in; (void)out_size; (void)ws_size;
}

// Round 9
// 1115.354 us; speedup vs baseline: 1.2776x; 1.1274x over previous
//
#include <hip/hip_runtime.h>
#include <math.h>

// Model constants
#define BL   2048   // B*L = 4*512
#define LSEQ 512
#define NB   4
#define DMOD 256
#define DIN  512
#define NCH  (NB * DIN)

typedef __attribute__((ext_vector_type(4))) float f32x4;
typedef __attribute__((ext_vector_type(8))) _Float16 f16x8;
typedef __attribute__((ext_vector_type(4))) _Float16 f16x4;

__device__ __forceinline__ float sigmoidf_(float x) { return 1.f / (1.f + __expf(-x)); }
__device__ __forceinline__ float siluf_(float x) { return x / (1.f + __expf(-x)); }

// ---------------- DAIN stats (single block) ----------------
__global__ __launch_bounds__(1024) void dain_k(
    const float* __restrict__ src, const float* __restrict__ Wm,
    const float* __restrict__ Ws, const float* __restrict__ Wg,
    const float* __restrict__ bg, float* __restrict__ stats) {
  __shared__ float part[1024];
  __shared__ float avg_s[128], sub_s[128], std_s[128], mn_s[128], inv_s[128];
  int tid = threadIdx.x;
  int p = tid >> 3, j = tid & 7;
  int b = p >> 5, f = p & 31;
  float s = 0.f;
  for (int l = j * 64; l < j * 64 + 64; ++l) s += src[((size_t)b * LSEQ + l) * 32 + f];
  part[tid] = s;
  __syncthreads();
  if (tid < 128) { float a = 0; for (int k = 0; k < 8; k++) a += part[tid * 8 + k]; avg_s[tid] = a * (1.f / 512.f); }
  __syncthreads();
  if (tid < 128) {
    int bb = tid >> 5, ff = tid & 31;
    float a = 0; for (int g = 0; g < 32; g++) a += avg_s[bb * 32 + g] * Wm[ff * 32 + g];
    sub_s[tid] = a;
  }
  __syncthreads();
  float sub = sub_s[p];
  s = 0.f;
  for (int l = j * 64; l < j * 64 + 64; ++l) {
    float v = src[((size_t)b * LSEQ + l) * 32 + f] - sub; s += v * v;
  }
  part[tid] = s;
  __syncthreads();
  if (tid < 128) { float a = 0; for (int k = 0; k < 8; k++) a += part[tid * 8 + k]; std_s[tid] = sqrtf(a * (1.f / 512.f)); }
  __syncthreads();
  if (tid < 128) {
    int bb = tid >> 5, ff = tid & 31;
    float a = 0; for (int g = 0; g < 32; g++) a += std_s[bb * 32 + g] * Ws[ff * 32 + g];
    if (a <= 1e-8f) a = 1.f;
    inv_s[tid] = 1.f / a;
    mn_s[tid] = (avg_s[tid] - sub_s[tid]) / a;
  }
  __syncthreads();
  if (tid < 128) {
    int bb = tid >> 5, ff = tid & 31;
    float a = bg[ff]; for (int g = 0; g < 32; g++) a += mn_s[bb * 32 + g] * Wg[ff * 32 + g];
    float gate = sigmoidf_(a);
    float scl = gate * inv_s[tid];
    stats[tid] = scl;
    stats[128 + tid] = sub_s[tid] * scl;
  }
}

// ---------------- embed -> h_hf (f16) ----------------
__global__ __launch_bounds__(256) void embed_k(
    const float* __restrict__ src, const float* __restrict__ tau,
    const float* __restrict__ stats, const float* __restrict__ membW,
    const float* __restrict__ membB, const float* __restrict__ tw0,
    const float* __restrict__ tb0, const float* __restrict__ tw,
    const float* __restrict__ tb, const float* __restrict__ tprojW,
    const float* __restrict__ tprojB, _Float16* __restrict__ h_hf) {
  int token = blockIdx.x;
  int b = token >> 9;
  int t = threadIdx.x;
  __shared__ float xs[32], te[32];
  if (t < 32) {
    float scl = stats[b * 32 + t], shf = stats[128 + b * 32 + t];
    xs[t] = src[(size_t)token * 32 + t] * scl - shf;
  } else if (t < 64) {
    int j = t - 32;
    const float* tr = tau + (size_t)token * 8;
    float a;
    if (j < 31) { a = tb[j]; for (int k = 0; k < 8; k++) a += tr[k] * tw[k * 31 + j]; a = sinf(a); }
    else        { a = tb0[0]; for (int k = 0; k < 8; k++) a += tr[k] * tw0[k]; }
    te[j] = a;
  }
  __syncthreads();
  float acc;
  if (t < 128) {
    acc = membB[t];
    for (int f = 0; f < 32; f++) acc += xs[f] * membW[f * 128 + t];
  } else {
    int d = t - 128;
    acc = tprojB[d];
    for (int j = 0; j < 32; j++) acc += te[j] * tprojW[j * 128 + d];
  }
  h_hf[(size_t)token * DMOD + t] = (_Float16)acc;
}

// ---------------- all weight transpose-converts in ONE launch ----------------
__device__ __forceinline__ void convT_one(const float* __restrict__ W, _Float16* __restrict__ WT,
                                          int K, int N, int Kout, int Nout, int idx) {
  int per = Nout * Kout;
  int l = idx / per; int rem = idx - l * per;
  int n = rem / Kout; int k = rem - n * Kout;
  const float* Wl = W + (size_t)l * K * N;
  float v = (k < K && n < N) ? Wl[(size_t)k * N + n] : 0.f;
  WT[(size_t)l * per + rem] = (_Float16)v;
}

__global__ __launch_bounds__(256) void convall_k(
    const float* ffn_W1, const float* ffn_W2, const float* inproj_W,
    const float* outproj_W, const float* mlp_W1, const float* mlp_W2,
    _Float16* ffn1T, _Float16* ffn2T, _Float16* inprojT,
    _Float16* outprojT, _Float16* mlp1T, _Float16* mlp2T) {
  int g = blockIdx.x, t = threadIdx.x;
  if (g < 1408)            convT_one(ffn_W1, ffn1T, 256, 1364, 256, 1408, g * 256 + t);
  else if (g < 2112)       convT_one(ffn_W2, ffn2T, 682, 256, 704, 256, (g - 1408) * 256 + t);
  else if (g < 10304)      convT_one(inproj_W, inprojT, 256, 1024, 256, 1024, (g - 2112) * 256 + t);
  else if (g < 14400)      convT_one(outproj_W, outprojT, 512, 256, 512, 256, (g - 10304) * 256 + t);
  else if (g < 18496)      convT_one(mlp_W1, mlp1T, 256, 512, 256, 512, (g - 14400) * 256 + t);
  else                     convT_one(mlp_W2, mlp2T, 256, 256, 256, 256, (g - 18496) * 256 + t);
}

// ---------------- plain f16 MFMA GEMM 64x64 tile (A stride == K) ----------------
__global__ __launch_bounds__(256) void gemm_hf_k(
    const _Float16* __restrict__ A, const _Float16* __restrict__ WT,
    const float* __restrict__ bias, float* __restrict__ C,
    int M, int Nstore, int K, int ldc, int flags) {
  __shared__ _Float16 As[64][40];
  __shared__ _Float16 Bs[64][40];
  int bm = blockIdx.y * 64, bn = blockIdx.x * 64;
  int t = threadIdx.x;
  int w = t >> 6, l = t & 63;
  int wm = w >> 1, wn = w & 1;
  int srow = t >> 2, sk = (t & 3) * 8;
  f32x4 acc[2][2] = {};
  int lr = l & 15, lk = (l >> 4) * 8;
  for (int k0 = 0; k0 < K; k0 += 32) {
    *(uint4*)&As[srow][sk] = *(const uint4*)&A[(size_t)(bm + srow) * K + k0 + sk];
    *(uint4*)&Bs[srow][sk] = *(const uint4*)&WT[(size_t)(bn + srow) * K + k0 + sk];
    __syncthreads();
    f16x8 a0 = *(const f16x8*)&As[wm * 32 + lr][lk];
    f16x8 a1 = *(const f16x8*)&As[wm * 32 + 16 + lr][lk];
    f16x8 b0 = *(const f16x8*)&Bs[wn * 32 + lr][lk];
    f16x8 b1 = *(const f16x8*)&Bs[wn * 32 + 16 + lr][lk];
    acc[0][0] = __builtin_amdgcn_mfma_f32_16x16x32_f16(a0, b0, acc[0][0], 0, 0, 0);
    acc[0][1] = __builtin_amdgcn_mfma_f32_16x16x32_f16(a0, b1, acc[0][1], 0, 0, 0);
    acc[1][0] = __builtin_amdgcn_mfma_f32_16x16x32_f16(a1, b0, acc[1][0], 0, 0, 0);
    acc[1][1] = __builtin_amdgcn_mfma_f32_16x16x32_f16(a1, b1, acc[1][1], 0, 0, 0);
    __syncthreads();
  }
  int lq = l >> 4;
#pragma unroll
  for (int i = 0; i < 2; i++) {
#pragma unroll
    for (int j = 0; j < 2; j++) {
      int col = bn + wn * 32 + j * 16 + lr;
      if (col >= Nstore) continue;
      float bv = bias ? bias[col] : 0.f;
#pragma unroll
      for (int r = 0; r < 4; r++) {
        int row = bm + wm * 32 + i * 16 + lq * 4 + r;
        float v = acc[i][j][r] + bv;
        size_t idx = (size_t)row * ldc + col;
        if (flags & 1) v += C[idx];
        C[idx] = v;
      }
    }
  }
}

// ---------------- FFN GLU (a * gelu_exact(g)) -> f16 padded to 704 ----------------
__global__ __launch_bounds__(256) void glugelu_k(const float* __restrict__ big, _Float16* __restrict__ out) {
  int i = blockIdx.x * 256 + threadIdx.x; // BL*704
  int token = i / 704, j = i - token * 704;
  float r = 0.f;
  if (j < 682) {
    float a = big[(size_t)token * 1364 + j];
    float g = big[(size_t)token * 1364 + 682 + j];
    r = a * 0.5f * g * (1.f + erff(g * 0.70710678118654752f));
  }
  out[i] = (_Float16)r;
}

// ---------------- LayerNorm, 4 rows/block (wave per row) -> f16 ----------------
__global__ __launch_bounds__(256) void ln4_k(const float* __restrict__ x, const float* __restrict__ w,
                                             const float* __restrict__ b, _Float16* __restrict__ out) {
  int row = blockIdx.x * 4 + (threadIdx.x >> 6), lane = threadIdx.x & 63;
  const float* rp = x + (size_t)row * 256;
  float4 v = *(const float4*)&rp[lane * 4];
  float s = v.x + v.y + v.z + v.w;
  float ss = v.x * v.x + v.y * v.y + v.z * v.z + v.w * v.w;
#pragma unroll
  for (int o = 32; o; o >>= 1) { s += __shfl_xor(s, o, 64); ss += __shfl_xor(ss, o, 64); }
  float mu = s * (1.f / 256.f);
  float var = ss * (1.f / 256.f) - mu * mu;
  float rs = rsqrtf(var + 1e-5f);
  float4 wv = *(const float4*)&w[lane * 4];
  float4 bv = *(const float4*)&b[lane * 4];
  f16x4 o4;
  o4[0] = (_Float16)((v.x - mu) * rs * wv.x + bv.x);
  o4[1] = (_Float16)((v.y - mu) * rs * wv.y + bv.y);
  o4[2] = (_Float16)((v.z - mu) * rs * wv.z + bv.z);
  o4[3] = (_Float16)((v.w - mu) * rs * wv.w + bv.w);
  *(f16x4*)&out[(size_t)row * 256 + lane * 4] = o4;
}

// ---------------- fused conv4+silu -> xproj -> dtproj+softplus ----------------
// XCD-swizzled: token = (bid&7)*256 + bid>>3 so neighboring tokens (sharing conv
// input rows) land on the same XCD's L2.
__global__ __launch_bounds__(128) void convxdt_k(
    const float* __restrict__ big, const float* __restrict__ cw, const float* __restrict__ cb,
    const float* __restrict__ xW, const float* __restrict__ dW, const float* __restrict__ dbias,
    float* __restrict__ ucv, float* __restrict__ xd, float* __restrict__ dt) {
  __shared__ float us[512];
  __shared__ float xs[48];
  int token = ((blockIdx.x & 7) << 8) | (blockIdx.x >> 3);
  int b = token >> 9, l = token & 511;
  int t = threadIdx.x;
  for (int c = t; c < 512; c += 128) {
    float acc = cb[c];
#pragma unroll
    for (int k = 0; k < 4; k++) {
      int l2 = l - 3 + k;
      if (l2 >= 0) acc += big[((size_t)(b * LSEQ + l2)) * 1024 + c] * cw[c * 4 + k];
    }
    float u = siluf_(acc);
    us[c] = u;
    ucv[(size_t)token * 512 + c] = u;
  }
  __syncthreads();
  float part = 0.f;
  int j = t >> 1, p = t & 1;
  if (t < 96) {
    for (int c = p * 256; c < p * 256 + 256; c++) part += us[c] * xW[c * 48 + j];
  }
  part += __shfl_xor(part, 1, 64);
  if (t < 96 && p == 0) {
    xs[j] = part;
    xd[(size_t)token * 48 + j] = part;
  }
  __syncthreads();
  for (int c = t; c < 512; c += 128) {
    float acc = dbias[c];
#pragma unroll
    for (int r = 0; r < 16; r++) acc += xs[r] * dW[r * 512 + c];
    dt[(size_t)token * 512 + c] = (acc > 20.f) ? acc : log1pf(__expf(acc));
  }
}

// ---------------- fused chunked scan (one block per channel) ----------------
// XCD-swizzled: ch = (bid&7)*256 + bid>>3 — each XCD owns a contiguous
// 256-channel slice, so the 64B lines of dt/ucv/zbuf (16 channels/line) are
// consumed entirely within one XCD's L2 (slice ~2MB < 4MB L2).
__global__ __launch_bounds__(256) void scan_k(
    const float* __restrict__ dt, const float* __restrict__ ucv, const float* __restrict__ xd,
    const float* __restrict__ zbuf, const float* __restrict__ A_log, const float* __restrict__ D_p,
    _Float16* __restrict__ gout) {
  __shared__ float Ps[16][17], Hs[16][17], Hi[16][17];
  int ch = ((blockIdx.x & 7) << 8) | (blockIdx.x >> 3);
  int b = ch >> 9, d = ch & 511;
  int t = threadIdx.x;
  int c = t >> 4, n = t & 15;
  float An = -__expf(A_log[d * 16 + n]);
  float P = 1.f, h = 0.f;
  int t0 = b * LSEQ + c * 32;
  for (int tt = 0; tt < 32; tt++) {
    int token = t0 + tt;
    float dtv = dt[(size_t)token * 512 + d];
    float uv = ucv[(size_t)token * 512 + d];
    float Bn = xd[(size_t)token * 48 + 16 + n];
    float dA = __expf(dtv * An);
    P *= dA;
    h = dA * h + dtv * uv * Bn;
  }
  Ps[c][n] = P; Hs[c][n] = h;
  __syncthreads();
  if (t < 16) {
    float hr = 0.f;
    for (int cc = 0; cc < 16; cc++) { Hi[cc][t] = hr; hr = Ps[cc][t] * hr + Hs[cc][t]; }
  }
  __syncthreads();
  h = Hi[c][n];
  float Dd = D_p[d];
  for (int tt = 0; tt < 32; tt++) {
    int token = t0 + tt;
    float dtv = dt[(size_t)token * 512 + d];
    float uv = ucv[(size_t)token * 512 + d];
    float Bn = xd[(size_t)token * 48 + 16 + n];
    float Cn = xd[(size_t)token * 48 + 32 + n];
    float dA = __expf(dtv * An);
    h = dA * h + dtv * uv * Bn;
    float y = h * Cn;
    y += __shfl_xor(y, 1, 64);
    y += __shfl_xor(y, 2, 64);
    y += __shfl_xor(y, 4, 64);
    y += __shfl_xor(y, 8, 64);
    if (n == 0) {
      float z = zbuf[(size_t)token * 1024 + 512 + d];
      gout[(size_t)token * 512 + d] = (_Float16)((y + uv * Dd) * siluf_(z));
    }
  }
}

// ---------------- SwiGLU for mlp: silu(g1)*g2 -> f16 ----------------
__global__ __launch_bounds__(256) void silumul_k(const float* __restrict__ big, _Float16* __restrict__ out) {
  int i = blockIdx.x * 256 + threadIdx.x; // BL*256
  int token = i >> 8, j = i & 255;
  float g1 = big[(size_t)token * 512 + j];
  float g2 = big[(size_t)token * 512 + 256 + j];
  out[i] = (_Float16)(siluf_(g1) * g2);
}

// ---------------- head: 6 wide kernels ----------------
__global__ __launch_bounds__(256) void lnf_k(const float* __restrict__ h, const float* __restrict__ nfw,
                                             const float* __restrict__ nfb, float* __restrict__ f) {
  __shared__ float red[4];
  int b = blockIdx.x, t = threadIdx.x;
  int lane = t & 63, wid = t >> 6;
  float v = h[((size_t)b * LSEQ + (LSEQ - 1)) * DMOD + t];
  float s = v;
#pragma unroll
  for (int o = 32; o; o >>= 1) s += __shfl_xor(s, o, 64);
  if (lane == 0) red[wid] = s;
  __syncthreads();
  float mu = (red[0] + red[1] + red[2] + red[3]) * (1.f / 256.f);
  float dv = v - mu;
  s = dv * dv;
#pragma unroll
  for (int o = 32; o; o >>= 1) s += __shfl_xor(s, o, 64);
  __syncthreads();
  if (lane == 0) red[wid] = s;
  __syncthreads();
  float var = (red[0] + red[1] + red[2] + red[3]) * (1.f / 256.f);
  f[b * 256 + t] = dv * rsqrtf(var + 1e-5f) * nfw[t] + nfb[t];
}

__global__ __launch_bounds__(256) void hgemm1_k(const float* __restrict__ f,
    const float* vW1, const float* vb1, const float* aW1, const float* ab1,
    float* __restrict__ a1) {
  int cb = blockIdx.x, b = blockIdx.y, p = blockIdx.z;
  const float* W1 = p ? aW1 : vW1;
  const float* b1 = p ? ab1 : vb1;
  __shared__ float fs[256];
  int t = threadIdx.x;
  fs[t] = f[b * 256 + t];
  __syncthreads();
  int col = cb * 256 + t;
  float acc = b1[col];
#pragma unroll 4
  for (int k = 0; k < 256; k++) acc += fs[k] * W1[k * 512 + col];
  a1[((b * 2 + p) * 512) + col] = acc;
}

__global__ __launch_bounds__(512) void hln1_k(const float* __restrict__ a1,
    const float* vl1w, const float* vl1b, const float* al1w, const float* al1b,
    float* __restrict__ t1) {
  __shared__ float red[8];
  int b = blockIdx.x, p = blockIdx.y, t = threadIdx.x;
  const float* lw = p ? al1w : vl1w;
  const float* lb = p ? al1b : vl1b;
  int lane = t & 63, wid = t >> 6;
  int idx = (b * 2 + p) * 512 + t;
  float v = a1[idx];
  float s = v;
#pragma unroll
  for (int o = 32; o; o >>= 1) s += __shfl_xor(s, o, 64);
  if (lane == 0) red[wid] = s;
  __syncthreads();
  float S = 0.f;
#pragma unroll
  for (int k = 0; k < 8; k++) S += red[k];
  float mu = S * (1.f / 512.f);
  float dv = v - mu;
  s = dv * dv;
#pragma unroll
  for (int o = 32; o; o >>= 1) s += __shfl_xor(s, o, 64);
  __syncthreads();
  if (lane == 0) red[wid] = s;
  __syncthreads();
  S = 0.f;
#pragma unroll
  for (int k = 0; k < 8; k++) S += red[k];
  float var = S * (1.f / 512.f);
  t1[idx] = fmaxf(dv * rsqrtf(var + 1e-5f) * lw[t] + lb[t], 0.f);
}

__global__ __launch_bounds__(256) void hgemm2_k(const float* __restrict__ t1,
    const float* vW2, const float* vb2, const float* aW2, const float* ab2,
    float* __restrict__ a2) {
  int b = blockIdx.x, p = blockIdx.y;
  const float* W2 = p ? aW2 : vW2;
  const float* b2 = p ? ab2 : vb2;
  __shared__ float ts[512];
  int t = threadIdx.x;
  ts[t] = t1[(b * 2 + p) * 512 + t];
  ts[256 + t] = t1[(b * 2 + p) * 512 + 256 + t];
  __syncthreads();
  float acc = b2[t];
#pragma unroll 4
  for (int k = 0; k < 512; k++) acc += ts[k] * W2[k * 256 + t];
  a2[(b * 2 + p) * 256 + t] = acc;
}

__global__ __launch_bounds__(256) void hln2_k(const float* __restrict__ a2,
    const float* vl2w, const float* vl2b, const float* al2w, const float* al2b,
    float* __restrict__ t2) {
  __shared__ float red[4];
  int b = blockIdx.x, p = blockIdx.y, t = threadIdx.x;
  const float* lw = p ? al2w : vl2w;
  const float* lb = p ? al2b : vl2b;
  int lane = t & 63, wid = t >> 6;
  int idx = (b * 2 + p) * 256 + t;
  float v = a2[idx];
  float s = v;
#pragma unroll
  for (int o = 32; o; o >>= 1) s += __shfl_xor(s, o, 64);
  if (lane == 0) red[wid] = s;
  __syncthreads();
  float mu = (red[0] + red[1] + red[2] + red[3]) * (1.f / 256.f);
  float dv = v - mu;
  s = dv * dv;
#pragma unroll
  for (int o = 32; o; o >>= 1) s += __shfl_xor(s, o, 64);
  __syncthreads();
  if (lane == 0) red[wid] = s;
  __syncthreads();
  float var = (red[0] + red[1] + red[2] + red[3]) * (1.f / 256.f);
  t2[idx] = fmaxf(dv * rsqrtf(var + 1e-5f) * lw[t] + lb[t], 0.f);
}

__global__ __launch_bounds__(256) void hfinal_k(const float* __restrict__ t2,
    const float* vW3, const float* vb3, const float* aW3, const float* ab3,
    float* __restrict__ q) {
  __shared__ float a3s[24];
  int t = threadIdx.x;
  int g = t >> 3, ln8 = t & 7;
  if (g < 24) {
    int b = g / 6, r = g - b * 6;
    int p = r ? 1 : 0;
    int o = r ? r - 1 : 0;
    const float* W3 = p ? aW3 : vW3;
    const float* b3 = p ? ab3 : vb3;
    int nout = p ? 5 : 1;
    const float* t2r = t2 + (b * 2 + p) * 256;
    float acc = 0.f;
    for (int k = ln8; k < 256; k += 8) acc += t2r[k] * W3[k * nout + o];
    acc += __shfl_xor(acc, 1, 64);
    acc += __shfl_xor(acc, 2, 64);
    acc += __shfl_xor(acc, 4, 64);
    if (ln8 == 0) a3s[g] = acc + b3[o];
  }
  __syncthreads();
  if (t < 20) {
    int b = t / 5, a = t - b * 5;
    float val = a3s[b * 6];
    float m = 0.f;
#pragma unroll
    for (int j = 0; j < 5; j++) m += a3s[b * 6 + 1 + j];
    m *= 0.2f;
    q[b * 5 + a] = val + a3s[b * 6 + 1 + a] - m;
  }
}

extern "C" void kernel_launch(void* const* d_in, const int* in_sizes, int n_in,
                              void* d_out, int out_size, void* d_ws, size_t ws_size,
                              hipStream_t stream) {
  const float* src = (const float*)d_in[0];
  const float* tau = (const float*)d_in[1];
  const float* dain_Wm = (const float*)d_in[2];
  const float* dain_Ws = (const float*)d_in[3];
  const float* dain_Wg = (const float*)d_in[4];
  const float* dain_bg = (const float*)d_in[5];
  const float* memb_W = (const float*)d_in[6];
  const float* memb_b = (const float*)d_in[7];
  const float* t_w0 = (const float*)d_in[8];
  const float* t_b0 = (const float*)d_in[9];
  const float* t_w = (const float*)d_in[10];
  const float* t_b = (const float*)d_in[11];
  const float* tproj_W = (const float*)d_in[12];
  const float* tproj_b = (const float*)d_in[13];
  const float* ffn_W1 = (const float*)d_in[14];
  const float* ffn_b1 = (const float*)d_in[15];
  const float* ffn_W2 = (const float*)d_in[16];
  const float* ffn_b2 = (const float*)d_in[17];
  const float* n1_w = (const float*)d_in[18];
  const float* n1_b = (const float*)d_in[19];
  const float* inproj_W = (const float*)d_in[20];
  const float* conv_w = (const float*)d_in[21];
  const float* conv_b = (const float*)d_in[22];
  const float* xproj_W = (const float*)d_in[23];
  const float* dtproj_W = (const float*)d_in[24];
  const float* dt_bias = (const float*)d_in[25];
  const float* A_log = (const float*)d_in[26];
  const float* D_p = (const float*)d_in[27];
  const float* outproj_W = (const float*)d_in[28];
  const float* n2_w = (const float*)d_in[29];
  const float* n2_b = (const float*)d_in[30];
  const float* mlp_W1 = (const float*)d_in[31];
  const float* mlp_W2 = (const float*)d_in[32];
  const float* nf_w = (const float*)d_in[33];
  const float* nf_b = (const float*)d_in[34];
  const float* vW1 = (const float*)d_in[35]; const float* vb1 = (const float*)d_in[36];
  const float* vl1w = (const float*)d_in[37]; const float* vl1b = (const float*)d_in[38];
  const float* vW2 = (const float*)d_in[39]; const float* vb2 = (const float*)d_in[40];
  const float* vl2w = (const float*)d_in[41]; const float* vl2b = (const float*)d_in[42];
  const float* vW3 = (const float*)d_in[43]; const float* vb3 = (const float*)d_in[44];
  const float* aW1 = (const float*)d_in[45]; const float* ab1 = (const float*)d_in[46];
  const float* al1w = (const float*)d_in[47]; const float* al1b = (const float*)d_in[48];
  const float* aW2 = (const float*)d_in[49]; const float* ab2 = (const float*)d_in[50];
  const float* al2w = (const float*)d_in[51]; const float* al2b = (const float*)d_in[52];
  const float* aW3 = (const float*)d_in[53]; const float* ab3 = (const float*)d_in[54];
  float* out = (float*)d_out;

  float* ws = (float*)d_ws;
  float* dstats = ws;                      // 256
  float* h    = dstats + 256;              // BL*256
  float* big  = h + (size_t)BL * DMOD;     // BL*1408
  float* ucv  = big + (size_t)BL * 1408;   // BL*512
  float* xd   = ucv + (size_t)BL * DIN;    // BL*48
  float* dt   = xd + (size_t)BL * 48;      // BL*512
  float* fh   = dt + (size_t)BL * DIN;     // 1024
  float* a1   = fh + 1024;                 // 4096
  float* t1   = a1 + 4096;                 // 4096
  float* a2   = t1 + 4096;                 // 2048
  float* t2   = a2 + 2048;                 // 2048
  float* fp_end = t2 + 2048;
  _Float16* h_hf    = (_Float16*)fp_end;            // BL*256
  _Float16* hn_hf   = h_hf + (size_t)BL * DMOD;     // BL*256
  _Float16* mid_hf  = hn_hf + (size_t)BL * DMOD;    // BL*704
  _Float16* gout_hf = mid_hf + (size_t)BL * 704;    // BL*512
  _Float16* ffn1T   = gout_hf + (size_t)BL * DIN;   // 1408*256
  _Float16* ffn2T   = ffn1T + (size_t)1408 * 256;   // 256*704
  _Float16* inprojT = ffn2T + (size_t)256 * 704;    // 8*1024*256
  _Float16* outprojT = inprojT + (size_t)8 * 1024 * 256;
  _Float16* mlp1T   = outprojT + (size_t)8 * 256 * 512;
  _Float16* mlp2T   = mlp1T + (size_t)8 * 512 * 256;

  convall_k<<<20544, 256, 0, stream>>>(ffn_W1, ffn_W2, inproj_W, outproj_W, mlp_W1, mlp_W2,
                                       ffn1T, ffn2T, inprojT, outprojT, mlp1T, mlp2T);
  dain_k<<<1, 1024, 0, stream>>>(src, dain_Wm, dain_Ws, dain_Wg, dain_bg, dstats);
  embed_k<<<BL, 256, 0, stream>>>(src, tau, dstats, memb_W, memb_b, t_w0, t_b0, t_w, t_b, tproj_W, tproj_b, h_hf);
  gemm_hf_k<<<dim3(22, 32), 256, 0, stream>>>(h_hf, ffn1T, ffn_b1, big, BL, 1364, 256, 1364, 0);
  glugelu_k<<<BL * 704 / 256, 256, 0, stream>>>(big, mid_hf);
  gemm_hf_k<<<dim3(4, 32), 256, 0, stream>>>(mid_hf, ffn2T, ffn_b2, h, BL, 256, 704, 256, 0);

  for (int i = 0; i < 8; i++) {
    ln4_k<<<BL / 4, 256, 0, stream>>>(h, n1_w + i * 256, n1_b + i * 256, hn_hf);
    gemm_hf_k<<<dim3(16, 32), 256, 0, stream>>>(hn_hf, inprojT + (size_t)i * 1024 * 256, nullptr, big,
                                                BL, 1024, 256, 1024, 0);
    convxdt_k<<<BL, 128, 0, stream>>>(big, conv_w + (size_t)i * 512 * 4, conv_b + i * 512,
                                      xproj_W + (size_t)i * 512 * 48, dtproj_W + (size_t)i * 16 * 512,
                                      dt_bias + i * 512, ucv, xd, dt);
    scan_k<<<NCH, 256, 0, stream>>>(dt, ucv, xd, big, A_log + (size_t)i * 512 * 16, D_p + i * 512, gout_hf);
    gemm_hf_k<<<dim3(4, 32), 256, 0, stream>>>(gout_hf, outprojT + (size_t)i * 256 * 512, nullptr, h,
                                               BL, 256, 512, 256, 1);
    ln4_k<<<BL / 4, 256, 0, stream>>>(h, n2_w + i * 256, n2_b + i * 256, hn_hf);
    gemm_hf_k<<<dim3(8, 32), 256, 0, stream>>>(hn_hf, mlp1T + (size_t)i * 512 * 256, nullptr, big,
                                               BL, 512, 256, 512, 0);
    silumul_k<<<BL, 256, 0, stream>>>(big, mid_hf);
    gemm_hf_k<<<dim3(4, 32), 256, 0, stream>>>(mid_hf, mlp2T + (size_t)i * 256 * 256, nullptr, h,
                                               BL, 256, 256, 256, 1);
  }

  lnf_k<<<NB, 256, 0, stream>>>(h, nf_w, nf_b, fh);
  hgemm1_k<<<dim3(2, 4, 2), 256, 0, stream>>>(fh, vW1, vb1, aW1, ab1, a1);
  hln1_k<<<dim3(4, 2), 512, 0, stream>>>(a1, vl1w, vl1b, al1w, al1b, t1);
  hgemm2_k<<<dim3(4, 2), 256, 0, stream>>>(t1, vW2, vb2, aW2, ab2, a2);
  hln2_k<<<dim3(4, 2), 256, 0, stream>>>(a2, vl2w, vl2b, al2w, al2b, t2);
  hfinal_k<<<1, 256, 0, stream>>>(t2, vW3, vb3, aW3, ab3, out);
  (void)in_sizes; (void)n_in; (void)out_size; (void)ws_size;
}

// Round 10
// 1073.529 us; speedup vs baseline: 1.3274x; 1.0390x over previous
//
#include <hip/hip_runtime.h>
#include <math.h>

// Model constants
#define BL   2048   // B*L = 4*512
#define LSEQ 512
#define NB   4
#define DMOD 256
#define DIN  512
#define NCH  (NB * DIN)

typedef __attribute__((ext_vector_type(4))) float f32x4;
typedef __attribute__((ext_vector_type(8))) _Float16 f16x8;
typedef __attribute__((ext_vector_type(4))) _Float16 f16x4;

__device__ __forceinline__ float sigmoidf_(float x) { return 1.f / (1.f + __expf(-x)); }
__device__ __forceinline__ float siluf_(float x) { return x / (1.f + __expf(-x)); }

// ---------------- DAIN stats (single block) ----------------
__global__ __launch_bounds__(1024) void dain_k(
    const float* __restrict__ src, const float* __restrict__ Wm,
    const float* __restrict__ Ws, const float* __restrict__ Wg,
    const float* __restrict__ bg, float* __restrict__ stats) {
  __shared__ float part[1024];
  __shared__ float avg_s[128], sub_s[128], std_s[128], mn_s[128], inv_s[128];
  int tid = threadIdx.x;
  int p = tid >> 3, j = tid & 7;
  int b = p >> 5, f = p & 31;
  float s = 0.f;
  for (int l = j * 64; l < j * 64 + 64; ++l) s += src[((size_t)b * LSEQ + l) * 32 + f];
  part[tid] = s;
  __syncthreads();
  if (tid < 128) { float a = 0; for (int k = 0; k < 8; k++) a += part[tid * 8 + k]; avg_s[tid] = a * (1.f / 512.f); }
  __syncthreads();
  if (tid < 128) {
    int bb = tid >> 5, ff = tid & 31;
    float a = 0; for (int g = 0; g < 32; g++) a += avg_s[bb * 32 + g] * Wm[ff * 32 + g];
    sub_s[tid] = a;
  }
  __syncthreads();
  float sub = sub_s[p];
  s = 0.f;
  for (int l = j * 64; l < j * 64 + 64; ++l) {
    float v = src[((size_t)b * LSEQ + l) * 32 + f] - sub; s += v * v;
  }
  part[tid] = s;
  __syncthreads();
  if (tid < 128) { float a = 0; for (int k = 0; k < 8; k++) a += part[tid * 8 + k]; std_s[tid] = sqrtf(a * (1.f / 512.f)); }
  __syncthreads();
  if (tid < 128) {
    int bb = tid >> 5, ff = tid & 31;
    float a = 0; for (int g = 0; g < 32; g++) a += std_s[bb * 32 + g] * Ws[ff * 32 + g];
    if (a <= 1e-8f) a = 1.f;
    inv_s[tid] = 1.f / a;
    mn_s[tid] = (avg_s[tid] - sub_s[tid]) / a;
  }
  __syncthreads();
  if (tid < 128) {
    int bb = tid >> 5, ff = tid & 31;
    float a = bg[ff]; for (int g = 0; g < 32; g++) a += mn_s[bb * 32 + g] * Wg[ff * 32 + g];
    float gate = sigmoidf_(a);
    float scl = gate * inv_s[tid];
    stats[tid] = scl;
    stats[128 + tid] = sub_s[tid] * scl;
  }
}

// ---------------- embed -> h_hf (f16) ----------------
__global__ __launch_bounds__(256) void embed_k(
    const float* __restrict__ src, const float* __restrict__ tau,
    const float* __restrict__ stats, const float* __restrict__ membW,
    const float* __restrict__ membB, const float* __restrict__ tw0,
    const float* __restrict__ tb0, const float* __restrict__ tw,
    const float* __restrict__ tb, const float* __restrict__ tprojW,
    const float* __restrict__ tprojB, _Float16* __restrict__ h_hf) {
  int token = blockIdx.x;
  int b = token >> 9;
  int t = threadIdx.x;
  __shared__ float xs[32], te[32];
  if (t < 32) {
    float scl = stats[b * 32 + t], shf = stats[128 + b * 32 + t];
    xs[t] = src[(size_t)token * 32 + t] * scl - shf;
  } else if (t < 64) {
    int j = t - 32;
    const float* tr = tau + (size_t)token * 8;
    float a;
    if (j < 31) { a = tb[j]; for (int k = 0; k < 8; k++) a += tr[k] * tw[k * 31 + j]; a = sinf(a); }
    else        { a = tb0[0]; for (int k = 0; k < 8; k++) a += tr[k] * tw0[k]; }
    te[j] = a;
  }
  __syncthreads();
  float acc;
  if (t < 128) {
    acc = membB[t];
    for (int f = 0; f < 32; f++) acc += xs[f] * membW[f * 128 + t];
  } else {
    int d = t - 128;
    acc = tprojB[d];
    for (int j = 0; j < 32; j++) acc += te[j] * tprojW[j * 128 + d];
  }
  h_hf[(size_t)token * DMOD + t] = (_Float16)acc;
}

// ---------------- all weight transpose-converts in ONE launch ----------------
__device__ __forceinline__ void convT_one(const float* __restrict__ W, _Float16* __restrict__ WT,
                                          int K, int N, int Kout, int Nout, int idx) {
  int per = Nout * Kout;
  int l = idx / per; int rem = idx - l * per;
  int n = rem / Kout; int k = rem - n * Kout;
  const float* Wl = W + (size_t)l * K * N;
  float v = (k < K && n < N) ? Wl[(size_t)k * N + n] : 0.f;
  WT[(size_t)l * per + rem] = (_Float16)v;
}

__global__ __launch_bounds__(256) void convall_k(
    const float* ffn_W1, const float* ffn_W2, const float* inproj_W,
    const float* outproj_W, const float* mlp_W1, const float* mlp_W2,
    _Float16* ffn1T, _Float16* ffn2T, _Float16* inprojT,
    _Float16* outprojT, _Float16* mlp1T, _Float16* mlp2T) {
  int g = blockIdx.x, t = threadIdx.x;
  if (g < 1408)            convT_one(ffn_W1, ffn1T, 256, 1364, 256, 1408, g * 256 + t);
  else if (g < 2112)       convT_one(ffn_W2, ffn2T, 682, 256, 704, 256, (g - 1408) * 256 + t);
  else if (g < 10304)      convT_one(inproj_W, inprojT, 256, 1024, 256, 1024, (g - 2112) * 256 + t);
  else if (g < 14400)      convT_one(outproj_W, outprojT, 512, 256, 512, 256, (g - 10304) * 256 + t);
  else if (g < 18496)      convT_one(mlp_W1, mlp1T, 256, 512, 256, 512, (g - 14400) * 256 + t);
  else                     convT_one(mlp_W2, mlp2T, 256, 256, 256, 256, (g - 18496) * 256 + t);
}

// ---------------- plain f16 MFMA GEMM 64x64 tile (A stride == K) ----------------
__global__ __launch_bounds__(256) void gemm_hf_k(
    const _Float16* __restrict__ A, const _Float16* __restrict__ WT,
    const float* __restrict__ bias, float* __restrict__ C,
    int M, int Nstore, int K, int ldc, int flags) {
  __shared__ _Float16 As[64][40];
  __shared__ _Float16 Bs[64][40];
  int bm = blockIdx.y * 64, bn = blockIdx.x * 64;
  int t = threadIdx.x;
  int w = t >> 6, l = t & 63;
  int wm = w >> 1, wn = w & 1;
  int srow = t >> 2, sk = (t & 3) * 8;
  f32x4 acc[2][2] = {};
  int lr = l & 15, lk = (l >> 4) * 8;
  for (int k0 = 0; k0 < K; k0 += 32) {
    *(uint4*)&As[srow][sk] = *(const uint4*)&A[(size_t)(bm + srow) * K + k0 + sk];
    *(uint4*)&Bs[srow][sk] = *(const uint4*)&WT[(size_t)(bn + srow) * K + k0 + sk];
    __syncthreads();
    f16x8 a0 = *(const f16x8*)&As[wm * 32 + lr][lk];
    f16x8 a1 = *(const f16x8*)&As[wm * 32 + 16 + lr][lk];
    f16x8 b0 = *(const f16x8*)&Bs[wn * 32 + lr][lk];
    f16x8 b1 = *(const f16x8*)&Bs[wn * 32 + 16 + lr][lk];
    acc[0][0] = __builtin_amdgcn_mfma_f32_16x16x32_f16(a0, b0, acc[0][0], 0, 0, 0);
    acc[0][1] = __builtin_amdgcn_mfma_f32_16x16x32_f16(a0, b1, acc[0][1], 0, 0, 0);
    acc[1][0] = __builtin_amdgcn_mfma_f32_16x16x32_f16(a1, b0, acc[1][0], 0, 0, 0);
    acc[1][1] = __builtin_amdgcn_mfma_f32_16x16x32_f16(a1, b1, acc[1][1], 0, 0, 0);
    __syncthreads();
  }
  int lq = l >> 4;
#pragma unroll
  for (int i = 0; i < 2; i++) {
#pragma unroll
    for (int j = 0; j < 2; j++) {
      int col = bn + wn * 32 + j * 16 + lr;
      if (col >= Nstore) continue;
      float bv = bias ? bias[col] : 0.f;
#pragma unroll
      for (int r = 0; r < 4; r++) {
        int row = bm + wm * 32 + i * 16 + lq * 4 + r;
        float v = acc[i][j][r] + bv;
        size_t idx = (size_t)row * ldc + col;
        if (flags & 1) v += C[idx];
        C[idx] = v;
      }
    }
  }
}

// ---------------- FFN GLU (a * gelu_exact(g)) -> f16 padded to 704 ----------------
__global__ __launch_bounds__(256) void glugelu_k(const float* __restrict__ big, _Float16* __restrict__ out) {
  int i = blockIdx.x * 256 + threadIdx.x; // BL*704
  int token = i / 704, j = i - token * 704;
  float r = 0.f;
  if (j < 682) {
    float a = big[(size_t)token * 1364 + j];
    float g = big[(size_t)token * 1364 + 682 + j];
    r = a * 0.5f * g * (1.f + erff(g * 0.70710678118654752f));
  }
  out[i] = (_Float16)r;
}

// ---------------- LayerNorm, 4 rows/block (wave per row) -> f16 ----------------
__global__ __launch_bounds__(256) void ln4_k(const float* __restrict__ x, const float* __restrict__ w,
                                             const float* __restrict__ b, _Float16* __restrict__ out) {
  int row = blockIdx.x * 4 + (threadIdx.x >> 6), lane = threadIdx.x & 63;
  const float* rp = x + (size_t)row * 256;
  float4 v = *(const float4*)&rp[lane * 4];
  float s = v.x + v.y + v.z + v.w;
  float ss = v.x * v.x + v.y * v.y + v.z * v.z + v.w * v.w;
#pragma unroll
  for (int o = 32; o; o >>= 1) { s += __shfl_xor(s, o, 64); ss += __shfl_xor(ss, o, 64); }
  float mu = s * (1.f / 256.f);
  float var = ss * (1.f / 256.f) - mu * mu;
  float rs = rsqrtf(var + 1e-5f);
  float4 wv = *(const float4*)&w[lane * 4];
  float4 bv = *(const float4*)&b[lane * 4];
  f16x4 o4;
  o4[0] = (_Float16)((v.x - mu) * rs * wv.x + bv.x);
  o4[1] = (_Float16)((v.y - mu) * rs * wv.y + bv.y);
  o4[2] = (_Float16)((v.z - mu) * rs * wv.z + bv.z);
  o4[3] = (_Float16)((v.w - mu) * rs * wv.w + bv.w);
  *(f16x4*)&out[(size_t)row * 256 + lane * 4] = o4;
}

// ---------------- fused conv4+silu -> xproj -> dtproj+softplus ----------------
__global__ __launch_bounds__(128) void convxdt_k(
    const float* __restrict__ big, const float* __restrict__ cw, const float* __restrict__ cb,
    const float* __restrict__ xW, const float* __restrict__ dW, const float* __restrict__ dbias,
    float* __restrict__ ucv, float* __restrict__ xd, float* __restrict__ dt) {
  __shared__ float us[512];
  __shared__ float xs[48];
  int token = ((blockIdx.x & 7) << 8) | (blockIdx.x >> 3);
  int b = token >> 9, l = token & 511;
  int t = threadIdx.x;
  for (int c = t; c < 512; c += 128) {
    float acc = cb[c];
#pragma unroll
    for (int k = 0; k < 4; k++) {
      int l2 = l - 3 + k;
      if (l2 >= 0) acc += big[((size_t)(b * LSEQ + l2)) * 1024 + c] * cw[c * 4 + k];
    }
    float u = siluf_(acc);
    us[c] = u;
    ucv[(size_t)token * 512 + c] = u;
  }
  __syncthreads();
  float part = 0.f;
  int j = t >> 1, p = t & 1;
  if (t < 96) {
    for (int c = p * 256; c < p * 256 + 256; c++) part += us[c] * xW[c * 48 + j];
  }
  part += __shfl_xor(part, 1, 64);
  if (t < 96 && p == 0) {
    xs[j] = part;
    xd[(size_t)token * 48 + j] = part;
  }
  __syncthreads();
  for (int c = t; c < 512; c += 128) {
    float acc = dbias[c];
#pragma unroll
    for (int r = 0; r < 16; r++) acc += xs[r] * dW[r * 512 + c];
    dt[(size_t)token * 512 + c] = (acc > 20.f) ? acc : log1pf(__expf(acc));
  }
}

// ---------------- fused chunked scan (one block per channel, XCD-swizzled) ----------------
__global__ __launch_bounds__(256) void scan_k(
    const float* __restrict__ dt, const float* __restrict__ ucv, const float* __restrict__ xd,
    const float* __restrict__ zbuf, const float* __restrict__ A_log, const float* __restrict__ D_p,
    _Float16* __restrict__ gout) {
  __shared__ float Ps[16][17], Hs[16][17], Hi[16][17];
  int ch = ((blockIdx.x & 7) << 8) | (blockIdx.x >> 3);
  int b = ch >> 9, d = ch & 511;
  int t = threadIdx.x;
  int c = t >> 4, n = t & 15;
  float An = -__expf(A_log[d * 16 + n]);
  float P = 1.f, h = 0.f;
  int t0 = b * LSEQ + c * 32;
#pragma unroll 4
  for (int tt = 0; tt < 32; tt++) {
    int token = t0 + tt;
    float dtv = dt[(size_t)token * 512 + d];
    float uv = ucv[(size_t)token * 512 + d];
    float Bn = xd[(size_t)token * 48 + 16 + n];
    float dA = __expf(dtv * An);
    P *= dA;
    h = dA * h + dtv * uv * Bn;
  }
  Ps[c][n] = P; Hs[c][n] = h;
  __syncthreads();
  if (t < 16) {
    float hr = 0.f;
    for (int cc = 0; cc < 16; cc++) { Hi[cc][t] = hr; hr = Ps[cc][t] * hr + Hs[cc][t]; }
  }
  __syncthreads();
  h = Hi[c][n];
  float Dd = D_p[d];
#pragma unroll 4
  for (int tt = 0; tt < 32; tt++) {
    int token = t0 + tt;
    float dtv = dt[(size_t)token * 512 + d];
    float uv = ucv[(size_t)token * 512 + d];
    float Bn = xd[(size_t)token * 48 + 16 + n];
    float Cn = xd[(size_t)token * 48 + 32 + n];
    float dA = __expf(dtv * An);
    h = dA * h + dtv * uv * Bn;
    float y = h * Cn;
    y += __shfl_xor(y, 1, 64);
    y += __shfl_xor(y, 2, 64);
    y += __shfl_xor(y, 4, 64);
    y += __shfl_xor(y, 8, 64);
    if (n == 0) {
      float z = zbuf[(size_t)token * 1024 + 512 + d];
      gout[(size_t)token * 512 + d] = (_Float16)((y + uv * Dd) * siluf_(z));
    }
  }
}

// ---------------- SwiGLU for mlp: silu(g1)*g2 -> f16 ----------------
__global__ __launch_bounds__(256) void silumul_k(const float* __restrict__ big, _Float16* __restrict__ out) {
  int i = blockIdx.x * 256 + threadIdx.x; // BL*256
  int token = i >> 8, j = i & 255;
  float g1 = big[(size_t)token * 512 + j];
  float g2 = big[(size_t)token * 512 + 256 + j];
  out[i] = (_Float16)(siluf_(g1) * g2);
}

// ---------------- head: wide kernels with K-split GEMMs ----------------
__global__ __launch_bounds__(256) void lnf_k(const float* __restrict__ h, const float* __restrict__ nfw,
                                             const float* __restrict__ nfb, float* __restrict__ f) {
  __shared__ float red[4];
  int b = blockIdx.x, t = threadIdx.x;
  int lane = t & 63, wid = t >> 6;
  float v = h[((size_t)b * LSEQ + (LSEQ - 1)) * DMOD + t];
  float s = v;
#pragma unroll
  for (int o = 32; o; o >>= 1) s += __shfl_xor(s, o, 64);
  if (lane == 0) red[wid] = s;
  __syncthreads();
  float mu = (red[0] + red[1] + red[2] + red[3]) * (1.f / 256.f);
  float dv = v - mu;
  s = dv * dv;
#pragma unroll
  for (int o = 32; o; o >>= 1) s += __shfl_xor(s, o, 64);
  __syncthreads();
  if (lane == 0) red[wid] = s;
  __syncthreads();
  float var = (red[0] + red[1] + red[2] + red[3]) * (1.f / 256.f);
  f[b * 256 + t] = dv * rsqrtf(var + 1e-5f) * nfw[t] + nfb[t];
}

// grid (8, 4, 2): 8 col-chunks x 64 cols; 4 k-parts x 64 k per thread-group
__global__ __launch_bounds__(256) void hgemm1_k(const float* __restrict__ f,
    const float* vW1, const float* vb1, const float* aW1, const float* ab1,
    float* __restrict__ a1) {
  int cb = blockIdx.x, b = blockIdx.y, p = blockIdx.z;
  const float* W1 = p ? aW1 : vW1;
  const float* b1 = p ? ab1 : vb1;
  __shared__ float fs[256];
  __shared__ float part[4][64];
  int t = threadIdx.x;
  fs[t] = f[b * 256 + t];
  __syncthreads();
  int col = cb * 64 + (t & 63);
  int kp = t >> 6;
  float acc = 0.f;
#pragma unroll 8
  for (int k = 0; k < 64; k++) acc += fs[kp * 64 + k] * W1[(size_t)(kp * 64 + k) * 512 + col];
  part[kp][t & 63] = acc;
  __syncthreads();
  if (t < 64) {
    float v = part[0][t] + part[1][t] + part[2][t] + part[3][t] + b1[cb * 64 + t];
    a1[((b * 2 + p) * 512) + cb * 64 + t] = v;
  }
}

__global__ __launch_bounds__(512) void hln1_k(const float* __restrict__ a1,
    const float* vl1w, const float* vl1b, const float* al1w, const float* al1b,
    float* __restrict__ t1) {
  __shared__ float red[8];
  int b = blockIdx.x, p = blockIdx.y, t = threadIdx.x;
  const float* lw = p ? al1w : vl1w;
  const float* lb = p ? al1b : vl1b;
  int lane = t & 63, wid = t >> 6;
  int idx = (b * 2 + p) * 512 + t;
  float v = a1[idx];
  float s = v;
#pragma unroll
  for (int o = 32; o; o >>= 1) s += __shfl_xor(s, o, 64);
  if (lane == 0) red[wid] = s;
  __syncthreads();
  float S = 0.f;
#pragma unroll
  for (int k = 0; k < 8; k++) S += red[k];
  float mu = S * (1.f / 512.f);
  float dv = v - mu;
  s = dv * dv;
#pragma unroll
  for (int o = 32; o; o >>= 1) s += __shfl_xor(s, o, 64);
  __syncthreads();
  if (lane == 0) red[wid] = s;
  __syncthreads();
  S = 0.f;
#pragma unroll
  for (int k = 0; k < 8; k++) S += red[k];
  float var = S * (1.f / 512.f);
  t1[idx] = fmaxf(dv * rsqrtf(var + 1e-5f) * lw[t] + lb[t], 0.f);
}

// grid (4, 4, 2): 4 col-chunks x 64 cols; 4 k-parts x 128 k
__global__ __launch_bounds__(256) void hgemm2_k(const float* __restrict__ t1,
    const float* vW2, const float* vb2, const float* aW2, const float* ab2,
    float* __restrict__ a2) {
  int cb = blockIdx.x, b = blockIdx.y, p = blockIdx.z;
  const float* W2 = p ? aW2 : vW2;
  const float* b2 = p ? ab2 : vb2;
  __shared__ float ts[512];
  __shared__ float part[4][64];
  int t = threadIdx.x;
  ts[t] = t1[(b * 2 + p) * 512 + t];
  ts[256 + t] = t1[(b * 2 + p) * 512 + 256 + t];
  __syncthreads();
  int col = cb * 64 + (t & 63);
  int kp = t >> 6;
  float acc = 0.f;
#pragma unroll 8
  for (int k = 0; k < 128; k++) acc += ts[kp * 128 + k] * W2[(size_t)(kp * 128 + k) * 256 + col];
  part[kp][t & 63] = acc;
  __syncthreads();
  if (t < 64) {
    float v = part[0][t] + part[1][t] + part[2][t] + part[3][t] + b2[cb * 64 + t];
    a2[(b * 2 + p) * 256 + cb * 64 + t] = v;
  }
}

__global__ __launch_bounds__(256) void hln2_k(const float* __restrict__ a2,
    const float* vl2w, const float* vl2b, const float* al2w, const float* al2b,
    float* __restrict__ t2) {
  __shared__ float red[4];
  int b = blockIdx.x, p = blockIdx.y, t = threadIdx.x;
  const float* lw = p ? al2w : vl2w;
  const float* lb = p ? al2b : vl2b;
  int lane = t & 63, wid = t >> 6;
  int idx = (b * 2 + p) * 256 + t;
  float v = a2[idx];
  float s = v;
#pragma unroll
  for (int o = 32; o; o >>= 1) s += __shfl_xor(s, o, 64);
  if (lane == 0) red[wid] = s;
  __syncthreads();
  float mu = (red[0] + red[1] + red[2] + red[3]) * (1.f / 256.f);
  float dv = v - mu;
  s = dv * dv;
#pragma unroll
  for (int o = 32; o; o >>= 1) s += __shfl_xor(s, o, 64);
  __syncthreads();
  if (lane == 0) red[wid] = s;
  __syncthreads();
  float var = (red[0] + red[1] + red[2] + red[3]) * (1.f / 256.f);
  t2[idx] = fmaxf(dv * rsqrtf(var + 1e-5f) * lw[t] + lb[t], 0.f);
}

__global__ __launch_bounds__(256) void hfinal_k(const float* __restrict__ t2,
    const float* vW3, const float* vb3, const float* aW3, const float* ab3,
    float* __restrict__ q) {
  __shared__ float a3s[24];
  int t = threadIdx.x;
  int g = t >> 3, ln8 = t & 7;
  if (g < 24) {
    int b = g / 6, r = g - b * 6;
    int p = r ? 1 : 0;
    int o = r ? r - 1 : 0;
    const float* W3 = p ? aW3 : vW3;
    const float* b3 = p ? ab3 : vb3;
    int nout = p ? 5 : 1;
    const float* t2r = t2 + (b * 2 + p) * 256;
    float acc = 0.f;
    for (int k = ln8; k < 256; k += 8) acc += t2r[k] * W3[k * nout + o];
    acc += __shfl_xor(acc, 1, 64);
    acc += __shfl_xor(acc, 2, 64);
    acc += __shfl_xor(acc, 4, 64);
    if (ln8 == 0) a3s[g] = acc + b3[o];
  }
  __syncthreads();
  if (t < 20) {
    int b = t / 5, a = t - b * 5;
    float val = a3s[b * 6];
    float m = 0.f;
#pragma unroll
    for (int j = 0; j < 5; j++) m += a3s[b * 6 + 1 + j];
    m *= 0.2f;
    q[b * 5 + a] = val + a3s[b * 6 + 1 + a] - m;
  }
}

extern "C" void kernel_launch(void* const* d_in, const int* in_sizes, int n_in,
                              void* d_out, int out_size, void* d_ws, size_t ws_size,
                              hipStream_t stream) {
  const float* src = (const float*)d_in[0];
  const float* tau = (const float*)d_in[1];
  const float* dain_Wm = (const float*)d_in[2];
  const float* dain_Ws = (const float*)d_in[3];
  const float* dain_Wg = (const float*)d_in[4];
  const float* dain_bg = (const float*)d_in[5];
  const float* memb_W = (const float*)d_in[6];
  const float* memb_b = (const float*)d_in[7];
  const float* t_w0 = (const float*)d_in[8];
  const float* t_b0 = (const float*)d_in[9];
  const float* t_w = (const float*)d_in[10];
  const float* t_b = (const float*)d_in[11];
  const float* tproj_W = (const float*)d_in[12];
  const float* tproj_b = (const float*)d_in[13];
  const float* ffn_W1 = (const float*)d_in[14];
  const float* ffn_b1 = (const float*)d_in[15];
  const float* ffn_W2 = (const float*)d_in[16];
  const float* ffn_b2 = (const float*)d_in[17];
  const float* n1_w = (const float*)d_in[18];
  const float* n1_b = (const float*)d_in[19];
  const float* inproj_W = (const float*)d_in[20];
  const float* conv_w = (const float*)d_in[21];
  const float* conv_b = (const float*)d_in[22];
  const float* xproj_W = (const float*)d_in[23];
  const float* dtproj_W = (const float*)d_in[24];
  const float* dt_bias = (const float*)d_in[25];
  const float* A_log = (const float*)d_in[26];
  const float* D_p = (const float*)d_in[27];
  const float* outproj_W = (const float*)d_in[28];
  const float* n2_w = (const float*)d_in[29];
  const float* n2_b = (const float*)d_in[30];
  const float* mlp_W1 = (const float*)d_in[31];
  const float* mlp_W2 = (const float*)d_in[32];
  const float* nf_w = (const float*)d_in[33];
  const float* nf_b = (const float*)d_in[34];
  const float* vW1 = (const float*)d_in[35]; const float* vb1 = (const float*)d_in[36];
  const float* vl1w = (const float*)d_in[37]; const float* vl1b = (const float*)d_in[38];
  const float* vW2 = (const float*)d_in[39]; const float* vb2 = (const float*)d_in[40];
  const float* vl2w = (const float*)d_in[41]; const float* vl2b = (const float*)d_in[42];
  const float* vW3 = (const float*)d_in[43]; const float* vb3 = (const float*)d_in[44];
  const float* aW1 = (const float*)d_in[45]; const float* ab1 = (const float*)d_in[46];
  const float* al1w = (const float*)d_in[47]; const float* al1b = (const float*)d_in[48];
  const float* aW2 = (const float*)d_in[49]; const float* ab2 = (const float*)d_in[50];
  const float* al2w = (const float*)d_in[51]; const float* al2b = (const float*)d_in[52];
  const float* aW3 = (const float*)d_in[53]; const float* ab3 = (const float*)d_in[54];
  float* out = (float*)d_out;

  float* ws = (float*)d_ws;
  float* dstats = ws;                      // 256
  float* h    = dstats + 256;              // BL*256
  float* big  = h + (size_t)BL * DMOD;     // BL*1408
  float* ucv  = big + (size_t)BL * 1408;   // BL*512
  float* xd   = ucv + (size_t)BL * DIN;    // BL*48
  float* dt   = xd + (size_t)BL * 48;      // BL*512
  float* fh   = dt + (size_t)BL * DIN;     // 1024
  float* a1   = fh + 1024;                 // 4096
  float* t1   = a1 + 4096;                 // 4096
  float* a2   = t1 + 4096;                 // 2048
  float* t2   = a2 + 2048;                 // 2048
  float* fp_end = t2 + 2048;
  _Float16* h_hf    = (_Float16*)fp_end;            // BL*256
  _Float16* hn_hf   = h_hf + (size_t)BL * DMOD;     // BL*256
  _Float16* mid_hf  = hn_hf + (size_t)BL * DMOD;    // BL*704
  _Float16* gout_hf = mid_hf + (size_t)BL * 704;    // BL*512
  _Float16* ffn1T   = gout_hf + (size_t)BL * DIN;   // 1408*256
  _Float16* ffn2T   = ffn1T + (size_t)1408 * 256;   // 256*704
  _Float16* inprojT = ffn2T + (size_t)256 * 704;    // 8*1024*256
  _Float16* outprojT = inprojT + (size_t)8 * 1024 * 256;
  _Float16* mlp1T   = outprojT + (size_t)8 * 256 * 512;
  _Float16* mlp2T   = mlp1T + (size_t)8 * 512 * 256;

  convall_k<<<20544, 256, 0, stream>>>(ffn_W1, ffn_W2, inproj_W, outproj_W, mlp_W1, mlp_W2,
                                       ffn1T, ffn2T, inprojT, outprojT, mlp1T, mlp2T);
  dain_k<<<1, 1024, 0, stream>>>(src, dain_Wm, dain_Ws, dain_Wg, dain_bg, dstats);
  embed_k<<<BL, 256, 0, stream>>>(src, tau, dstats, memb_W, memb_b, t_w0, t_b0, t_w, t_b, tproj_W, tproj_b, h_hf);
  gemm_hf_k<<<dim3(22, 32), 256, 0, stream>>>(h_hf, ffn1T, ffn_b1, big, BL, 1364, 256, 1364, 0);
  glugelu_k<<<BL * 704 / 256, 256, 0, stream>>>(big, mid_hf);
  gemm_hf_k<<<dim3(4, 32), 256, 0, stream>>>(mid_hf, ffn2T, ffn_b2, h, BL, 256, 704, 256, 0);

  for (int i = 0; i < 8; i++) {
    ln4_k<<<BL / 4, 256, 0, stream>>>(h, n1_w + i * 256, n1_b + i * 256, hn_hf);
    gemm_hf_k<<<dim3(16, 32), 256, 0, stream>>>(hn_hf, inprojT + (size_t)i * 1024 * 256, nullptr, big,
                                                BL, 1024, 256, 1024, 0);
    convxdt_k<<<BL, 128, 0, stream>>>(big, conv_w + (size_t)i * 512 * 4, conv_b + i * 512,
                                      xproj_W + (size_t)i * 512 * 48, dtproj_W + (size_t)i * 16 * 512,
                                      dt_bias + i * 512, ucv, xd, dt);
    scan_k<<<NCH, 256, 0, stream>>>(dt, ucv, xd, big, A_log + (size_t)i * 512 * 16, D_p + i * 512, gout_hf);
    gemm_hf_k<<<dim3(4, 32), 256, 0, stream>>>(gout_hf, outprojT + (size_t)i * 256 * 512, nullptr, h,
                                               BL, 256, 512, 256, 1);
    ln4_k<<<BL / 4, 256, 0, stream>>>(h, n2_w + i * 256, n2_b + i * 256, hn_hf);
    gemm_hf_k<<<dim3(8, 32), 256, 0, stream>>>(hn_hf, mlp1T + (size_t)i * 512 * 256, nullptr, big,
                                               BL, 512, 256, 512, 0);
    silumul_k<<<BL, 256, 0, stream>>>(big, mid_hf);
    gemm_hf_k<<<dim3(4, 32), 256, 0, stream>>>(mid_hf, mlp2T + (size_t)i * 256 * 256, nullptr, h,
                                               BL, 256, 256, 256, 1);
  }

  lnf_k<<<NB, 256, 0, stream>>>(h, nf_w, nf_b, fh);
  hgemm1_k<<<dim3(8, 4, 2), 256, 0, stream>>>(fh, vW1, vb1, aW1, ab1, a1);
  hln1_k<<<dim3(4, 2), 512, 0, stream>>>(a1, vl1w, vl1b, al1w, al1b, t1);
  hgemm2_k<<<dim3(4, 4, 2), 256, 0, stream>>>(t1, vW2, vb2, aW2, ab2, a2);
  hln2_k<<<dim3(4, 2), 256, 0, stream>>>(a2, vl2w, vl2b, al2w, al2b, t2);
  hfinal_k<<<1, 256, 0, stream>>>(t2, vW3, vb3, aW3, ab3, out);
  (void)in_sizes; (void)n_in; (void)out_size; (void)ws_size;
}

// Round 11
// 1066.020 us; speedup vs baseline: 1.3367x; 1.0070x over previous
//
#include <hip/hip_runtime.h>
#include <math.h>

// Model constants
#define BL   2048   // B*L = 4*512
#define LSEQ 512
#define NB   4
#define DMOD 256
#define DIN  512
#define NCH  (NB * DIN)

typedef __attribute__((ext_vector_type(4))) float f32x4;
typedef __attribute__((ext_vector_type(8))) _Float16 f16x8;
typedef __attribute__((ext_vector_type(4))) _Float16 f16x4;

__device__ __forceinline__ float sigmoidf_(float x) { return 1.f / (1.f + __expf(-x)); }
__device__ __forceinline__ float siluf_(float x) { return x / (1.f + __expf(-x)); }

// ---------------- DAIN stats (single block) ----------------
__global__ __launch_bounds__(1024) void dain_k(
    const float* __restrict__ src, const float* __restrict__ Wm,
    const float* __restrict__ Ws, const float* __restrict__ Wg,
    const float* __restrict__ bg, float* __restrict__ stats) {
  __shared__ float part[1024];
  __shared__ float avg_s[128], sub_s[128], std_s[128], mn_s[128], inv_s[128];
  int tid = threadIdx.x;
  int p = tid >> 3, j = tid & 7;
  int b = p >> 5, f = p & 31;
  float s = 0.f;
  for (int l = j * 64; l < j * 64 + 64; ++l) s += src[((size_t)b * LSEQ + l) * 32 + f];
  part[tid] = s;
  __syncthreads();
  if (tid < 128) { float a = 0; for (int k = 0; k < 8; k++) a += part[tid * 8 + k]; avg_s[tid] = a * (1.f / 512.f); }
  __syncthreads();
  if (tid < 128) {
    int bb = tid >> 5, ff = tid & 31;
    float a = 0; for (int g = 0; g < 32; g++) a += avg_s[bb * 32 + g] * Wm[ff * 32 + g];
    sub_s[tid] = a;
  }
  __syncthreads();
  float sub = sub_s[p];
  s = 0.f;
  for (int l = j * 64; l < j * 64 + 64; ++l) {
    float v = src[((size_t)b * LSEQ + l) * 32 + f] - sub; s += v * v;
  }
  part[tid] = s;
  __syncthreads();
  if (tid < 128) { float a = 0; for (int k = 0; k < 8; k++) a += part[tid * 8 + k]; std_s[tid] = sqrtf(a * (1.f / 512.f)); }
  __syncthreads();
  if (tid < 128) {
    int bb = tid >> 5, ff = tid & 31;
    float a = 0; for (int g = 0; g < 32; g++) a += std_s[bb * 32 + g] * Ws[ff * 32 + g];
    if (a <= 1e-8f) a = 1.f;
    inv_s[tid] = 1.f / a;
    mn_s[tid] = (avg_s[tid] - sub_s[tid]) / a;
  }
  __syncthreads();
  if (tid < 128) {
    int bb = tid >> 5, ff = tid & 31;
    float a = bg[ff]; for (int g = 0; g < 32; g++) a += mn_s[bb * 32 + g] * Wg[ff * 32 + g];
    float gate = sigmoidf_(a);
    float scl = gate * inv_s[tid];
    stats[tid] = scl;
    stats[128 + tid] = sub_s[tid] * scl;
  }
}

// ---------------- embed -> h_hf (f16) ----------------
__global__ __launch_bounds__(256) void embed_k(
    const float* __restrict__ src, const float* __restrict__ tau,
    const float* __restrict__ stats, const float* __restrict__ membW,
    const float* __restrict__ membB, const float* __restrict__ tw0,
    const float* __restrict__ tb0, const float* __restrict__ tw,
    const float* __restrict__ tb, const float* __restrict__ tprojW,
    const float* __restrict__ tprojB, _Float16* __restrict__ h_hf) {
  int token = blockIdx.x;
  int b = token >> 9;
  int t = threadIdx.x;
  __shared__ float xs[32], te[32];
  if (t < 32) {
    float scl = stats[b * 32 + t], shf = stats[128 + b * 32 + t];
    xs[t] = src[(size_t)token * 32 + t] * scl - shf;
  } else if (t < 64) {
    int j = t - 32;
    const float* tr = tau + (size_t)token * 8;
    float a;
    if (j < 31) { a = tb[j]; for (int k = 0; k < 8; k++) a += tr[k] * tw[k * 31 + j]; a = sinf(a); }
    else        { a = tb0[0]; for (int k = 0; k < 8; k++) a += tr[k] * tw0[k]; }
    te[j] = a;
  }
  __syncthreads();
  float acc;
  if (t < 128) {
    acc = membB[t];
    for (int f = 0; f < 32; f++) acc += xs[f] * membW[f * 128 + t];
  } else {
    int d = t - 128;
    acc = tprojB[d];
    for (int j = 0; j < 32; j++) acc += te[j] * tprojW[j * 128 + d];
  }
  h_hf[(size_t)token * DMOD + t] = (_Float16)acc;
}

// ---------------- all weight transpose-converts in ONE launch ----------------
__device__ __forceinline__ void convT_one(const float* __restrict__ W, _Float16* __restrict__ WT,
                                          int K, int N, int Kout, int Nout, int idx) {
  int per = Nout * Kout;
  int l = idx / per; int rem = idx - l * per;
  int n = rem / Kout; int k = rem - n * Kout;
  const float* Wl = W + (size_t)l * K * N;
  float v = (k < K && n < N) ? Wl[(size_t)k * N + n] : 0.f;
  WT[(size_t)l * per + rem] = (_Float16)v;
}

__global__ __launch_bounds__(256) void convall_k(
    const float* ffn_W1, const float* ffn_W2, const float* inproj_W,
    const float* outproj_W, const float* mlp_W1, const float* mlp_W2,
    _Float16* ffn1T, _Float16* ffn2T, _Float16* inprojT,
    _Float16* outprojT, _Float16* mlp1T, _Float16* mlp2T) {
  int g = blockIdx.x, t = threadIdx.x;
  if (g < 1408)            convT_one(ffn_W1, ffn1T, 256, 1364, 256, 1408, g * 256 + t);
  else if (g < 2112)       convT_one(ffn_W2, ffn2T, 682, 256, 704, 256, (g - 1408) * 256 + t);
  else if (g < 10304)      convT_one(inproj_W, inprojT, 256, 1024, 256, 1024, (g - 2112) * 256 + t);
  else if (g < 14400)      convT_one(outproj_W, outprojT, 512, 256, 512, 256, (g - 10304) * 256 + t);
  else if (g < 18496)      convT_one(mlp_W1, mlp1T, 256, 512, 256, 512, (g - 14400) * 256 + t);
  else                     convT_one(mlp_W2, mlp2T, 256, 256, 256, 256, (g - 18496) * 256 + t);
}

// ---------------- plain f16 MFMA GEMM 64x64 tile (A stride == K) ----------------
__global__ __launch_bounds__(256) void gemm_hf_k(
    const _Float16* __restrict__ A, const _Float16* __restrict__ WT,
    const float* __restrict__ bias, float* __restrict__ C,
    int M, int Nstore, int K, int ldc, int flags) {
  __shared__ _Float16 As[64][40];
  __shared__ _Float16 Bs[64][40];
  int bm = blockIdx.y * 64, bn = blockIdx.x * 64;
  int t = threadIdx.x;
  int w = t >> 6, l = t & 63;
  int wm = w >> 1, wn = w & 1;
  int srow = t >> 2, sk = (t & 3) * 8;
  f32x4 acc[2][2] = {};
  int lr = l & 15, lk = (l >> 4) * 8;
  for (int k0 = 0; k0 < K; k0 += 32) {
    *(uint4*)&As[srow][sk] = *(const uint4*)&A[(size_t)(bm + srow) * K + k0 + sk];
    *(uint4*)&Bs[srow][sk] = *(const uint4*)&WT[(size_t)(bn + srow) * K + k0 + sk];
    __syncthreads();
    f16x8 a0 = *(const f16x8*)&As[wm * 32 + lr][lk];
    f16x8 a1 = *(const f16x8*)&As[wm * 32 + 16 + lr][lk];
    f16x8 b0 = *(const f16x8*)&Bs[wn * 32 + lr][lk];
    f16x8 b1 = *(const f16x8*)&Bs[wn * 32 + 16 + lr][lk];
    acc[0][0] = __builtin_amdgcn_mfma_f32_16x16x32_f16(a0, b0, acc[0][0], 0, 0, 0);
    acc[0][1] = __builtin_amdgcn_mfma_f32_16x16x32_f16(a0, b1, acc[0][1], 0, 0, 0);
    acc[1][0] = __builtin_amdgcn_mfma_f32_16x16x32_f16(a1, b0, acc[1][0], 0, 0, 0);
    acc[1][1] = __builtin_amdgcn_mfma_f32_16x16x32_f16(a1, b1, acc[1][1], 0, 0, 0);
    __syncthreads();
  }
  int lq = l >> 4;
#pragma unroll
  for (int i = 0; i < 2; i++) {
#pragma unroll
    for (int j = 0; j < 2; j++) {
      int col = bn + wn * 32 + j * 16 + lr;
      if (col >= Nstore) continue;
      float bv = bias ? bias[col] : 0.f;
#pragma unroll
      for (int r = 0; r < 4; r++) {
        int row = bm + wm * 32 + i * 16 + lq * 4 + r;
        float v = acc[i][j][r] + bv;
        size_t idx = (size_t)row * ldc + col;
        if (flags & 1) v += C[idx];
        C[idx] = v;
      }
    }
  }
}

// ---------------- FFN GLU (a * gelu_exact(g)) -> f16 padded to 704 ----------------
__global__ __launch_bounds__(256) void glugelu_k(const float* __restrict__ big, _Float16* __restrict__ out) {
  int i = blockIdx.x * 256 + threadIdx.x; // BL*704
  int token = i / 704, j = i - token * 704;
  float r = 0.f;
  if (j < 682) {
    float a = big[(size_t)token * 1364 + j];
    float g = big[(size_t)token * 1364 + 682 + j];
    r = a * 0.5f * g * (1.f + erff(g * 0.70710678118654752f));
  }
  out[i] = (_Float16)r;
}

// ---------------- LayerNorm, 4 rows/block (wave per row) -> f16 ----------------
__global__ __launch_bounds__(256) void ln4_k(const float* __restrict__ x, const float* __restrict__ w,
                                             const float* __restrict__ b, _Float16* __restrict__ out) {
  int row = blockIdx.x * 4 + (threadIdx.x >> 6), lane = threadIdx.x & 63;
  const float* rp = x + (size_t)row * 256;
  float4 v = *(const float4*)&rp[lane * 4];
  float s = v.x + v.y + v.z + v.w;
  float ss = v.x * v.x + v.y * v.y + v.z * v.z + v.w * v.w;
#pragma unroll
  for (int o = 32; o; o >>= 1) { s += __shfl_xor(s, o, 64); ss += __shfl_xor(ss, o, 64); }
  float mu = s * (1.f / 256.f);
  float var = ss * (1.f / 256.f) - mu * mu;
  float rs = rsqrtf(var + 1e-5f);
  float4 wv = *(const float4*)&w[lane * 4];
  float4 bv = *(const float4*)&b[lane * 4];
  f16x4 o4;
  o4[0] = (_Float16)((v.x - mu) * rs * wv.x + bv.x);
  o4[1] = (_Float16)((v.y - mu) * rs * wv.y + bv.y);
  o4[2] = (_Float16)((v.z - mu) * rs * wv.z + bv.z);
  o4[3] = (_Float16)((v.w - mu) * rs * wv.w + bv.w);
  *(f16x4*)&out[(size_t)row * 256 + lane * 4] = o4;
}

// ---------------- fused conv4+silu -> xproj -> dtproj+softplus ----------------
__global__ __launch_bounds__(128) void convxdt_k(
    const float* __restrict__ big, const float* __restrict__ cw, const float* __restrict__ cb,
    const float* __restrict__ xW, const float* __restrict__ dW, const float* __restrict__ dbias,
    float* __restrict__ ucv, float* __restrict__ xd, float* __restrict__ dt) {
  __shared__ float us[512];
  __shared__ float xs[48];
  int token = ((blockIdx.x & 7) << 8) | (blockIdx.x >> 3);
  int b = token >> 9, l = token & 511;
  int t = threadIdx.x;
  for (int c = t; c < 512; c += 128) {
    float acc = cb[c];
#pragma unroll
    for (int k = 0; k < 4; k++) {
      int l2 = l - 3 + k;
      if (l2 >= 0) acc += big[((size_t)(b * LSEQ + l2)) * 1024 + c] * cw[c * 4 + k];
    }
    float u = siluf_(acc);
    us[c] = u;
    ucv[(size_t)token * 512 + c] = u;
  }
  __syncthreads();
  float part = 0.f;
  int j = t >> 1, p = t & 1;
  if (t < 96) {
    for (int c = p * 256; c < p * 256 + 256; c++) part += us[c] * xW[c * 48 + j];
  }
  part += __shfl_xor(part, 1, 64);
  if (t < 96 && p == 0) {
    xs[j] = part;
    xd[(size_t)token * 48 + j] = part;
  }
  __syncthreads();
  for (int c = t; c < 512; c += 128) {
    float acc = dbias[c];
#pragma unroll
    for (int r = 0; r < 16; r++) acc += xs[r] * dW[r * 512 + c];
    dt[(size_t)token * 512 + c] = (acc > 20.f) ? acc : log1pf(__expf(acc));
  }
}

// ---------------- fused chunked scan (one block per channel, XCD-swizzled) ----------------
// Explicit 8-wide load batching: fill register arrays with independent loads,
// then compute — one waitcnt per 8 iterations instead of per iteration.
__global__ __launch_bounds__(256) void scan_k(
    const float* __restrict__ dt, const float* __restrict__ ucv, const float* __restrict__ xd,
    const float* __restrict__ zbuf, const float* __restrict__ A_log, const float* __restrict__ D_p,
    _Float16* __restrict__ gout) {
  __shared__ float Ps[16][17], Hs[16][17], Hi[16][17];
  int ch = ((blockIdx.x & 7) << 8) | (blockIdx.x >> 3);
  int b = ch >> 9, d = ch & 511;
  int t = threadIdx.x;
  int c = t >> 4, n = t & 15;
  float An = -__expf(A_log[d * 16 + n]);
  float P = 1.f, h = 0.f;
  int t0 = b * LSEQ + c * 32;
  for (int tb = 0; tb < 4; tb++) {
    float dtv[8], uv[8], Bn[8];
#pragma unroll
    for (int j = 0; j < 8; j++) {
      int token = t0 + tb * 8 + j;
      dtv[j] = dt[(size_t)token * 512 + d];
      uv[j]  = ucv[(size_t)token * 512 + d];
      Bn[j]  = xd[(size_t)token * 48 + 16 + n];
    }
#pragma unroll
    for (int j = 0; j < 8; j++) {
      float dA = __expf(dtv[j] * An);
      P *= dA;
      h = dA * h + dtv[j] * uv[j] * Bn[j];
    }
  }
  Ps[c][n] = P; Hs[c][n] = h;
  __syncthreads();
  if (t < 16) {
    float hr = 0.f;
    for (int cc = 0; cc < 16; cc++) { Hi[cc][t] = hr; hr = Ps[cc][t] * hr + Hs[cc][t]; }
  }
  __syncthreads();
  h = Hi[c][n];
  float Dd = D_p[d];
  for (int tb = 0; tb < 4; tb++) {
    float dtv[8], uv[8], Bn[8], Cn[8], zv[8];
#pragma unroll
    for (int j = 0; j < 8; j++) {
      int token = t0 + tb * 8 + j;
      dtv[j] = dt[(size_t)token * 512 + d];
      uv[j]  = ucv[(size_t)token * 512 + d];
      Bn[j]  = xd[(size_t)token * 48 + 16 + n];
      Cn[j]  = xd[(size_t)token * 48 + 32 + n];
      zv[j]  = (n == 0) ? zbuf[(size_t)token * 1024 + 512 + d] : 0.f;
    }
#pragma unroll
    for (int j = 0; j < 8; j++) {
      float dA = __expf(dtv[j] * An);
      h = dA * h + dtv[j] * uv[j] * Bn[j];
      float y = h * Cn[j];
      y += __shfl_xor(y, 1, 64);
      y += __shfl_xor(y, 2, 64);
      y += __shfl_xor(y, 4, 64);
      y += __shfl_xor(y, 8, 64);
      if (n == 0) {
        int token = t0 + tb * 8 + j;
        gout[(size_t)token * 512 + d] = (_Float16)((y + uv[j] * Dd) * siluf_(zv[j]));
      }
    }
  }
}

// ---------------- SwiGLU for mlp: silu(g1)*g2 -> f16 ----------------
__global__ __launch_bounds__(256) void silumul_k(const float* __restrict__ big, _Float16* __restrict__ out) {
  int i = blockIdx.x * 256 + threadIdx.x; // BL*256
  int token = i >> 8, j = i & 255;
  float g1 = big[(size_t)token * 512 + j];
  float g2 = big[(size_t)token * 512 + 256 + j];
  out[i] = (_Float16)(siluf_(g1) * g2);
}

// ---------------- head: wide kernels with K-split GEMMs ----------------
__global__ __launch_bounds__(256) void lnf_k(const float* __restrict__ h, const float* __restrict__ nfw,
                                             const float* __restrict__ nfb, float* __restrict__ f) {
  __shared__ float red[4];
  int b = blockIdx.x, t = threadIdx.x;
  int lane = t & 63, wid = t >> 6;
  float v = h[((size_t)b * LSEQ + (LSEQ - 1)) * DMOD + t];
  float s = v;
#pragma unroll
  for (int o = 32; o; o >>= 1) s += __shfl_xor(s, o, 64);
  if (lane == 0) red[wid] = s;
  __syncthreads();
  float mu = (red[0] + red[1] + red[2] + red[3]) * (1.f / 256.f);
  float dv = v - mu;
  s = dv * dv;
#pragma unroll
  for (int o = 32; o; o >>= 1) s += __shfl_xor(s, o, 64);
  __syncthreads();
  if (lane == 0) red[wid] = s;
  __syncthreads();
  float var = (red[0] + red[1] + red[2] + red[3]) * (1.f / 256.f);
  f[b * 256 + t] = dv * rsqrtf(var + 1e-5f) * nfw[t] + nfb[t];
}

// grid (8, 4, 2): 8 col-chunks x 64 cols; 4 k-parts x 64 k per thread-group
__global__ __launch_bounds__(256) void hgemm1_k(const float* __restrict__ f,
    const float* vW1, const float* vb1, const float* aW1, const float* ab1,
    float* __restrict__ a1) {
  int cb = blockIdx.x, b = blockIdx.y, p = blockIdx.z;
  const float* W1 = p ? aW1 : vW1;
  const float* b1 = p ? ab1 : vb1;
  __shared__ float fs[256];
  __shared__ float part[4][64];
  int t = threadIdx.x;
  fs[t] = f[b * 256 + t];
  __syncthreads();
  int col = cb * 64 + (t & 63);
  int kp = t >> 6;
  float acc = 0.f;
#pragma unroll 8
  for (int k = 0; k < 64; k++) acc += fs[kp * 64 + k] * W1[(size_t)(kp * 64 + k) * 512 + col];
  part[kp][t & 63] = acc;
  __syncthreads();
  if (t < 64) {
    float v = part[0][t] + part[1][t] + part[2][t] + part[3][t] + b1[cb * 64 + t];
    a1[((b * 2 + p) * 512) + cb * 64 + t] = v;
  }
}

__global__ __launch_bounds__(512) void hln1_k(const float* __restrict__ a1,
    const float* vl1w, const float* vl1b, const float* al1w, const float* al1b,
    float* __restrict__ t1) {
  __shared__ float red[8];
  int b = blockIdx.x, p = blockIdx.y, t = threadIdx.x;
  const float* lw = p ? al1w : vl1w;
  const float* lb = p ? al1b : vl1b;
  int lane = t & 63, wid = t >> 6;
  int idx = (b * 2 + p) * 512 + t;
  float v = a1[idx];
  float s = v;
#pragma unroll
  for (int o = 32; o; o >>= 1) s += __shfl_xor(s, o, 64);
  if (lane == 0) red[wid] = s;
  __syncthreads();
  float S = 0.f;
#pragma unroll
  for (int k = 0; k < 8; k++) S += red[k];
  float mu = S * (1.f / 512.f);
  float dv = v - mu;
  s = dv * dv;
#pragma unroll
  for (int o = 32; o; o >>= 1) s += __shfl_xor(s, o, 64);
  __syncthreads();
  if (lane == 0) red[wid] = s;
  __syncthreads();
  S = 0.f;
#pragma unroll
  for (int k = 0; k < 8; k++) S += red[k];
  float var = S * (1.f / 512.f);
  t1[idx] = fmaxf(dv * rsqrtf(var + 1e-5f) * lw[t] + lb[t], 0.f);
}

// grid (4, 4, 2): 4 col-chunks x 64 cols; 4 k-parts x 128 k
__global__ __launch_bounds__(256) void hgemm2_k(const float* __restrict__ t1,
    const float* vW2, const float* vb2, const float* aW2, const float* ab2,
    float* __restrict__ a2) {
  int cb = blockIdx.x, b = blockIdx.y, p = blockIdx.z;
  const float* W2 = p ? aW2 : vW2;
  const float* b2 = p ? ab2 : vb2;
  __shared__ float ts[512];
  __shared__ float part[4][64];
  int t = threadIdx.x;
  ts[t] = t1[(b * 2 + p) * 512 + t];
  ts[256 + t] = t1[(b * 2 + p) * 512 + 256 + t];
  __syncthreads();
  int col = cb * 64 + (t & 63);
  int kp = t >> 6;
  float acc = 0.f;
#pragma unroll 8
  for (int k = 0; k < 128; k++) acc += ts[kp * 128 + k] * W2[(size_t)(kp * 128 + k) * 256 + col];
  part[kp][t & 63] = acc;
  __syncthreads();
  if (t < 64) {
    float v = part[0][t] + part[1][t] + part[2][t] + part[3][t] + b2[cb * 64 + t];
    a2[(b * 2 + p) * 256 + cb * 64 + t] = v;
  }
}

__global__ __launch_bounds__(256) void hln2_k(const float* __restrict__ a2,
    const float* vl2w, const float* vl2b, const float* al2w, const float* al2b,
    float* __restrict__ t2) {
  __shared__ float red[4];
  int b = blockIdx.x, p = blockIdx.y, t = threadIdx.x;
  const float* lw = p ? al2w : vl2w;
  const float* lb = p ? al2b : vl2b;
  int lane = t & 63, wid = t >> 6;
  int idx = (b * 2 + p) * 256 + t;
  float v = a2[idx];
  float s = v;
#pragma unroll
  for (int o = 32; o; o >>= 1) s += __shfl_xor(s, o, 64);
  if (lane == 0) red[wid] = s;
  __syncthreads();
  float mu = (red[0] + red[1] + red[2] + red[3]) * (1.f / 256.f);
  float dv = v - mu;
  s = dv * dv;
#pragma unroll
  for (int o = 32; o; o >>= 1) s += __shfl_xor(s, o, 64);
  __syncthreads();
  if (lane == 0) red[wid] = s;
  __syncthreads();
  float var = (red[0] + red[1] + red[2] + red[3]) * (1.f / 256.f);
  t2[idx] = fmaxf(dv * rsqrtf(var + 1e-5f) * lw[t] + lb[t], 0.f);
}

__global__ __launch_bounds__(256) void hfinal_k(const float* __restrict__ t2,
    const float* vW3, const float* vb3, const float* aW3, const float* ab3,
    float* __restrict__ q) {
  __shared__ float a3s[24];
  int t = threadIdx.x;
  int g = t >> 3, ln8 = t & 7;
  if (g < 24) {
    int b = g / 6, r = g - b * 6;
    int p = r ? 1 : 0;
    int o = r ? r - 1 : 0;
    const float* W3 = p ? aW3 : vW3;
    const float* b3 = p ? ab3 : vb3;
    int nout = p ? 5 : 1;
    const float* t2r = t2 + (b * 2 + p) * 256;
    float acc = 0.f;
    for (int k = ln8; k < 256; k += 8) acc += t2r[k] * W3[k * nout + o];
    acc += __shfl_xor(acc, 1, 64);
    acc += __shfl_xor(acc, 2, 64);
    acc += __shfl_xor(acc, 4, 64);
    if (ln8 == 0) a3s[g] = acc + b3[o];
  }
  __syncthreads();
  if (t < 20) {
    int b = t / 5, a = t - b * 5;
    float val = a3s[b * 6];
    float m = 0.f;
#pragma unroll
    for (int j = 0; j < 5; j++) m += a3s[b * 6 + 1 + j];
    m *= 0.2f;
    q[b * 5 + a] = val + a3s[b * 6 + 1 + a] - m;
  }
}

extern "C" void kernel_launch(void* const* d_in, const int* in_sizes, int n_in,
                              void* d_out, int out_size, void* d_ws, size_t ws_size,
                              hipStream_t stream) {
  const float* src = (const float*)d_in[0];
  const float* tau = (const float*)d_in[1];
  const float* dain_Wm = (const float*)d_in[2];
  const float* dain_Ws = (const float*)d_in[3];
  const float* dain_Wg = (const float*)d_in[4];
  const float* dain_bg = (const float*)d_in[5];
  const float* memb_W = (const float*)d_in[6];
  const float* memb_b = (const float*)d_in[7];
  const float* t_w0 = (const float*)d_in[8];
  const float* t_b0 = (const float*)d_in[9];
  const float* t_w = (const float*)d_in[10];
  const float* t_b = (const float*)d_in[11];
  const float* tproj_W = (const float*)d_in[12];
  const float* tproj_b = (const float*)d_in[13];
  const float* ffn_W1 = (const float*)d_in[14];
  const float* ffn_b1 = (const float*)d_in[15];
  const float* ffn_W2 = (const float*)d_in[16];
  const float* ffn_b2 = (const float*)d_in[17];
  const float* n1_w = (const float*)d_in[18];
  const float* n1_b = (const float*)d_in[19];
  const float* inproj_W = (const float*)d_in[20];
  const float* conv_w = (const float*)d_in[21];
  const float* conv_b = (const float*)d_in[22];
  const float* xproj_W = (const float*)d_in[23];
  const float* dtproj_W = (const float*)d_in[24];
  const float* dt_bias = (const float*)d_in[25];
  const float* A_log = (const float*)d_in[26];
  const float* D_p = (const float*)d_in[27];
  const float* outproj_W = (const float*)d_in[28];
  const float* n2_w = (const float*)d_in[29];
  const float* n2_b = (const float*)d_in[30];
  const float* mlp_W1 = (const float*)d_in[31];
  const float* mlp_W2 = (const float*)d_in[32];
  const float* nf_w = (const float*)d_in[33];
  const float* nf_b = (const float*)d_in[34];
  const float* vW1 = (const float*)d_in[35]; const float* vb1 = (const float*)d_in[36];
  const float* vl1w = (const float*)d_in[37]; const float* vl1b = (const float*)d_in[38];
  const float* vW2 = (const float*)d_in[39]; const float* vb2 = (const float*)d_in[40];
  const float* vl2w = (const float*)d_in[41]; const float* vl2b = (const float*)d_in[42];
  const float* vW3 = (const float*)d_in[43]; const float* vb3 = (const float*)d_in[44];
  const float* aW1 = (const float*)d_in[45]; const float* ab1 = (const float*)d_in[46];
  const float* al1w = (const float*)d_in[47]; const float* al1b = (const float*)d_in[48];
  const float* aW2 = (const float*)d_in[49]; const float* ab2 = (const float*)d_in[50];
  const float* al2w = (const float*)d_in[51]; const float* al2b = (const float*)d_in[52];
  const float* aW3 = (const float*)d_in[53]; const float* ab3 = (const float*)d_in[54];
  float* out = (float*)d_out;

  float* ws = (float*)d_ws;
  float* dstats = ws;                      // 256
  float* h    = dstats + 256;              // BL*256
  float* big  = h + (size_t)BL * DMOD;     // BL*1408
  float* ucv  = big + (size_t)BL * 1408;   // BL*512
  float* xd   = ucv + (size_t)BL * DIN;    // BL*48
  float* dt   = xd + (size_t)BL * 48;      // BL*512
  float* fh   = dt + (size_t)BL * DIN;     // 1024
  float* a1   = fh + 1024;                 // 4096
  float* t1   = a1 + 4096;                 // 4096
  float* a2   = t1 + 4096;                 // 2048
  float* t2   = a2 + 2048;                 // 2048
  float* fp_end = t2 + 2048;
  _Float16* h_hf    = (_Float16*)fp_end;            // BL*256
  _Float16* hn_hf   = h_hf + (size_t)BL * DMOD;     // BL*256
  _Float16* mid_hf  = hn_hf + (size_t)BL * DMOD;    // BL*704
  _Float16* gout_hf = mid_hf + (size_t)BL * 704;    // BL*512
  _Float16* ffn1T   = gout_hf + (size_t)BL * DIN;   // 1408*256
  _Float16* ffn2T   = ffn1T + (size_t)1408 * 256;   // 256*704
  _Float16* inprojT = ffn2T + (size_t)256 * 704;    // 8*1024*256
  _Float16* outprojT = inprojT + (size_t)8 * 1024 * 256;
  _Float16* mlp1T   = outprojT + (size_t)8 * 256 * 512;
  _Float16* mlp2T   = mlp1T + (size_t)8 * 512 * 256;

  convall_k<<<20544, 256, 0, stream>>>(ffn_W1, ffn_W2, inproj_W, outproj_W, mlp_W1, mlp_W2,
                                       ffn1T, ffn2T, inprojT, outprojT, mlp1T, mlp2T);
  dain_k<<<1, 1024, 0, stream>>>(src, dain_Wm, dain_Ws, dain_Wg, dain_bg, dstats);
  embed_k<<<BL, 256, 0, stream>>>(src, tau, dstats, memb_W, memb_b, t_w0, t_b0, t_w, t_b, tproj_W, tproj_b, h_hf);
  gemm_hf_k<<<dim3(22, 32), 256, 0, stream>>>(h_hf, ffn1T, ffn_b1, big, BL, 1364, 256, 1364, 0);
  glugelu_k<<<BL * 704 / 256, 256, 0, stream>>>(big, mid_hf);
  gemm_hf_k<<<dim3(4, 32), 256, 0, stream>>>(mid_hf, ffn2T, ffn_b2, h, BL, 256, 704, 256, 0);

  for (int i = 0; i < 8; i++) {
    ln4_k<<<BL / 4, 256, 0, stream>>>(h, n1_w + i * 256, n1_b + i * 256, hn_hf);
    gemm_hf_k<<<dim3(16, 32), 256, 0, stream>>>(hn_hf, inprojT + (size_t)i * 1024 * 256, nullptr, big,
                                                BL, 1024, 256, 1024, 0);
    convxdt_k<<<BL, 128, 0, stream>>>(big, conv_w + (size_t)i * 512 * 4, conv_b + i * 512,
                                      xproj_W + (size_t)i * 512 * 48, dtproj_W + (size_t)i * 16 * 512,
                                      dt_bias + i * 512, ucv, xd, dt);
    scan_k<<<NCH, 256, 0, stream>>>(dt, ucv, xd, big, A_log + (size_t)i * 512 * 16, D_p + i * 512, gout_hf);
    gemm_hf_k<<<dim3(4, 32), 256, 0, stream>>>(gout_hf, outprojT + (size_t)i * 256 * 512, nullptr, h,
                                               BL, 256, 512, 256, 1);
    ln4_k<<<BL / 4, 256, 0, stream>>>(h, n2_w + i * 256, n2_b + i * 256, hn_hf);
    gemm_hf_k<<<dim3(8, 32), 256, 0, stream>>>(hn_hf, mlp1T + (size_t)i * 512 * 256, nullptr, big,
                                               BL, 512, 256, 512, 0);
    silumul_k<<<BL, 256, 0, stream>>>(big, mid_hf);
    gemm_hf_k<<<dim3(4, 32), 256, 0, stream>>>(mid_hf, mlp2T + (size_t)i * 256 * 256, nullptr, h,
                                               BL, 256, 256, 256, 1);
  }

  lnf_k<<<NB, 256, 0, stream>>>(h, nf_w, nf_b, fh);
  hgemm1_k<<<dim3(8, 4, 2), 256, 0, stream>>>(fh, vW1, vb1, aW1, ab1, a1);
  hln1_k<<<dim3(4, 2), 512, 0, stream>>>(a1, vl1w, vl1b, al1w, al1b, t1);
  hgemm2_k<<<dim3(4, 4, 2), 256, 0, stream>>>(t1, vW2, vb2, aW2, ab2, a2);
  hln2_k<<<dim3(4, 2), 256, 0, stream>>>(a2, vl2w, vl2b, al2w, al2b, t2);
  hfinal_k<<<1, 256, 0, stream>>>(t2, vW3, vb3, aW3, ab3, out);
  (void)in_sizes; (void)n_in; (void)out_size; (void)ws_size;
}

// Round 12
// 1035.942 us; speedup vs baseline: 1.3756x; 1.0290x over previous
//
#include <hip/hip_runtime.h>
#include <math.h>

// Model constants
#define BL   2048   // B*L = 4*512
#define LSEQ 512
#define NB   4
#define DMOD 256
#define DIN  512
#define NCH  (NB * DIN)

typedef __attribute__((ext_vector_type(4))) float f32x4;
typedef __attribute__((ext_vector_type(8))) _Float16 f16x8;
typedef __attribute__((ext_vector_type(4))) _Float16 f16x4;

__device__ __forceinline__ float sigmoidf_(float x) { return 1.f / (1.f + __expf(-x)); }
__device__ __forceinline__ float siluf_(float x) { return x / (1.f + __expf(-x)); }

// ---------------- DAIN stats (single block) ----------------
__global__ __launch_bounds__(1024) void dain_k(
    const float* __restrict__ src, const float* __restrict__ Wm,
    const float* __restrict__ Ws, const float* __restrict__ Wg,
    const float* __restrict__ bg, float* __restrict__ stats) {
  __shared__ float part[1024];
  __shared__ float avg_s[128], sub_s[128], std_s[128], mn_s[128], inv_s[128];
  int tid = threadIdx.x;
  int p = tid >> 3, j = tid & 7;
  int b = p >> 5, f = p & 31;
  float s = 0.f;
  for (int l = j * 64; l < j * 64 + 64; ++l) s += src[((size_t)b * LSEQ + l) * 32 + f];
  part[tid] = s;
  __syncthreads();
  if (tid < 128) { float a = 0; for (int k = 0; k < 8; k++) a += part[tid * 8 + k]; avg_s[tid] = a * (1.f / 512.f); }
  __syncthreads();
  if (tid < 128) {
    int bb = tid >> 5, ff = tid & 31;
    float a = 0; for (int g = 0; g < 32; g++) a += avg_s[bb * 32 + g] * Wm[ff * 32 + g];
    sub_s[tid] = a;
  }
  __syncthreads();
  float sub = sub_s[p];
  s = 0.f;
  for (int l = j * 64; l < j * 64 + 64; ++l) {
    float v = src[((size_t)b * LSEQ + l) * 32 + f] - sub; s += v * v;
  }
  part[tid] = s;
  __syncthreads();
  if (tid < 128) { float a = 0; for (int k = 0; k < 8; k++) a += part[tid * 8 + k]; std_s[tid] = sqrtf(a * (1.f / 512.f)); }
  __syncthreads();
  if (tid < 128) {
    int bb = tid >> 5, ff = tid & 31;
    float a = 0; for (int g = 0; g < 32; g++) a += std_s[bb * 32 + g] * Ws[ff * 32 + g];
    if (a <= 1e-8f) a = 1.f;
    inv_s[tid] = 1.f / a;
    mn_s[tid] = (avg_s[tid] - sub_s[tid]) / a;
  }
  __syncthreads();
  if (tid < 128) {
    int bb = tid >> 5, ff = tid & 31;
    float a = bg[ff]; for (int g = 0; g < 32; g++) a += mn_s[bb * 32 + g] * Wg[ff * 32 + g];
    float gate = sigmoidf_(a);
    float scl = gate * inv_s[tid];
    stats[tid] = scl;
    stats[128 + tid] = sub_s[tid] * scl;
  }
}

// ---------------- embed -> h_hf (f16) ----------------
__global__ __launch_bounds__(256) void embed_k(
    const float* __restrict__ src, const float* __restrict__ tau,
    const float* __restrict__ stats, const float* __restrict__ membW,
    const float* __restrict__ membB, const float* __restrict__ tw0,
    const float* __restrict__ tb0, const float* __restrict__ tw,
    const float* __restrict__ tb, const float* __restrict__ tprojW,
    const float* __restrict__ tprojB, _Float16* __restrict__ h_hf) {
  int token = blockIdx.x;
  int b = token >> 9;
  int t = threadIdx.x;
  __shared__ float xs[32], te[32];
  if (t < 32) {
    float scl = stats[b * 32 + t], shf = stats[128 + b * 32 + t];
    xs[t] = src[(size_t)token * 32 + t] * scl - shf;
  } else if (t < 64) {
    int j = t - 32;
    const float* tr = tau + (size_t)token * 8;
    float a;
    if (j < 31) { a = tb[j]; for (int k = 0; k < 8; k++) a += tr[k] * tw[k * 31 + j]; a = sinf(a); }
    else        { a = tb0[0]; for (int k = 0; k < 8; k++) a += tr[k] * tw0[k]; }
    te[j] = a;
  }
  __syncthreads();
  float acc;
  if (t < 128) {
    acc = membB[t];
    for (int f = 0; f < 32; f++) acc += xs[f] * membW[f * 128 + t];
  } else {
    int d = t - 128;
    acc = tprojB[d];
    for (int j = 0; j < 32; j++) acc += te[j] * tprojW[j * 128 + d];
  }
  h_hf[(size_t)token * DMOD + t] = (_Float16)acc;
}

// ---------------- all weight transpose-converts in ONE launch ----------------
__device__ __forceinline__ void convT_one(const float* __restrict__ W, _Float16* __restrict__ WT,
                                          int K, int N, int Kout, int Nout, int idx) {
  int per = Nout * Kout;
  int l = idx / per; int rem = idx - l * per;
  int n = rem / Kout; int k = rem - n * Kout;
  const float* Wl = W + (size_t)l * K * N;
  float v = (k < K && n < N) ? Wl[(size_t)k * N + n] : 0.f;
  WT[(size_t)l * per + rem] = (_Float16)v;
}

__global__ __launch_bounds__(256) void convall_k(
    const float* ffn_W1, const float* ffn_W2, const float* inproj_W,
    const float* outproj_W, const float* mlp_W1, const float* mlp_W2,
    _Float16* ffn1T, _Float16* ffn2T, _Float16* inprojT,
    _Float16* outprojT, _Float16* mlp1T, _Float16* mlp2T) {
  int g = blockIdx.x, t = threadIdx.x;
  if (g < 1408)            convT_one(ffn_W1, ffn1T, 256, 1364, 256, 1408, g * 256 + t);
  else if (g < 2112)       convT_one(ffn_W2, ffn2T, 682, 256, 704, 256, (g - 1408) * 256 + t);
  else if (g < 10304)      convT_one(inproj_W, inprojT, 256, 1024, 256, 1024, (g - 2112) * 256 + t);
  else if (g < 14400)      convT_one(outproj_W, outprojT, 512, 256, 512, 256, (g - 10304) * 256 + t);
  else if (g < 18496)      convT_one(mlp_W1, mlp1T, 256, 512, 256, 512, (g - 14400) * 256 + t);
  else                     convT_one(mlp_W2, mlp2T, 256, 256, 256, 256, (g - 18496) * 256 + t);
}

// ---------------- plain f16 MFMA GEMM 64x64 tile (A stride == K) ----------------
__global__ __launch_bounds__(256) void gemm_hf_k(
    const _Float16* __restrict__ A, const _Float16* __restrict__ WT,
    const float* __restrict__ bias, float* __restrict__ C,
    int M, int Nstore, int K, int ldc, int flags) {
  __shared__ _Float16 As[64][40];
  __shared__ _Float16 Bs[64][40];
  int bm = blockIdx.y * 64, bn = blockIdx.x * 64;
  int t = threadIdx.x;
  int w = t >> 6, l = t & 63;
  int wm = w >> 1, wn = w & 1;
  int srow = t >> 2, sk = (t & 3) * 8;
  f32x4 acc[2][2] = {};
  int lr = l & 15, lk = (l >> 4) * 8;
  for (int k0 = 0; k0 < K; k0 += 32) {
    *(uint4*)&As[srow][sk] = *(const uint4*)&A[(size_t)(bm + srow) * K + k0 + sk];
    *(uint4*)&Bs[srow][sk] = *(const uint4*)&WT[(size_t)(bn + srow) * K + k0 + sk];
    __syncthreads();
    f16x8 a0 = *(const f16x8*)&As[wm * 32 + lr][lk];
    f16x8 a1 = *(const f16x8*)&As[wm * 32 + 16 + lr][lk];
    f16x8 b0 = *(const f16x8*)&Bs[wn * 32 + lr][lk];
    f16x8 b1 = *(const f16x8*)&Bs[wn * 32 + 16 + lr][lk];
    acc[0][0] = __builtin_amdgcn_mfma_f32_16x16x32_f16(a0, b0, acc[0][0], 0, 0, 0);
    acc[0][1] = __builtin_amdgcn_mfma_f32_16x16x32_f16(a0, b1, acc[0][1], 0, 0, 0);
    acc[1][0] = __builtin_amdgcn_mfma_f32_16x16x32_f16(a1, b0, acc[1][0], 0, 0, 0);
    acc[1][1] = __builtin_amdgcn_mfma_f32_16x16x32_f16(a1, b1, acc[1][1], 0, 0, 0);
    __syncthreads();
  }
  int lq = l >> 4;
#pragma unroll
  for (int i = 0; i < 2; i++) {
#pragma unroll
    for (int j = 0; j < 2; j++) {
      int col = bn + wn * 32 + j * 16 + lr;
      if (col >= Nstore) continue;
      float bv = bias ? bias[col] : 0.f;
#pragma unroll
      for (int r = 0; r < 4; r++) {
        int row = bm + wm * 32 + i * 16 + lq * 4 + r;
        float v = acc[i][j][r] + bv;
        size_t idx = (size_t)row * ldc + col;
        if (flags & 1) v += C[idx];
        C[idx] = v;
      }
    }
  }
}

// ---------------- FFN GLU (a * gelu_exact(g)) -> f16 padded to 704 ----------------
__global__ __launch_bounds__(256) void glugelu_k(const float* __restrict__ big, _Float16* __restrict__ out) {
  int i = blockIdx.x * 256 + threadIdx.x; // BL*704
  int token = i / 704, j = i - token * 704;
  float r = 0.f;
  if (j < 682) {
    float a = big[(size_t)token * 1364 + j];
    float g = big[(size_t)token * 1364 + 682 + j];
    r = a * 0.5f * g * (1.f + erff(g * 0.70710678118654752f));
  }
  out[i] = (_Float16)r;
}

// ---------------- LayerNorm, 4 rows/block (wave per row) -> f16 ----------------
__global__ __launch_bounds__(256) void ln4_k(const float* __restrict__ x, const float* __restrict__ w,
                                             const float* __restrict__ b, _Float16* __restrict__ out) {
  int row = blockIdx.x * 4 + (threadIdx.x >> 6), lane = threadIdx.x & 63;
  const float* rp = x + (size_t)row * 256;
  float4 v = *(const float4*)&rp[lane * 4];
  float s = v.x + v.y + v.z + v.w;
  float ss = v.x * v.x + v.y * v.y + v.z * v.z + v.w * v.w;
#pragma unroll
  for (int o = 32; o; o >>= 1) { s += __shfl_xor(s, o, 64); ss += __shfl_xor(ss, o, 64); }
  float mu = s * (1.f / 256.f);
  float var = ss * (1.f / 256.f) - mu * mu;
  float rs = rsqrtf(var + 1e-5f);
  float4 wv = *(const float4*)&w[lane * 4];
  float4 bv = *(const float4*)&b[lane * 4];
  f16x4 o4;
  o4[0] = (_Float16)((v.x - mu) * rs * wv.x + bv.x);
  o4[1] = (_Float16)((v.y - mu) * rs * wv.y + bv.y);
  o4[2] = (_Float16)((v.z - mu) * rs * wv.z + bv.z);
  o4[3] = (_Float16)((v.w - mu) * rs * wv.w + bv.w);
  *(f16x4*)&out[(size_t)row * 256 + lane * 4] = o4;
}

// ---------------- fused conv4+silu -> xproj -> dtproj+softplus ----------------
__global__ __launch_bounds__(128) void convxdt_k(
    const float* __restrict__ big, const float* __restrict__ cw, const float* __restrict__ cb,
    const float* __restrict__ xW, const float* __restrict__ dW, const float* __restrict__ dbias,
    float* __restrict__ ucv, float* __restrict__ xd, float* __restrict__ dt) {
  __shared__ float us[512];
  __shared__ float xs[48];
  int token = ((blockIdx.x & 7) << 8) | (blockIdx.x >> 3);
  int b = token >> 9, l = token & 511;
  int t = threadIdx.x;
  for (int c = t; c < 512; c += 128) {
    float acc = cb[c];
#pragma unroll
    for (int k = 0; k < 4; k++) {
      int l2 = l - 3 + k;
      if (l2 >= 0) acc += big[((size_t)(b * LSEQ + l2)) * 1024 + c] * cw[c * 4 + k];
    }
    float u = siluf_(acc);
    us[c] = u;
    ucv[(size_t)token * 512 + c] = u;
  }
  __syncthreads();
  float part = 0.f;
  int j = t >> 1, p = t & 1;
  if (t < 96) {
    for (int c = p * 256; c < p * 256 + 256; c++) part += us[c] * xW[c * 48 + j];
  }
  part += __shfl_xor(part, 1, 64);
  if (t < 96 && p == 0) {
    xs[j] = part;
    xd[(size_t)token * 48 + j] = part;
  }
  __syncthreads();
  for (int c = t; c < 512; c += 128) {
    float acc = dbias[c];
#pragma unroll
    for (int r = 0; r < 16; r++) acc += xs[r] * dW[r * 512 + c];
    dt[(size_t)token * 512 + c] = (acc > 20.f) ? acc : log1pf(__expf(acc));
  }
}

// ---------------- scan v2: thread = (chunk, channel), 16 states in registers ----------------
// 128 blocks = (b, dgroup of 16 channels); 256 threads = 16 chunks x 16 channels.
// All global loads/stores coalesced across dl; n-reduction in registers (no shuffles).
// Bn/Cn staged via LDS by the owning wave (wave-synchronous, no barrier needed).
__global__ __launch_bounds__(256) void scan_k(
    const float* __restrict__ dt, const float* __restrict__ ucv, const float* __restrict__ xd,
    const float* __restrict__ zbuf, const float* __restrict__ A_log, const float* __restrict__ D_p,
    _Float16* __restrict__ gout) {
  __shared__ float PsL[16][16][17];   // [c][dl][n] (+pad)
  __shared__ float HsL[16][16][17];
  __shared__ float BnS[16][16];
  __shared__ float CnS[16][16];
  int bid = blockIdx.x;
  int b = bid >> 5, dg = bid & 31;
  int t = threadIdx.x;
  int c = t >> 4, dl = t & 15;
  int d = dg * 16 + dl;
  float An[16];
#pragma unroll
  for (int n = 0; n < 16; n++) An[n] = -__expf(A_log[(size_t)d * 16 + n]);
  float P[16], H[16];
#pragma unroll
  for (int n = 0; n < 16; n++) { P[n] = 1.f; H[n] = 0.f; }
  int t0 = b * LSEQ + c * 32;
  for (int tt = 0; tt < 32; tt++) {
    int token = t0 + tt;
    float dtv = dt[(size_t)token * 512 + d];
    float uv = ucv[(size_t)token * 512 + d];
    BnS[c][dl] = xd[(size_t)token * 48 + 16 + dl];
    float x = dtv * uv;
#pragma unroll
    for (int n = 0; n < 16; n++) {
      float dA = __expf(dtv * An[n]);
      P[n] *= dA;
      H[n] = dA * H[n] + x * BnS[c][n];
    }
  }
#pragma unroll
  for (int n = 0; n < 16; n++) { PsL[c][dl][n] = P[n]; HsL[c][dl][n] = H[n]; }
  __syncthreads();
  {
    int n2 = t >> 4, dl2 = t & 15;
    float hc = 0.f;
#pragma unroll
    for (int c2 = 0; c2 < 16; c2++) {
      float Pv = PsL[c2][dl2][n2];
      float Hv = HsL[c2][dl2][n2];
      PsL[c2][dl2][n2] = hc;   // Hin (state before chunk c2)
      hc = Pv * hc + Hv;
    }
  }
  __syncthreads();
  float h[16];
#pragma unroll
  for (int n = 0; n < 16; n++) h[n] = PsL[c][dl][n];
  float Dd = D_p[d];
  for (int tt = 0; tt < 32; tt++) {
    int token = t0 + tt;
    float dtv = dt[(size_t)token * 512 + d];
    float uv = ucv[(size_t)token * 512 + d];
    float zv = zbuf[(size_t)token * 1024 + 512 + d];
    BnS[c][dl] = xd[(size_t)token * 48 + 16 + dl];
    CnS[c][dl] = xd[(size_t)token * 48 + 32 + dl];
    float x = dtv * uv;
    float y = 0.f;
#pragma unroll
    for (int n = 0; n < 16; n++) {
      float dA = __expf(dtv * An[n]);
      h[n] = dA * h[n] + x * BnS[c][n];
      y += h[n] * CnS[c][n];
    }
    gout[(size_t)token * 512 + d] = (_Float16)((y + uv * Dd) * siluf_(zv));
  }
}

// ---------------- SwiGLU for mlp: silu(g1)*g2 -> f16 ----------------
__global__ __launch_bounds__(256) void silumul_k(const float* __restrict__ big, _Float16* __restrict__ out) {
  int i = blockIdx.x * 256 + threadIdx.x; // BL*256
  int token = i >> 8, j = i & 255;
  float g1 = big[(size_t)token * 512 + j];
  float g2 = big[(size_t)token * 512 + 256 + j];
  out[i] = (_Float16)(siluf_(g1) * g2);
}

// ---------------- head: wide kernels with K-split GEMMs ----------------
__global__ __launch_bounds__(256) void lnf_k(const float* __restrict__ h, const float* __restrict__ nfw,
                                             const float* __restrict__ nfb, float* __restrict__ f) {
  __shared__ float red[4];
  int b = blockIdx.x, t = threadIdx.x;
  int lane = t & 63, wid = t >> 6;
  float v = h[((size_t)b * LSEQ + (LSEQ - 1)) * DMOD + t];
  float s = v;
#pragma unroll
  for (int o = 32; o; o >>= 1) s += __shfl_xor(s, o, 64);
  if (lane == 0) red[wid] = s;
  __syncthreads();
  float mu = (red[0] + red[1] + red[2] + red[3]) * (1.f / 256.f);
  float dv = v - mu;
  s = dv * dv;
#pragma unroll
  for (int o = 32; o; o >>= 1) s += __shfl_xor(s, o, 64);
  __syncthreads();
  if (lane == 0) red[wid] = s;
  __syncthreads();
  float var = (red[0] + red[1] + red[2] + red[3]) * (1.f / 256.f);
  f[b * 256 + t] = dv * rsqrtf(var + 1e-5f) * nfw[t] + nfb[t];
}

__global__ __launch_bounds__(256) void hgemm1_k(const float* __restrict__ f,
    const float* vW1, const float* vb1, const float* aW1, const float* ab1,
    float* __restrict__ a1) {
  int cb = blockIdx.x, b = blockIdx.y, p = blockIdx.z;
  const float* W1 = p ? aW1 : vW1;
  const float* b1 = p ? ab1 : vb1;
  __shared__ float fs[256];
  __shared__ float part[4][64];
  int t = threadIdx.x;
  fs[t] = f[b * 256 + t];
  __syncthreads();
  int col = cb * 64 + (t & 63);
  int kp = t >> 6;
  float acc = 0.f;
#pragma unroll 8
  for (int k = 0; k < 64; k++) acc += fs[kp * 64 + k] * W1[(size_t)(kp * 64 + k) * 512 + col];
  part[kp][t & 63] = acc;
  __syncthreads();
  if (t < 64) {
    float v = part[0][t] + part[1][t] + part[2][t] + part[3][t] + b1[cb * 64 + t];
    a1[((b * 2 + p) * 512) + cb * 64 + t] = v;
  }
}

__global__ __launch_bounds__(512) void hln1_k(const float* __restrict__ a1,
    const float* vl1w, const float* vl1b, const float* al1w, const float* al1b,
    float* __restrict__ t1) {
  __shared__ float red[8];
  int b = blockIdx.x, p = blockIdx.y, t = threadIdx.x;
  const float* lw = p ? al1w : vl1w;
  const float* lb = p ? al1b : vl1b;
  int lane = t & 63, wid = t >> 6;
  int idx = (b * 2 + p) * 512 + t;
  float v = a1[idx];
  float s = v;
#pragma unroll
  for (int o = 32; o; o >>= 1) s += __shfl_xor(s, o, 64);
  if (lane == 0) red[wid] = s;
  __syncthreads();
  float S = 0.f;
#pragma unroll
  for (int k = 0; k < 8; k++) S += red[k];
  float mu = S * (1.f / 512.f);
  float dv = v - mu;
  s = dv * dv;
#pragma unroll
  for (int o = 32; o; o >>= 1) s += __shfl_xor(s, o, 64);
  __syncthreads();
  if (lane == 0) red[wid] = s;
  __syncthreads();
  S = 0.f;
#pragma unroll
  for (int k = 0; k < 8; k++) S += red[k];
  float var = S * (1.f / 512.f);
  t1[idx] = fmaxf(dv * rsqrtf(var + 1e-5f) * lw[t] + lb[t], 0.f);
}

__global__ __launch_bounds__(256) void hgemm2_k(const float* __restrict__ t1,
    const float* vW2, const float* vb2, const float* aW2, const float* ab2,
    float* __restrict__ a2) {
  int cb = blockIdx.x, b = blockIdx.y, p = blockIdx.z;
  const float* W2 = p ? aW2 : vW2;
  const float* b2 = p ? ab2 : vb2;
  __shared__ float ts[512];
  __shared__ float part[4][64];
  int t = threadIdx.x;
  ts[t] = t1[(b * 2 + p) * 512 + t];
  ts[256 + t] = t1[(b * 2 + p) * 512 + 256 + t];
  __syncthreads();
  int col = cb * 64 + (t & 63);
  int kp = t >> 6;
  float acc = 0.f;
#pragma unroll 8
  for (int k = 0; k < 128; k++) acc += ts[kp * 128 + k] * W2[(size_t)(kp * 128 + k) * 256 + col];
  part[kp][t & 63] = acc;
  __syncthreads();
  if (t < 64) {
    float v = part[0][t] + part[1][t] + part[2][t] + part[3][t] + b2[cb * 64 + t];
    a2[(b * 2 + p) * 256 + cb * 64 + t] = v;
  }
}

__global__ __launch_bounds__(256) void hln2_k(const float* __restrict__ a2,
    const float* vl2w, const float* vl2b, const float* al2w, const float* al2b,
    float* __restrict__ t2) {
  __shared__ float red[4];
  int b = blockIdx.x, p = blockIdx.y, t = threadIdx.x;
  const float* lw = p ? al2w : vl2w;
  const float* lb = p ? al2b : vl2b;
  int lane = t & 63, wid = t >> 6;
  int idx = (b * 2 + p) * 256 + t;
  float v = a2[idx];
  float s = v;
#pragma unroll
  for (int o = 32; o; o >>= 1) s += __shfl_xor(s, o, 64);
  if (lane == 0) red[wid] = s;
  __syncthreads();
  float mu = (red[0] + red[1] + red[2] + red[3]) * (1.f / 256.f);
  float dv = v - mu;
  s = dv * dv;
#pragma unroll
  for (int o = 32; o; o >>= 1) s += __shfl_xor(s, o, 64);
  __syncthreads();
  if (lane == 0) red[wid] = s;
  __syncthreads();
  float var = (red[0] + red[1] + red[2] + red[3]) * (1.f / 256.f);
  t2[idx] = fmaxf(dv * rsqrtf(var + 1e-5f) * lw[t] + lb[t], 0.f);
}

__global__ __launch_bounds__(256) void hfinal_k(const float* __restrict__ t2,
    const float* vW3, const float* vb3, const float* aW3, const float* ab3,
    float* __restrict__ q) {
  __shared__ float a3s[24];
  int t = threadIdx.x;
  int g = t >> 3, ln8 = t & 7;
  if (g < 24) {
    int b = g / 6, r = g - b * 6;
    int p = r ? 1 : 0;
    int o = r ? r - 1 : 0;
    const float* W3 = p ? aW3 : vW3;
    const float* b3 = p ? ab3 : vb3;
    int nout = p ? 5 : 1;
    const float* t2r = t2 + (b * 2 + p) * 256;
    float acc = 0.f;
    for (int k = ln8; k < 256; k += 8) acc += t2r[k] * W3[k * nout + o];
    acc += __shfl_xor(acc, 1, 64);
    acc += __shfl_xor(acc, 2, 64);
    acc += __shfl_xor(acc, 4, 64);
    if (ln8 == 0) a3s[g] = acc + b3[o];
  }
  __syncthreads();
  if (t < 20) {
    int b = t / 5, a = t - b * 5;
    float val = a3s[b * 6];
    float m = 0.f;
#pragma unroll
    for (int j = 0; j < 5; j++) m += a3s[b * 6 + 1 + j];
    m *= 0.2f;
    q[b * 5 + a] = val + a3s[b * 6 + 1 + a] - m;
  }
}

extern "C" void kernel_launch(void* const* d_in, const int* in_sizes, int n_in,
                              void* d_out, int out_size, void* d_ws, size_t ws_size,
                              hipStream_t stream) {
  const float* src = (const float*)d_in[0];
  const float* tau = (const float*)d_in[1];
  const float* dain_Wm = (const float*)d_in[2];
  const float* dain_Ws = (const float*)d_in[3];
  const float* dain_Wg = (const float*)d_in[4];
  const float* dain_bg = (const float*)d_in[5];
  const float* memb_W = (const float*)d_in[6];
  const float* memb_b = (const float*)d_in[7];
  const float* t_w0 = (const float*)d_in[8];
  const float* t_b0 = (const float*)d_in[9];
  const float* t_w = (const float*)d_in[10];
  const float* t_b = (const float*)d_in[11];
  const float* tproj_W = (const float*)d_in[12];
  const float* tproj_b = (const float*)d_in[13];
  const float* ffn_W1 = (const float*)d_in[14];
  const float* ffn_b1 = (const float*)d_in[15];
  const float* ffn_W2 = (const float*)d_in[16];
  const float* ffn_b2 = (const float*)d_in[17];
  const float* n1_w = (const float*)d_in[18];
  const float* n1_b = (const float*)d_in[19];
  const float* inproj_W = (const float*)d_in[20];
  const float* conv_w = (const float*)d_in[21];
  const float* conv_b = (const float*)d_in[22];
  const float* xproj_W = (const float*)d_in[23];
  const float* dtproj_W = (const float*)d_in[24];
  const float* dt_bias = (const float*)d_in[25];
  const float* A_log = (const float*)d_in[26];
  const float* D_p = (const float*)d_in[27];
  const float* outproj_W = (const float*)d_in[28];
  const float* n2_w = (const float*)d_in[29];
  const float* n2_b = (const float*)d_in[30];
  const float* mlp_W1 = (const float*)d_in[31];
  const float* mlp_W2 = (const float*)d_in[32];
  const float* nf_w = (const float*)d_in[33];
  const float* nf_b = (const float*)d_in[34];
  const float* vW1 = (const float*)d_in[35]; const float* vb1 = (const float*)d_in[36];
  const float* vl1w = (const float*)d_in[37]; const float* vl1b = (const float*)d_in[38];
  const float* vW2 = (const float*)d_in[39]; const float* vb2 = (const float*)d_in[40];
  const float* vl2w = (const float*)d_in[41]; const float* vl2b = (const float*)d_in[42];
  const float* vW3 = (const float*)d_in[43]; const float* vb3 = (const float*)d_in[44];
  const float* aW1 = (const float*)d_in[45]; const float* ab1 = (const float*)d_in[46];
  const float* al1w = (const float*)d_in[47]; const float* al1b = (const float*)d_in[48];
  const float* aW2 = (const float*)d_in[49]; const float* ab2 = (const float*)d_in[50];
  const float* al2w = (const float*)d_in[51]; const float* al2b = (const float*)d_in[52];
  const float* aW3 = (const float*)d_in[53]; const float* ab3 = (const float*)d_in[54];
  float* out = (float*)d_out;

  float* ws = (float*)d_ws;
  float* dstats = ws;                      // 256
  float* h    = dstats + 256;              // BL*256
  float* big  = h + (size_t)BL * DMOD;     // BL*1408
  float* ucv  = big + (size_t)BL * 1408;   // BL*512
  float* xd   = ucv + (size_t)BL * DIN;    // BL*48
  float* dt   = xd + (size_t)BL * 48;      // BL*512
  float* fh   = dt + (size_t)BL * DIN;     // 1024
  float* a1   = fh + 1024;                 // 4096
  float* t1   = a1 + 4096;                 // 4096
  float* a2   = t1 + 4096;                 // 2048
  float* t2   = a2 + 2048;                 // 2048
  float* fp_end = t2 + 2048;
  _Float16* h_hf    = (_Float16*)fp_end;            // BL*256
  _Float16* hn_hf   = h_hf + (size_t)BL * DMOD;     // BL*256
  _Float16* mid_hf  = hn_hf + (size_t)BL * DMOD;    // BL*704
  _Float16* gout_hf = mid_hf + (size_t)BL * 704;    // BL*512
  _Float16* ffn1T   = gout_hf + (size_t)BL * DIN;   // 1408*256
  _Float16* ffn2T   = ffn1T + (size_t)1408 * 256;   // 256*704
  _Float16* inprojT = ffn2T + (size_t)256 * 704;    // 8*1024*256
  _Float16* outprojT = inprojT + (size_t)8 * 1024 * 256;
  _Float16* mlp1T   = outprojT + (size_t)8 * 256 * 512;
  _Float16* mlp2T   = mlp1T + (size_t)8 * 512 * 256;

  convall_k<<<20544, 256, 0, stream>>>(ffn_W1, ffn_W2, inproj_W, outproj_W, mlp_W1, mlp_W2,
                                       ffn1T, ffn2T, inprojT, outprojT, mlp1T, mlp2T);
  dain_k<<<1, 1024, 0, stream>>>(src, dain_Wm, dain_Ws, dain_Wg, dain_bg, dstats);
  embed_k<<<BL, 256, 0, stream>>>(src, tau, dstats, memb_W, memb_b, t_w0, t_b0, t_w, t_b, tproj_W, tproj_b, h_hf);
  gemm_hf_k<<<dim3(22, 32), 256, 0, stream>>>(h_hf, ffn1T, ffn_b1, big, BL, 1364, 256, 1364, 0);
  glugelu_k<<<BL * 704 / 256, 256, 0, stream>>>(big, mid_hf);
  gemm_hf_k<<<dim3(4, 32), 256, 0, stream>>>(mid_hf, ffn2T, ffn_b2, h, BL, 256, 704, 256, 0);

  for (int i = 0; i < 8; i++) {
    ln4_k<<<BL / 4, 256, 0, stream>>>(h, n1_w + i * 256, n1_b + i * 256, hn_hf);
    gemm_hf_k<<<dim3(16, 32), 256, 0, stream>>>(hn_hf, inprojT + (size_t)i * 1024 * 256, nullptr, big,
                                                BL, 1024, 256, 1024, 0);
    convxdt_k<<<BL, 128, 0, stream>>>(big, conv_w + (size_t)i * 512 * 4, conv_b + i * 512,
                                      xproj_W + (size_t)i * 512 * 48, dtproj_W + (size_t)i * 16 * 512,
                                      dt_bias + i * 512, ucv, xd, dt);
    scan_k<<<128, 256, 0, stream>>>(dt, ucv, xd, big, A_log + (size_t)i * 512 * 16, D_p + i * 512, gout_hf);
    gemm_hf_k<<<dim3(4, 32), 256, 0, stream>>>(gout_hf, outprojT + (size_t)i * 256 * 512, nullptr, h,
                                               BL, 256, 512, 256, 1);
    ln4_k<<<BL / 4, 256, 0, stream>>>(h, n2_w + i * 256, n2_b + i * 256, hn_hf);
    gemm_hf_k<<<dim3(8, 32), 256, 0, stream>>>(hn_hf, mlp1T + (size_t)i * 512 * 256, nullptr, big,
                                               BL, 512, 256, 512, 0);
    silumul_k<<<BL, 256, 0, stream>>>(big, mid_hf);
    gemm_hf_k<<<dim3(4, 32), 256, 0, stream>>>(mid_hf, mlp2T + (size_t)i * 256 * 256, nullptr, h,
                                               BL, 256, 256, 256, 1);
  }

  lnf_k<<<NB, 256, 0, stream>>>(h, nf_w, nf_b, fh);
  hgemm1_k<<<dim3(8, 4, 2), 256, 0, stream>>>(fh, vW1, vb1, aW1, ab1, a1);
  hln1_k<<<dim3(4, 2), 512, 0, stream>>>(a1, vl1w, vl1b, al1w, al1b, t1);
  hgemm2_k<<<dim3(4, 4, 2), 256, 0, stream>>>(t1, vW2, vb2, aW2, ab2, a2);
  hln2_k<<<dim3(4, 2), 256, 0, stream>>>(a2, vl2w, vl2b, al2w, al2b, t2);
  hfinal_k<<<1, 256, 0, stream>>>(t2, vW3, vb3, aW3, ab3, out);
  (void)in_sizes; (void)n_in; (void)out_size; (void)ws_size;
}

// Round 13
// 917.241 us; speedup vs baseline: 1.5536x; 1.1294x over previous
//
#include <hip/hip_runtime.h>
#include <math.h>

// Model constants
#define BL   2048   // B*L = 4*512
#define LSEQ 512
#define NB   4
#define DMOD 256
#define DIN  512
#define NCH  (NB * DIN)

typedef __attribute__((ext_vector_type(4))) float f32x4;
typedef __attribute__((ext_vector_type(8))) _Float16 f16x8;
typedef __attribute__((ext_vector_type(4))) _Float16 f16x4;

__device__ __forceinline__ float sigmoidf_(float x) { return 1.f / (1.f + __expf(-x)); }
__device__ __forceinline__ float siluf_(float x) { return x / (1.f + __expf(-x)); }

// ---------------- DAIN stats (single block) ----------------
__global__ __launch_bounds__(1024) void dain_k(
    const float* __restrict__ src, const float* __restrict__ Wm,
    const float* __restrict__ Ws, const float* __restrict__ Wg,
    const float* __restrict__ bg, float* __restrict__ stats) {
  __shared__ float part[1024];
  __shared__ float avg_s[128], sub_s[128], std_s[128], mn_s[128], inv_s[128];
  int tid = threadIdx.x;
  int p = tid >> 3, j = tid & 7;
  int b = p >> 5, f = p & 31;
  float s = 0.f;
  for (int l = j * 64; l < j * 64 + 64; ++l) s += src[((size_t)b * LSEQ + l) * 32 + f];
  part[tid] = s;
  __syncthreads();
  if (tid < 128) { float a = 0; for (int k = 0; k < 8; k++) a += part[tid * 8 + k]; avg_s[tid] = a * (1.f / 512.f); }
  __syncthreads();
  if (tid < 128) {
    int bb = tid >> 5, ff = tid & 31;
    float a = 0; for (int g = 0; g < 32; g++) a += avg_s[bb * 32 + g] * Wm[ff * 32 + g];
    sub_s[tid] = a;
  }
  __syncthreads();
  float sub = sub_s[p];
  s = 0.f;
  for (int l = j * 64; l < j * 64 + 64; ++l) {
    float v = src[((size_t)b * LSEQ + l) * 32 + f] - sub; s += v * v;
  }
  part[tid] = s;
  __syncthreads();
  if (tid < 128) { float a = 0; for (int k = 0; k < 8; k++) a += part[tid * 8 + k]; std_s[tid] = sqrtf(a * (1.f / 512.f)); }
  __syncthreads();
  if (tid < 128) {
    int bb = tid >> 5, ff = tid & 31;
    float a = 0; for (int g = 0; g < 32; g++) a += std_s[bb * 32 + g] * Ws[ff * 32 + g];
    if (a <= 1e-8f) a = 1.f;
    inv_s[tid] = 1.f / a;
    mn_s[tid] = (avg_s[tid] - sub_s[tid]) / a;
  }
  __syncthreads();
  if (tid < 128) {
    int bb = tid >> 5, ff = tid & 31;
    float a = bg[ff]; for (int g = 0; g < 32; g++) a += mn_s[bb * 32 + g] * Wg[ff * 32 + g];
    float gate = sigmoidf_(a);
    float scl = gate * inv_s[tid];
    stats[tid] = scl;
    stats[128 + tid] = sub_s[tid] * scl;
  }
}

// ---------------- embed -> h_hf (f16) ----------------
__global__ __launch_bounds__(256) void embed_k(
    const float* __restrict__ src, const float* __restrict__ tau,
    const float* __restrict__ stats, const float* __restrict__ membW,
    const float* __restrict__ membB, const float* __restrict__ tw0,
    const float* __restrict__ tb0, const float* __restrict__ tw,
    const float* __restrict__ tb, const float* __restrict__ tprojW,
    const float* __restrict__ tprojB, _Float16* __restrict__ h_hf) {
  int token = blockIdx.x;
  int b = token >> 9;
  int t = threadIdx.x;
  __shared__ float xs[32], te[32];
  if (t < 32) {
    float scl = stats[b * 32 + t], shf = stats[128 + b * 32 + t];
    xs[t] = src[(size_t)token * 32 + t] * scl - shf;
  } else if (t < 64) {
    int j = t - 32;
    const float* tr = tau + (size_t)token * 8;
    float a;
    if (j < 31) { a = tb[j]; for (int k = 0; k < 8; k++) a += tr[k] * tw[k * 31 + j]; a = sinf(a); }
    else        { a = tb0[0]; for (int k = 0; k < 8; k++) a += tr[k] * tw0[k]; }
    te[j] = a;
  }
  __syncthreads();
  float acc;
  if (t < 128) {
    acc = membB[t];
    for (int f = 0; f < 32; f++) acc += xs[f] * membW[f * 128 + t];
  } else {
    int d = t - 128;
    acc = tprojB[d];
    for (int j = 0; j < 32; j++) acc += te[j] * tprojW[j * 128 + d];
  }
  h_hf[(size_t)token * DMOD + t] = (_Float16)acc;
}

// ---------------- all weight transpose-converts in ONE launch ----------------
__device__ __forceinline__ void convT_one(const float* __restrict__ W, _Float16* __restrict__ WT,
                                          int K, int N, int Kout, int Nout, int idx) {
  int per = Nout * Kout;
  int l = idx / per; int rem = idx - l * per;
  int n = rem / Kout; int k = rem - n * Kout;
  const float* Wl = W + (size_t)l * K * N;
  float v = (k < K && n < N) ? Wl[(size_t)k * N + n] : 0.f;
  WT[(size_t)l * per + rem] = (_Float16)v;
}

__global__ __launch_bounds__(256) void convall_k(
    const float* ffn_W1, const float* ffn_W2, const float* inproj_W,
    const float* outproj_W, const float* mlp_W1, const float* mlp_W2,
    _Float16* ffn1T, _Float16* ffn2T, _Float16* inprojT,
    _Float16* outprojT, _Float16* mlp1T, _Float16* mlp2T) {
  int g = blockIdx.x, t = threadIdx.x;
  if (g < 1408)            convT_one(ffn_W1, ffn1T, 256, 1364, 256, 1408, g * 256 + t);
  else if (g < 2112)       convT_one(ffn_W2, ffn2T, 682, 256, 704, 256, (g - 1408) * 256 + t);
  else if (g < 10304)      convT_one(inproj_W, inprojT, 256, 1024, 256, 1024, (g - 2112) * 256 + t);
  else if (g < 14400)      convT_one(outproj_W, outprojT, 512, 256, 512, 256, (g - 10304) * 256 + t);
  else if (g < 18496)      convT_one(mlp_W1, mlp1T, 256, 512, 256, 512, (g - 14400) * 256 + t);
  else                     convT_one(mlp_W2, mlp2T, 256, 256, 256, 256, (g - 18496) * 256 + t);
}

// ---------------- plain f16 MFMA GEMM 64x64 tile (A stride == K) ----------------
__global__ __launch_bounds__(256) void gemm_hf_k(
    const _Float16* __restrict__ A, const _Float16* __restrict__ WT,
    const float* __restrict__ bias, float* __restrict__ C,
    int M, int Nstore, int K, int ldc, int flags) {
  __shared__ _Float16 As[64][40];
  __shared__ _Float16 Bs[64][40];
  int bm = blockIdx.y * 64, bn = blockIdx.x * 64;
  int t = threadIdx.x;
  int w = t >> 6, l = t & 63;
  int wm = w >> 1, wn = w & 1;
  int srow = t >> 2, sk = (t & 3) * 8;
  f32x4 acc[2][2] = {};
  int lr = l & 15, lk = (l >> 4) * 8;
  for (int k0 = 0; k0 < K; k0 += 32) {
    *(uint4*)&As[srow][sk] = *(const uint4*)&A[(size_t)(bm + srow) * K + k0 + sk];
    *(uint4*)&Bs[srow][sk] = *(const uint4*)&WT[(size_t)(bn + srow) * K + k0 + sk];
    __syncthreads();
    f16x8 a0 = *(const f16x8*)&As[wm * 32 + lr][lk];
    f16x8 a1 = *(const f16x8*)&As[wm * 32 + 16 + lr][lk];
    f16x8 b0 = *(const f16x8*)&Bs[wn * 32 + lr][lk];
    f16x8 b1 = *(const f16x8*)&Bs[wn * 32 + 16 + lr][lk];
    acc[0][0] = __builtin_amdgcn_mfma_f32_16x16x32_f16(a0, b0, acc[0][0], 0, 0, 0);
    acc[0][1] = __builtin_amdgcn_mfma_f32_16x16x32_f16(a0, b1, acc[0][1], 0, 0, 0);
    acc[1][0] = __builtin_amdgcn_mfma_f32_16x16x32_f16(a1, b0, acc[1][0], 0, 0, 0);
    acc[1][1] = __builtin_amdgcn_mfma_f32_16x16x32_f16(a1, b1, acc[1][1], 0, 0, 0);
    __syncthreads();
  }
  int lq = l >> 4;
#pragma unroll
  for (int i = 0; i < 2; i++) {
#pragma unroll
    for (int j = 0; j < 2; j++) {
      int col = bn + wn * 32 + j * 16 + lr;
      if (col >= Nstore) continue;
      float bv = bias ? bias[col] : 0.f;
#pragma unroll
      for (int r = 0; r < 4; r++) {
        int row = bm + wm * 32 + i * 16 + lq * 4 + r;
        float v = acc[i][j][r] + bv;
        size_t idx = (size_t)row * ldc + col;
        if (flags & 1) v += C[idx];
        C[idx] = v;
      }
    }
  }
}

// ---------------- FFN GLU (a * gelu_exact(g)) -> f16 padded to 704 ----------------
__global__ __launch_bounds__(256) void glugelu_k(const float* __restrict__ big, _Float16* __restrict__ out) {
  int i = blockIdx.x * 256 + threadIdx.x; // BL*704
  int token = i / 704, j = i - token * 704;
  float r = 0.f;
  if (j < 682) {
    float a = big[(size_t)token * 1364 + j];
    float g = big[(size_t)token * 1364 + 682 + j];
    r = a * 0.5f * g * (1.f + erff(g * 0.70710678118654752f));
  }
  out[i] = (_Float16)r;
}

// ---------------- LayerNorm, 4 rows/block (wave per row) -> f16 ----------------
__global__ __launch_bounds__(256) void ln4_k(const float* __restrict__ x, const float* __restrict__ w,
                                             const float* __restrict__ b, _Float16* __restrict__ out) {
  int row = blockIdx.x * 4 + (threadIdx.x >> 6), lane = threadIdx.x & 63;
  const float* rp = x + (size_t)row * 256;
  float4 v = *(const float4*)&rp[lane * 4];
  float s = v.x + v.y + v.z + v.w;
  float ss = v.x * v.x + v.y * v.y + v.z * v.z + v.w * v.w;
#pragma unroll
  for (int o = 32; o; o >>= 1) { s += __shfl_xor(s, o, 64); ss += __shfl_xor(ss, o, 64); }
  float mu = s * (1.f / 256.f);
  float var = ss * (1.f / 256.f) - mu * mu;
  float rs = rsqrtf(var + 1e-5f);
  float4 wv = *(const float4*)&w[lane * 4];
  float4 bv = *(const float4*)&b[lane * 4];
  f16x4 o4;
  o4[0] = (_Float16)((v.x - mu) * rs * wv.x + bv.x);
  o4[1] = (_Float16)((v.y - mu) * rs * wv.y + bv.y);
  o4[2] = (_Float16)((v.z - mu) * rs * wv.z + bv.z);
  o4[3] = (_Float16)((v.w - mu) * rs * wv.w + bv.w);
  *(f16x4*)&out[(size_t)row * 256 + lane * 4] = o4;
}

// ---------------- fused conv4+silu -> xproj -> dtproj+softplus ----------------
__global__ __launch_bounds__(128) void convxdt_k(
    const float* __restrict__ big, const float* __restrict__ cw, const float* __restrict__ cb,
    const float* __restrict__ xW, const float* __restrict__ dW, const float* __restrict__ dbias,
    float* __restrict__ ucv, float* __restrict__ xd, float* __restrict__ dt) {
  __shared__ float us[512];
  __shared__ float xs[48];
  int token = ((blockIdx.x & 7) << 8) | (blockIdx.x >> 3);
  int b = token >> 9, l = token & 511;
  int t = threadIdx.x;
  for (int c = t; c < 512; c += 128) {
    float acc = cb[c];
#pragma unroll
    for (int k = 0; k < 4; k++) {
      int l2 = l - 3 + k;
      if (l2 >= 0) acc += big[((size_t)(b * LSEQ + l2)) * 1024 + c] * cw[c * 4 + k];
    }
    float u = siluf_(acc);
    us[c] = u;
    ucv[(size_t)token * 512 + c] = u;
  }
  __syncthreads();
  float part = 0.f;
  int j = t >> 1, p = t & 1;
  if (t < 96) {
    for (int c = p * 256; c < p * 256 + 256; c++) part += us[c] * xW[c * 48 + j];
  }
  part += __shfl_xor(part, 1, 64);
  if (t < 96 && p == 0) {
    xs[j] = part;
    xd[(size_t)token * 48 + j] = part;
  }
  __syncthreads();
  for (int c = t; c < 512; c += 128) {
    float acc = dbias[c];
#pragma unroll
    for (int r = 0; r < 16; r++) acc += xs[r] * dW[r * 512 + c];
    dt[(size_t)token * 512 + c] = (acc > 20.f) ? acc : log1pf(__expf(acc));
  }
}

// ---------------- scan v3: thread = (chunk, channel), states in regs, 256 blocks ----------------
// Block = 32 chunks x 8 channels (CHUNK=16); grid = 4b x 64 channel-groups = 256 blocks.
// Loads coalesced (8 consecutive d per 8-lane group); n-reduce in registers.
__global__ __launch_bounds__(256) void scan_k(
    const float* __restrict__ dt, const float* __restrict__ ucv, const float* __restrict__ xd,
    const float* __restrict__ zbuf, const float* __restrict__ A_log, const float* __restrict__ D_p,
    _Float16* __restrict__ gout) {
  __shared__ float PsL[32][8][17];   // [c][dl][n] (+pad)
  __shared__ float HsL[32][8][17];
  __shared__ float BnS[32][16];
  __shared__ float CnS[32][16];
  int bid = blockIdx.x;
  int b = bid >> 6, dg = bid & 63;
  int t = threadIdx.x;
  int c = t >> 3, dl = t & 7;
  int d = dg * 8 + dl;
  float An[16];
#pragma unroll
  for (int n = 0; n < 16; n++) An[n] = -__expf(A_log[(size_t)d * 16 + n]);
  float P[16], H[16];
#pragma unroll
  for (int n = 0; n < 16; n++) { P[n] = 1.f; H[n] = 0.f; }
  int t0 = b * LSEQ + c * 16;
  for (int tt = 0; tt < 16; tt++) {
    int token = t0 + tt;
    float dtv = dt[(size_t)token * 512 + d];
    float uv = ucv[(size_t)token * 512 + d];
    if (dl < 8) { // stage Bn row for this chunk: 8 lanes load 16 values (2 each)
      BnS[c][dl] = xd[(size_t)token * 48 + 16 + dl];
      BnS[c][8 + dl] = xd[(size_t)token * 48 + 24 + dl];
    }
    float x = dtv * uv;
#pragma unroll
    for (int n = 0; n < 16; n++) {
      float dA = __expf(dtv * An[n]);
      P[n] *= dA;
      H[n] = dA * H[n] + x * BnS[c][n];
    }
  }
#pragma unroll
  for (int n = 0; n < 16; n++) { PsL[c][dl][n] = P[n]; HsL[c][dl][n] = H[n]; }
  __syncthreads();
  if (t < 128) {
    int n2 = t >> 3, dl2 = t & 7;
    float hc = 0.f;
#pragma unroll
    for (int c2 = 0; c2 < 32; c2++) {
      float Pv = PsL[c2][dl2][n2];
      float Hv = HsL[c2][dl2][n2];
      PsL[c2][dl2][n2] = hc;   // Hin (state before chunk c2)
      hc = Pv * hc + Hv;
    }
  }
  __syncthreads();
  float h[16];
#pragma unroll
  for (int n = 0; n < 16; n++) h[n] = PsL[c][dl][n];
  float Dd = D_p[d];
  for (int tt = 0; tt < 16; tt++) {
    int token = t0 + tt;
    float dtv = dt[(size_t)token * 512 + d];
    float uv = ucv[(size_t)token * 512 + d];
    float zv = zbuf[(size_t)token * 1024 + 512 + d];
    BnS[c][dl] = xd[(size_t)token * 48 + 16 + dl];
    BnS[c][8 + dl] = xd[(size_t)token * 48 + 24 + dl];
    CnS[c][dl] = xd[(size_t)token * 48 + 32 + dl];
    CnS[c][8 + dl] = xd[(size_t)token * 48 + 40 + dl];
    float x = dtv * uv;
    float y = 0.f;
#pragma unroll
    for (int n = 0; n < 16; n++) {
      float dA = __expf(dtv * An[n]);
      h[n] = dA * h[n] + x * BnS[c][n];
      y += h[n] * CnS[c][n];
    }
    gout[(size_t)token * 512 + d] = (_Float16)((y + uv * Dd) * siluf_(zv));
  }
}

// ---------------- SwiGLU for mlp: silu(g1)*g2 -> f16 ----------------
__global__ __launch_bounds__(256) void silumul_k(const float* __restrict__ big, _Float16* __restrict__ out) {
  int i = blockIdx.x * 256 + threadIdx.x; // BL*256
  int token = i >> 8, j = i & 255;
  float g1 = big[(size_t)token * 512 + j];
  float g2 = big[(size_t)token * 512 + 256 + j];
  out[i] = (_Float16)(siluf_(g1) * g2);
}

// ---------------- head: wide kernels with K-split GEMMs ----------------
__global__ __launch_bounds__(256) void lnf_k(const float* __restrict__ h, const float* __restrict__ nfw,
                                             const float* __restrict__ nfb, float* __restrict__ f) {
  __shared__ float red[4];
  int b = blockIdx.x, t = threadIdx.x;
  int lane = t & 63, wid = t >> 6;
  float v = h[((size_t)b * LSEQ + (LSEQ - 1)) * DMOD + t];
  float s = v;
#pragma unroll
  for (int o = 32; o; o >>= 1) s += __shfl_xor(s, o, 64);
  if (lane == 0) red[wid] = s;
  __syncthreads();
  float mu = (red[0] + red[1] + red[2] + red[3]) * (1.f / 256.f);
  float dv = v - mu;
  s = dv * dv;
#pragma unroll
  for (int o = 32; o; o >>= 1) s += __shfl_xor(s, o, 64);
  __syncthreads();
  if (lane == 0) red[wid] = s;
  __syncthreads();
  float var = (red[0] + red[1] + red[2] + red[3]) * (1.f / 256.f);
  f[b * 256 + t] = dv * rsqrtf(var + 1e-5f) * nfw[t] + nfb[t];
}

__global__ __launch_bounds__(256) void hgemm1_k(const float* __restrict__ f,
    const float* vW1, const float* vb1, const float* aW1, const float* ab1,
    float* __restrict__ a1) {
  int cb = blockIdx.x, b = blockIdx.y, p = blockIdx.z;
  const float* W1 = p ? aW1 : vW1;
  const float* b1 = p ? ab1 : vb1;
  __shared__ float fs[256];
  __shared__ float part[4][64];
  int t = threadIdx.x;
  fs[t] = f[b * 256 + t];
  __syncthreads();
  int col = cb * 64 + (t & 63);
  int kp = t >> 6;
  float acc = 0.f;
#pragma unroll 8
  for (int k = 0; k < 64; k++) acc += fs[kp * 64 + k] * W1[(size_t)(kp * 64 + k) * 512 + col];
  part[kp][t & 63] = acc;
  __syncthreads();
  if (t < 64) {
    float v = part[0][t] + part[1][t] + part[2][t] + part[3][t] + b1[cb * 64 + t];
    a1[((b * 2 + p) * 512) + cb * 64 + t] = v;
  }
}

__global__ __launch_bounds__(512) void hln1_k(const float* __restrict__ a1,
    const float* vl1w, const float* vl1b, const float* al1w, const float* al1b,
    float* __restrict__ t1) {
  __shared__ float red[8];
  int b = blockIdx.x, p = blockIdx.y, t = threadIdx.x;
  const float* lw = p ? al1w : vl1w;
  const float* lb = p ? al1b : vl1b;
  int lane = t & 63, wid = t >> 6;
  int idx = (b * 2 + p) * 512 + t;
  float v = a1[idx];
  float s = v;
#pragma unroll
  for (int o = 32; o; o >>= 1) s += __shfl_xor(s, o, 64);
  if (lane == 0) red[wid] = s;
  __syncthreads();
  float S = 0.f;
#pragma unroll
  for (int k = 0; k < 8; k++) S += red[k];
  float mu = S * (1.f / 512.f);
  float dv = v - mu;
  s = dv * dv;
#pragma unroll
  for (int o = 32; o; o >>= 1) s += __shfl_xor(s, o, 64);
  __syncthreads();
  if (lane == 0) red[wid] = s;
  __syncthreads();
  S = 0.f;
#pragma unroll
  for (int k = 0; k < 8; k++) S += red[k];
  float var = S * (1.f / 512.f);
  t1[idx] = fmaxf(dv * rsqrtf(var + 1e-5f) * lw[t] + lb[t], 0.f);
}

__global__ __launch_bounds__(256) void hgemm2_k(const float* __restrict__ t1,
    const float* vW2, const float* vb2, const float* aW2, const float* ab2,
    float* __restrict__ a2) {
  int cb = blockIdx.x, b = blockIdx.y, p = blockIdx.z;
  const float* W2 = p ? aW2 : vW2;
  const float* b2 = p ? ab2 : vb2;
  __shared__ float ts[512];
  __shared__ float part[4][64];
  int t = threadIdx.x;
  ts[t] = t1[(b * 2 + p) * 512 + t];
  ts[256 + t] = t1[(b * 2 + p) * 512 + 256 + t];
  __syncthreads();
  int col = cb * 64 + (t & 63);
  int kp = t >> 6;
  float acc = 0.f;
#pragma unroll 8
  for (int k = 0; k < 128; k++) acc += ts[kp * 128 + k] * W2[(size_t)(kp * 128 + k) * 256 + col];
  part[kp][t & 63] = acc;
  __syncthreads();
  if (t < 64) {
    float v = part[0][t] + part[1][t] + part[2][t] + part[3][t] + b2[cb * 64 + t];
    a2[(b * 2 + p) * 256 + cb * 64 + t] = v;
  }
}

__global__ __launch_bounds__(256) void hln2_k(const float* __restrict__ a2,
    const float* vl2w, const float* vl2b, const float* al2w, const float* al2b,
    float* __restrict__ t2) {
  __shared__ float red[4];
  int b = blockIdx.x, p = blockIdx.y, t = threadIdx.x;
  const float* lw = p ? al2w : vl2w;
  const float* lb = p ? al2b : vl2b;
  int lane = t & 63, wid = t >> 6;
  int idx = (b * 2 + p) * 256 + t;
  float v = a2[idx];
  float s = v;
#pragma unroll
  for (int o = 32; o; o >>= 1) s += __shfl_xor(s, o, 64);
  if (lane == 0) red[wid] = s;
  __syncthreads();
  float mu = (red[0] + red[1] + red[2] + red[3]) * (1.f / 256.f);
  float dv = v - mu;
  s = dv * dv;
#pragma unroll
  for (int o = 32; o; o >>= 1) s += __shfl_xor(s, o, 64);
  __syncthreads();
  if (lane == 0) red[wid] = s;
  __syncthreads();
  float var = (red[0] + red[1] + red[2] + red[3]) * (1.f / 256.f);
  t2[idx] = fmaxf(dv * rsqrtf(var + 1e-5f) * lw[t] + lb[t], 0.f);
}

__global__ __launch_bounds__(256) void hfinal_k(const float* __restrict__ t2,
    const float* vW3, const float* vb3, const float* aW3, const float* ab3,
    float* __restrict__ q) {
  __shared__ float a3s[24];
  int t = threadIdx.x;
  int g = t >> 3, ln8 = t & 7;
  if (g < 24) {
    int b = g / 6, r = g - b * 6;
    int p = r ? 1 : 0;
    int o = r ? r - 1 : 0;
    const float* W3 = p ? aW3 : vW3;
    const float* b3 = p ? ab3 : vb3;
    int nout = p ? 5 : 1;
    const float* t2r = t2 + (b * 2 + p) * 256;
    float acc = 0.f;
    for (int k = ln8; k < 256; k += 8) acc += t2r[k] * W3[k * nout + o];
    acc += __shfl_xor(acc, 1, 64);
    acc += __shfl_xor(acc, 2, 64);
    acc += __shfl_xor(acc, 4, 64);
    if (ln8 == 0) a3s[g] = acc + b3[o];
  }
  __syncthreads();
  if (t < 20) {
    int b = t / 5, a = t - b * 5;
    float val = a3s[b * 6];
    float m = 0.f;
#pragma unroll
    for (int j = 0; j < 5; j++) m += a3s[b * 6 + 1 + j];
    m *= 0.2f;
    q[b * 5 + a] = val + a3s[b * 6 + 1 + a] - m;
  }
}

extern "C" void kernel_launch(void* const* d_in, const int* in_sizes, int n_in,
                              void* d_out, int out_size, void* d_ws, size_t ws_size,
                              hipStream_t stream) {
  const float* src = (const float*)d_in[0];
  const float* tau = (const float*)d_in[1];
  const float* dain_Wm = (const float*)d_in[2];
  const float* dain_Ws = (const float*)d_in[3];
  const float* dain_Wg = (const float*)d_in[4];
  const float* dain_bg = (const float*)d_in[5];
  const float* memb_W = (const float*)d_in[6];
  const float* memb_b = (const float*)d_in[7];
  const float* t_w0 = (const float*)d_in[8];
  const float* t_b0 = (const float*)d_in[9];
  const float* t_w = (const float*)d_in[10];
  const float* t_b = (const float*)d_in[11];
  const float* tproj_W = (const float*)d_in[12];
  const float* tproj_b = (const float*)d_in[13];
  const float* ffn_W1 = (const float*)d_in[14];
  const float* ffn_b1 = (const float*)d_in[15];
  const float* ffn_W2 = (const float*)d_in[16];
  const float* ffn_b2 = (const float*)d_in[17];
  const float* n1_w = (const float*)d_in[18];
  const float* n1_b = (const float*)d_in[19];
  const float* inproj_W = (const float*)d_in[20];
  const float* conv_w = (const float*)d_in[21];
  const float* conv_b = (const float*)d_in[22];
  const float* xproj_W = (const float*)d_in[23];
  const float* dtproj_W = (const float*)d_in[24];
  const float* dt_bias = (const float*)d_in[25];
  const float* A_log = (const float*)d_in[26];
  const float* D_p = (const float*)d_in[27];
  const float* outproj_W = (const float*)d_in[28];
  const float* n2_w = (const float*)d_in[29];
  const float* n2_b = (const float*)d_in[30];
  const float* mlp_W1 = (const float*)d_in[31];
  const float* mlp_W2 = (const float*)d_in[32];
  const float* nf_w = (const float*)d_in[33];
  const float* nf_b = (const float*)d_in[34];
  const float* vW1 = (const float*)d_in[35]; const float* vb1 = (const float*)d_in[36];
  const float* vl1w = (const float*)d_in[37]; const float* vl1b = (const float*)d_in[38];
  const float* vW2 = (const float*)d_in[39]; const float* vb2 = (const float*)d_in[40];
  const float* vl2w = (const float*)d_in[41]; const float* vl2b = (const float*)d_in[42];
  const float* vW3 = (const float*)d_in[43]; const float* vb3 = (const float*)d_in[44];
  const float* aW1 = (const float*)d_in[45]; const float* ab1 = (const float*)d_in[46];
  const float* al1w = (const float*)d_in[47]; const float* al1b = (const float*)d_in[48];
  const float* aW2 = (const float*)d_in[49]; const float* ab2 = (const float*)d_in[50];
  const float* al2w = (const float*)d_in[51]; const float* al2b = (const float*)d_in[52];
  const float* aW3 = (const float*)d_in[53]; const float* ab3 = (const float*)d_in[54];
  float* out = (float*)d_out;

  float* ws = (float*)d_ws;
  float* dstats = ws;                      // 256
  float* h    = dstats + 256;              // BL*256
  float* big  = h + (size_t)BL * DMOD;     // BL*1408
  float* ucv  = big + (size_t)BL * 1408;   // BL*512
  float* xd   = ucv + (size_t)BL * DIN;    // BL*48
  float* dt   = xd + (size_t)BL * 48;      // BL*512
  float* fh   = dt + (size_t)BL * DIN;     // 1024
  float* a1   = fh + 1024;                 // 4096
  float* t1   = a1 + 4096;                 // 4096
  float* a2   = t1 + 4096;                 // 2048
  float* t2   = a2 + 2048;                 // 2048
  float* fp_end = t2 + 2048;
  _Float16* h_hf    = (_Float16*)fp_end;            // BL*256
  _Float16* hn_hf   = h_hf + (size_t)BL * DMOD;     // BL*256
  _Float16* mid_hf  = hn_hf + (size_t)BL * DMOD;    // BL*704
  _Float16* gout_hf = mid_hf + (size_t)BL * 704;    // BL*512
  _Float16* ffn1T   = gout_hf + (size_t)BL * DIN;   // 1408*256
  _Float16* ffn2T   = ffn1T + (size_t)1408 * 256;   // 256*704
  _Float16* inprojT = ffn2T + (size_t)256 * 704;    // 8*1024*256
  _Float16* outprojT = inprojT + (size_t)8 * 1024 * 256;
  _Float16* mlp1T   = outprojT + (size_t)8 * 256 * 512;
  _Float16* mlp2T   = mlp1T + (size_t)8 * 512 * 256;

  convall_k<<<20544, 256, 0, stream>>>(ffn_W1, ffn_W2, inproj_W, outproj_W, mlp_W1, mlp_W2,
                                       ffn1T, ffn2T, inprojT, outprojT, mlp1T, mlp2T);
  dain_k<<<1, 1024, 0, stream>>>(src, dain_Wm, dain_Ws, dain_Wg, dain_bg, dstats);
  embed_k<<<BL, 256, 0, stream>>>(src, tau, dstats, memb_W, memb_b, t_w0, t_b0, t_w, t_b, tproj_W, tproj_b, h_hf);
  gemm_hf_k<<<dim3(22, 32), 256, 0, stream>>>(h_hf, ffn1T, ffn_b1, big, BL, 1364, 256, 1364, 0);
  glugelu_k<<<BL * 704 / 256, 256, 0, stream>>>(big, mid_hf);
  gemm_hf_k<<<dim3(4, 32), 256, 0, stream>>>(mid_hf, ffn2T, ffn_b2, h, BL, 256, 704, 256, 0);

  for (int i = 0; i < 8; i++) {
    ln4_k<<<BL / 4, 256, 0, stream>>>(h, n1_w + i * 256, n1_b + i * 256, hn_hf);
    gemm_hf_k<<<dim3(16, 32), 256, 0, stream>>>(hn_hf, inprojT + (size_t)i * 1024 * 256, nullptr, big,
                                                BL, 1024, 256, 1024, 0);
    convxdt_k<<<BL, 128, 0, stream>>>(big, conv_w + (size_t)i * 512 * 4, conv_b + i * 512,
                                      xproj_W + (size_t)i * 512 * 48, dtproj_W + (size_t)i * 16 * 512,
                                      dt_bias + i * 512, ucv, xd, dt);
    scan_k<<<256, 256, 0, stream>>>(dt, ucv, xd, big, A_log + (size_t)i * 512 * 16, D_p + i * 512, gout_hf);
    gemm_hf_k<<<dim3(4, 32), 256, 0, stream>>>(gout_hf, outprojT + (size_t)i * 256 * 512, nullptr, h,
                                               BL, 256, 512, 256, 1);
    ln4_k<<<BL / 4, 256, 0, stream>>>(h, n2_w + i * 256, n2_b + i * 256, hn_hf);
    gemm_hf_k<<<dim3(8, 32), 256, 0, stream>>>(hn_hf, mlp1T + (size_t)i * 512 * 256, nullptr, big,
                                               BL, 512, 256, 512, 0);
    silumul_k<<<BL, 256, 0, stream>>>(big, mid_hf);
    gemm_hf_k<<<dim3(4, 32), 256, 0, stream>>>(mid_hf, mlp2T + (size_t)i * 256 * 256, nullptr, h,
                                               BL, 256, 256, 256, 1);
  }

  lnf_k<<<NB, 256, 0, stream>>>(h, nf_w, nf_b, fh);
  hgemm1_k<<<dim3(8, 4, 2), 256, 0, stream>>>(fh, vW1, vb1, aW1, ab1, a1);
  hln1_k<<<dim3(4, 2), 512, 0, stream>>>(a1, vl1w, vl1b, al1w, al1b, t1);
  hgemm2_k<<<dim3(4, 4, 2), 256, 0, stream>>>(t1, vW2, vb2, aW2, ab2, a2);
  hln2_k<<<dim3(4, 2), 256, 0, stream>>>(a2, vl2w, vl2b, al2w, al2b, t2);
  hfinal_k<<<1, 256, 0, stream>>>(t2, vW3, vb3, aW3, ab3, out);
  (void)in_sizes; (void)n_in; (void)out_size; (void)ws_size;
}

// Round 14
// 892.779 us; speedup vs baseline: 1.5961x; 1.0274x over previous
//
#include <hip/hip_runtime.h>
#include <math.h>

// Model constants
#define BL   2048   // B*L = 4*512
#define LSEQ 512
#define NB   4
#define DMOD 256
#define DIN  512
#define NCH  (NB * DIN)

typedef __attribute__((ext_vector_type(4))) float f32x4;
typedef __attribute__((ext_vector_type(8))) _Float16 f16x8;
typedef __attribute__((ext_vector_type(4))) _Float16 f16x4;

__device__ __forceinline__ float sigmoidf_(float x) { return 1.f / (1.f + __expf(-x)); }
__device__ __forceinline__ float siluf_(float x) { return x / (1.f + __expf(-x)); }

// ---------------- DAIN stats (single block) ----------------
__global__ __launch_bounds__(1024) void dain_k(
    const float* __restrict__ src, const float* __restrict__ Wm,
    const float* __restrict__ Ws, const float* __restrict__ Wg,
    const float* __restrict__ bg, float* __restrict__ stats) {
  __shared__ float part[1024];
  __shared__ float avg_s[128], sub_s[128], std_s[128], mn_s[128], inv_s[128];
  int tid = threadIdx.x;
  int p = tid >> 3, j = tid & 7;
  int b = p >> 5, f = p & 31;
  float s = 0.f;
  for (int l = j * 64; l < j * 64 + 64; ++l) s += src[((size_t)b * LSEQ + l) * 32 + f];
  part[tid] = s;
  __syncthreads();
  if (tid < 128) { float a = 0; for (int k = 0; k < 8; k++) a += part[tid * 8 + k]; avg_s[tid] = a * (1.f / 512.f); }
  __syncthreads();
  if (tid < 128) {
    int bb = tid >> 5, ff = tid & 31;
    float a = 0; for (int g = 0; g < 32; g++) a += avg_s[bb * 32 + g] * Wm[ff * 32 + g];
    sub_s[tid] = a;
  }
  __syncthreads();
  float sub = sub_s[p];
  s = 0.f;
  for (int l = j * 64; l < j * 64 + 64; ++l) {
    float v = src[((size_t)b * LSEQ + l) * 32 + f] - sub; s += v * v;
  }
  part[tid] = s;
  __syncthreads();
  if (tid < 128) { float a = 0; for (int k = 0; k < 8; k++) a += part[tid * 8 + k]; std_s[tid] = sqrtf(a * (1.f / 512.f)); }
  __syncthreads();
  if (tid < 128) {
    int bb = tid >> 5, ff = tid & 31;
    float a = 0; for (int g = 0; g < 32; g++) a += std_s[bb * 32 + g] * Ws[ff * 32 + g];
    if (a <= 1e-8f) a = 1.f;
    inv_s[tid] = 1.f / a;
    mn_s[tid] = (avg_s[tid] - sub_s[tid]) / a;
  }
  __syncthreads();
  if (tid < 128) {
    int bb = tid >> 5, ff = tid & 31;
    float a = bg[ff]; for (int g = 0; g < 32; g++) a += mn_s[bb * 32 + g] * Wg[ff * 32 + g];
    float gate = sigmoidf_(a);
    float scl = gate * inv_s[tid];
    stats[tid] = scl;
    stats[128 + tid] = sub_s[tid] * scl;
  }
}

// ---------------- embed -> h_hf (f16) ----------------
__global__ __launch_bounds__(256) void embed_k(
    const float* __restrict__ src, const float* __restrict__ tau,
    const float* __restrict__ stats, const float* __restrict__ membW,
    const float* __restrict__ membB, const float* __restrict__ tw0,
    const float* __restrict__ tb0, const float* __restrict__ tw,
    const float* __restrict__ tb, const float* __restrict__ tprojW,
    const float* __restrict__ tprojB, _Float16* __restrict__ h_hf) {
  int token = blockIdx.x;
  int b = token >> 9;
  int t = threadIdx.x;
  __shared__ float xs[32], te[32];
  if (t < 32) {
    float scl = stats[b * 32 + t], shf = stats[128 + b * 32 + t];
    xs[t] = src[(size_t)token * 32 + t] * scl - shf;
  } else if (t < 64) {
    int j = t - 32;
    const float* tr = tau + (size_t)token * 8;
    float a;
    if (j < 31) { a = tb[j]; for (int k = 0; k < 8; k++) a += tr[k] * tw[k * 31 + j]; a = sinf(a); }
    else        { a = tb0[0]; for (int k = 0; k < 8; k++) a += tr[k] * tw0[k]; }
    te[j] = a;
  }
  __syncthreads();
  float acc;
  if (t < 128) {
    acc = membB[t];
    for (int f = 0; f < 32; f++) acc += xs[f] * membW[f * 128 + t];
  } else {
    int d = t - 128;
    acc = tprojB[d];
    for (int j = 0; j < 32; j++) acc += te[j] * tprojW[j * 128 + d];
  }
  h_hf[(size_t)token * DMOD + t] = (_Float16)acc;
}

// ---------------- all weight transpose-converts in ONE launch ----------------
__device__ __forceinline__ void convT_one(const float* __restrict__ W, _Float16* __restrict__ WT,
                                          int K, int N, int Kout, int Nout, int idx) {
  int per = Nout * Kout;
  int l = idx / per; int rem = idx - l * per;
  int n = rem / Kout; int k = rem - n * Kout;
  const float* Wl = W + (size_t)l * K * N;
  float v = (k < K && n < N) ? Wl[(size_t)k * N + n] : 0.f;
  WT[(size_t)l * per + rem] = (_Float16)v;
}

__global__ __launch_bounds__(256) void convall_k(
    const float* ffn_W1, const float* ffn_W2, const float* inproj_W,
    const float* outproj_W, const float* mlp_W1, const float* mlp_W2,
    _Float16* ffn1T, _Float16* ffn2T, _Float16* inprojT,
    _Float16* outprojT, _Float16* mlp1T, _Float16* mlp2T) {
  int g = blockIdx.x, t = threadIdx.x;
  if (g < 1408)            convT_one(ffn_W1, ffn1T, 256, 1364, 256, 1408, g * 256 + t);
  else if (g < 2112)       convT_one(ffn_W2, ffn2T, 682, 256, 704, 256, (g - 1408) * 256 + t);
  else if (g < 10304)      convT_one(inproj_W, inprojT, 256, 1024, 256, 1024, (g - 2112) * 256 + t);
  else if (g < 14400)      convT_one(outproj_W, outprojT, 512, 256, 512, 256, (g - 10304) * 256 + t);
  else if (g < 18496)      convT_one(mlp_W1, mlp1T, 256, 512, 256, 512, (g - 14400) * 256 + t);
  else                     convT_one(mlp_W2, mlp2T, 256, 256, 256, 256, (g - 18496) * 256 + t);
}

// ---------------- plain f16 MFMA GEMM 64x64 tile (A stride == K) ----------------
__global__ __launch_bounds__(256) void gemm_hf_k(
    const _Float16* __restrict__ A, const _Float16* __restrict__ WT,
    const float* __restrict__ bias, float* __restrict__ C,
    int M, int Nstore, int K, int ldc, int flags) {
  __shared__ _Float16 As[64][40];
  __shared__ _Float16 Bs[64][40];
  int bm = blockIdx.y * 64, bn = blockIdx.x * 64;
  int t = threadIdx.x;
  int w = t >> 6, l = t & 63;
  int wm = w >> 1, wn = w & 1;
  int srow = t >> 2, sk = (t & 3) * 8;
  f32x4 acc[2][2] = {};
  int lr = l & 15, lk = (l >> 4) * 8;
  for (int k0 = 0; k0 < K; k0 += 32) {
    *(uint4*)&As[srow][sk] = *(const uint4*)&A[(size_t)(bm + srow) * K + k0 + sk];
    *(uint4*)&Bs[srow][sk] = *(const uint4*)&WT[(size_t)(bn + srow) * K + k0 + sk];
    __syncthreads();
    f16x8 a0 = *(const f16x8*)&As[wm * 32 + lr][lk];
    f16x8 a1 = *(const f16x8*)&As[wm * 32 + 16 + lr][lk];
    f16x8 b0 = *(const f16x8*)&Bs[wn * 32 + lr][lk];
    f16x8 b1 = *(const f16x8*)&Bs[wn * 32 + 16 + lr][lk];
    acc[0][0] = __builtin_amdgcn_mfma_f32_16x16x32_f16(a0, b0, acc[0][0], 0, 0, 0);
    acc[0][1] = __builtin_amdgcn_mfma_f32_16x16x32_f16(a0, b1, acc[0][1], 0, 0, 0);
    acc[1][0] = __builtin_amdgcn_mfma_f32_16x16x32_f16(a1, b0, acc[1][0], 0, 0, 0);
    acc[1][1] = __builtin_amdgcn_mfma_f32_16x16x32_f16(a1, b1, acc[1][1], 0, 0, 0);
    __syncthreads();
  }
  int lq = l >> 4;
#pragma unroll
  for (int i = 0; i < 2; i++) {
#pragma unroll
    for (int j = 0; j < 2; j++) {
      int col = bn + wn * 32 + j * 16 + lr;
      if (col >= Nstore) continue;
      float bv = bias ? bias[col] : 0.f;
#pragma unroll
      for (int r = 0; r < 4; r++) {
        int row = bm + wm * 32 + i * 16 + lq * 4 + r;
        float v = acc[i][j][r] + bv;
        size_t idx = (size_t)row * ldc + col;
        if (flags & 1) v += C[idx];
        C[idx] = v;
      }
    }
  }
}

// ---------------- FFN GLU (a * gelu_exact(g)) -> f16 padded to 704 ----------------
__global__ __launch_bounds__(256) void glugelu_k(const float* __restrict__ big, _Float16* __restrict__ out) {
  int i = blockIdx.x * 256 + threadIdx.x; // BL*704
  int token = i / 704, j = i - token * 704;
  float r = 0.f;
  if (j < 682) {
    float a = big[(size_t)token * 1364 + j];
    float g = big[(size_t)token * 1364 + 682 + j];
    r = a * 0.5f * g * (1.f + erff(g * 0.70710678118654752f));
  }
  out[i] = (_Float16)r;
}

// ---------------- LayerNorm, 4 rows/block (wave per row) -> f16 ----------------
__global__ __launch_bounds__(256) void ln4_k(const float* __restrict__ x, const float* __restrict__ w,
                                             const float* __restrict__ b, _Float16* __restrict__ out) {
  int row = blockIdx.x * 4 + (threadIdx.x >> 6), lane = threadIdx.x & 63;
  const float* rp = x + (size_t)row * 256;
  float4 v = *(const float4*)&rp[lane * 4];
  float s = v.x + v.y + v.z + v.w;
  float ss = v.x * v.x + v.y * v.y + v.z * v.z + v.w * v.w;
#pragma unroll
  for (int o = 32; o; o >>= 1) { s += __shfl_xor(s, o, 64); ss += __shfl_xor(ss, o, 64); }
  float mu = s * (1.f / 256.f);
  float var = ss * (1.f / 256.f) - mu * mu;
  float rs = rsqrtf(var + 1e-5f);
  float4 wv = *(const float4*)&w[lane * 4];
  float4 bv = *(const float4*)&b[lane * 4];
  f16x4 o4;
  o4[0] = (_Float16)((v.x - mu) * rs * wv.x + bv.x);
  o4[1] = (_Float16)((v.y - mu) * rs * wv.y + bv.y);
  o4[2] = (_Float16)((v.z - mu) * rs * wv.z + bv.z);
  o4[3] = (_Float16)((v.w - mu) * rs * wv.w + bv.w);
  *(f16x4*)&out[(size_t)row * 256 + lane * 4] = o4;
}

// ---------------- fused conv4+silu -> xproj -> dtproj+softplus (256 threads) ----------------
// conv/dtproj: 2 channels/thread. xproj: 192 threads = 48 j x 4 k-parts of 128.
__global__ __launch_bounds__(256) void convxdt_k(
    const float* __restrict__ big, const float* __restrict__ cw, const float* __restrict__ cb,
    const float* __restrict__ xW, const float* __restrict__ dW, const float* __restrict__ dbias,
    float* __restrict__ ucv, float* __restrict__ xd, float* __restrict__ dt) {
  __shared__ float us[512];
  __shared__ float xs[48];
  int token = ((blockIdx.x & 7) << 8) | (blockIdx.x >> 3);
  int b = token >> 9, l = token & 511;
  int t = threadIdx.x;
#pragma unroll
  for (int e = 0; e < 2; e++) {
    int c = t + e * 256;
    float acc = cb[c];
#pragma unroll
    for (int k = 0; k < 4; k++) {
      int l2 = l - 3 + k;
      if (l2 >= 0) acc += big[((size_t)(b * LSEQ + l2)) * 1024 + c] * cw[c * 4 + k];
    }
    float u = siluf_(acc);
    us[c] = u;
    ucv[(size_t)token * 512 + c] = u;
  }
  __syncthreads();
  if (t < 192) {
    int j = t >> 2, p = t & 3;
    float part = 0.f;
#pragma unroll 8
    for (int c = p * 128; c < p * 128 + 128; c++) part += us[c] * xW[c * 48 + j];
    part += __shfl_xor(part, 1, 64);
    part += __shfl_xor(part, 2, 64);
    if (p == 0) {
      xs[j] = part;
      xd[(size_t)token * 48 + j] = part;
    }
  }
  __syncthreads();
#pragma unroll
  for (int e = 0; e < 2; e++) {
    int c = t + e * 256;
    float acc = dbias[c];
#pragma unroll
    for (int r = 0; r < 16; r++) acc += xs[r] * dW[r * 512 + c];
    dt[(size_t)token * 512 + c] = (acc > 20.f) ? acc : log1pf(__expf(acc));
  }
}

// ---------------- scan v3: thread = (chunk, channel), states in regs, 256 blocks ----------------
__global__ __launch_bounds__(256) void scan_k(
    const float* __restrict__ dt, const float* __restrict__ ucv, const float* __restrict__ xd,
    const float* __restrict__ zbuf, const float* __restrict__ A_log, const float* __restrict__ D_p,
    _Float16* __restrict__ gout) {
  __shared__ float PsL[32][8][17];   // [c][dl][n] (+pad)
  __shared__ float HsL[32][8][17];
  __shared__ float BnS[32][16];
  __shared__ float CnS[32][16];
  int bid = blockIdx.x;
  int b = bid >> 6, dg = bid & 63;
  int t = threadIdx.x;
  int c = t >> 3, dl = t & 7;
  int d = dg * 8 + dl;
  float An[16];
#pragma unroll
  for (int n = 0; n < 16; n++) An[n] = -__expf(A_log[(size_t)d * 16 + n]);
  float P[16], H[16];
#pragma unroll
  for (int n = 0; n < 16; n++) { P[n] = 1.f; H[n] = 0.f; }
  int t0 = b * LSEQ + c * 16;
  for (int tt = 0; tt < 16; tt++) {
    int token = t0 + tt;
    float dtv = dt[(size_t)token * 512 + d];
    float uv = ucv[(size_t)token * 512 + d];
    BnS[c][dl] = xd[(size_t)token * 48 + 16 + dl];
    BnS[c][8 + dl] = xd[(size_t)token * 48 + 24 + dl];
    float x = dtv * uv;
#pragma unroll
    for (int n = 0; n < 16; n++) {
      float dA = __expf(dtv * An[n]);
      P[n] *= dA;
      H[n] = dA * H[n] + x * BnS[c][n];
    }
  }
#pragma unroll
  for (int n = 0; n < 16; n++) { PsL[c][dl][n] = P[n]; HsL[c][dl][n] = H[n]; }
  __syncthreads();
  if (t < 128) {
    int n2 = t >> 3, dl2 = t & 7;
    float hc = 0.f;
#pragma unroll
    for (int c2 = 0; c2 < 32; c2++) {
      float Pv = PsL[c2][dl2][n2];
      float Hv = HsL[c2][dl2][n2];
      PsL[c2][dl2][n2] = hc;
      hc = Pv * hc + Hv;
    }
  }
  __syncthreads();
  float h[16];
#pragma unroll
  for (int n = 0; n < 16; n++) h[n] = PsL[c][dl][n];
  float Dd = D_p[d];
  for (int tt = 0; tt < 16; tt++) {
    int token = t0 + tt;
    float dtv = dt[(size_t)token * 512 + d];
    float uv = ucv[(size_t)token * 512 + d];
    float zv = zbuf[(size_t)token * 1024 + 512 + d];
    BnS[c][dl] = xd[(size_t)token * 48 + 16 + dl];
    BnS[c][8 + dl] = xd[(size_t)token * 48 + 24 + dl];
    CnS[c][dl] = xd[(size_t)token * 48 + 32 + dl];
    CnS[c][8 + dl] = xd[(size_t)token * 48 + 40 + dl];
    float x = dtv * uv;
    float y = 0.f;
#pragma unroll
    for (int n = 0; n < 16; n++) {
      float dA = __expf(dtv * An[n]);
      h[n] = dA * h[n] + x * BnS[c][n];
      y += h[n] * CnS[c][n];
    }
    gout[(size_t)token * 512 + d] = (_Float16)((y + uv * Dd) * siluf_(zv));
  }
}

// ---------------- SwiGLU for mlp: silu(g1)*g2 -> f16 ----------------
__global__ __launch_bounds__(256) void silumul_k(const float* __restrict__ big, _Float16* __restrict__ out) {
  int i = blockIdx.x * 256 + threadIdx.x; // BL*256
  int token = i >> 8, j = i & 255;
  float g1 = big[(size_t)token * 512 + j];
  float g2 = big[(size_t)token * 512 + 256 + j];
  out[i] = (_Float16)(siluf_(g1) * g2);
}

// ---------------- head: wide kernels with K-split GEMMs ----------------
__global__ __launch_bounds__(256) void lnf_k(const float* __restrict__ h, const float* __restrict__ nfw,
                                             const float* __restrict__ nfb, float* __restrict__ f) {
  __shared__ float red[4];
  int b = blockIdx.x, t = threadIdx.x;
  int lane = t & 63, wid = t >> 6;
  float v = h[((size_t)b * LSEQ + (LSEQ - 1)) * DMOD + t];
  float s = v;
#pragma unroll
  for (int o = 32; o; o >>= 1) s += __shfl_xor(s, o, 64);
  if (lane == 0) red[wid] = s;
  __syncthreads();
  float mu = (red[0] + red[1] + red[2] + red[3]) * (1.f / 256.f);
  float dv = v - mu;
  s = dv * dv;
#pragma unroll
  for (int o = 32; o; o >>= 1) s += __shfl_xor(s, o, 64);
  __syncthreads();
  if (lane == 0) red[wid] = s;
  __syncthreads();
  float var = (red[0] + red[1] + red[2] + red[3]) * (1.f / 256.f);
  f[b * 256 + t] = dv * rsqrtf(var + 1e-5f) * nfw[t] + nfb[t];
}

__global__ __launch_bounds__(256) void hgemm1_k(const float* __restrict__ f,
    const float* vW1, const float* vb1, const float* aW1, const float* ab1,
    float* __restrict__ a1) {
  int cb = blockIdx.x, b = blockIdx.y, p = blockIdx.z;
  const float* W1 = p ? aW1 : vW1;
  const float* b1 = p ? ab1 : vb1;
  __shared__ float fs[256];
  __shared__ float part[4][64];
  int t = threadIdx.x;
  fs[t] = f[b * 256 + t];
  __syncthreads();
  int col = cb * 64 + (t & 63);
  int kp = t >> 6;
  float acc = 0.f;
#pragma unroll 8
  for (int k = 0; k < 64; k++) acc += fs[kp * 64 + k] * W1[(size_t)(kp * 64 + k) * 512 + col];
  part[kp][t & 63] = acc;
  __syncthreads();
  if (t < 64) {
    float v = part[0][t] + part[1][t] + part[2][t] + part[3][t] + b1[cb * 64 + t];
    a1[((b * 2 + p) * 512) + cb * 64 + t] = v;
  }
}

__global__ __launch_bounds__(512) void hln1_k(const float* __restrict__ a1,
    const float* vl1w, const float* vl1b, const float* al1w, const float* al1b,
    float* __restrict__ t1) {
  __shared__ float red[8];
  int b = blockIdx.x, p = blockIdx.y, t = threadIdx.x;
  const float* lw = p ? al1w : vl1w;
  const float* lb = p ? al1b : vl1b;
  int lane = t & 63, wid = t >> 6;
  int idx = (b * 2 + p) * 512 + t;
  float v = a1[idx];
  float s = v;
#pragma unroll
  for (int o = 32; o; o >>= 1) s += __shfl_xor(s, o, 64);
  if (lane == 0) red[wid] = s;
  __syncthreads();
  float S = 0.f;
#pragma unroll
  for (int k = 0; k < 8; k++) S += red[k];
  float mu = S * (1.f / 512.f);
  float dv = v - mu;
  s = dv * dv;
#pragma unroll
  for (int o = 32; o; o >>= 1) s += __shfl_xor(s, o, 64);
  __syncthreads();
  if (lane == 0) red[wid] = s;
  __syncthreads();
  S = 0.f;
#pragma unroll
  for (int k = 0; k < 8; k++) S += red[k];
  float var = S * (1.f / 512.f);
  t1[idx] = fmaxf(dv * rsqrtf(var + 1e-5f) * lw[t] + lb[t], 0.f);
}

__global__ __launch_bounds__(256) void hgemm2_k(const float* __restrict__ t1,
    const float* vW2, const float* vb2, const float* aW2, const float* ab2,
    float* __restrict__ a2) {
  int cb = blockIdx.x, b = blockIdx.y, p = blockIdx.z;
  const float* W2 = p ? aW2 : vW2;
  const float* b2 = p ? ab2 : vb2;
  __shared__ float ts[512];
  __shared__ float part[4][64];
  int t = threadIdx.x;
  ts[t] = t1[(b * 2 + p) * 512 + t];
  ts[256 + t] = t1[(b * 2 + p) * 512 + 256 + t];
  __syncthreads();
  int col = cb * 64 + (t & 63);
  int kp = t >> 6;
  float acc = 0.f;
#pragma unroll 8
  for (int k = 0; k < 128; k++) acc += ts[kp * 128 + k] * W2[(size_t)(kp * 128 + k) * 256 + col];
  part[kp][t & 63] = acc;
  __syncthreads();
  if (t < 64) {
    float v = part[0][t] + part[1][t] + part[2][t] + part[3][t] + b2[cb * 64 + t];
    a2[(b * 2 + p) * 256 + cb * 64 + t] = v;
  }
}

__global__ __launch_bounds__(256) void hln2_k(const float* __restrict__ a2,
    const float* vl2w, const float* vl2b, const float* al2w, const float* al2b,
    float* __restrict__ t2) {
  __shared__ float red[4];
  int b = blockIdx.x, p = blockIdx.y, t = threadIdx.x;
  const float* lw = p ? al2w : vl2w;
  const float* lb = p ? al2b : vl2b;
  int lane = t & 63, wid = t >> 6;
  int idx = (b * 2 + p) * 256 + t;
  float v = a2[idx];
  float s = v;
#pragma unroll
  for (int o = 32; o; o >>= 1) s += __shfl_xor(s, o, 64);
  if (lane == 0) red[wid] = s;
  __syncthreads();
  float mu = (red[0] + red[1] + red[2] + red[3]) * (1.f / 256.f);
  float dv = v - mu;
  s = dv * dv;
#pragma unroll
  for (int o = 32; o; o >>= 1) s += __shfl_xor(s, o, 64);
  __syncthreads();
  if (lane == 0) red[wid] = s;
  __syncthreads();
  float var = (red[0] + red[1] + red[2] + red[3]) * (1.f / 256.f);
  t2[idx] = fmaxf(dv * rsqrtf(var + 1e-5f) * lw[t] + lb[t], 0.f);
}

__global__ __launch_bounds__(256) void hfinal_k(const float* __restrict__ t2,
    const float* vW3, const float* vb3, const float* aW3, const float* ab3,
    float* __restrict__ q) {
  __shared__ float a3s[24];
  int t = threadIdx.x;
  int g = t >> 3, ln8 = t & 7;
  if (g < 24) {
    int b = g / 6, r = g - b * 6;
    int p = r ? 1 : 0;
    int o = r ? r - 1 : 0;
    const float* W3 = p ? aW3 : vW3;
    const float* b3 = p ? ab3 : vb3;
    int nout = p ? 5 : 1;
    const float* t2r = t2 + (b * 2 + p) * 256;
    float acc = 0.f;
    for (int k = ln8; k < 256; k += 8) acc += t2r[k] * W3[k * nout + o];
    acc += __shfl_xor(acc, 1, 64);
    acc += __shfl_xor(acc, 2, 64);
    acc += __shfl_xor(acc, 4, 64);
    if (ln8 == 0) a3s[g] = acc + b3[o];
  }
  __syncthreads();
  if (t < 20) {
    int b = t / 5, a = t - b * 5;
    float val = a3s[b * 6];
    float m = 0.f;
#pragma unroll
    for (int j = 0; j < 5; j++) m += a3s[b * 6 + 1 + j];
    m *= 0.2f;
    q[b * 5 + a] = val + a3s[b * 6 + 1 + a] - m;
  }
}

extern "C" void kernel_launch(void* const* d_in, const int* in_sizes, int n_in,
                              void* d_out, int out_size, void* d_ws, size_t ws_size,
                              hipStream_t stream) {
  const float* src = (const float*)d_in[0];
  const float* tau = (const float*)d_in[1];
  const float* dain_Wm = (const float*)d_in[2];
  const float* dain_Ws = (const float*)d_in[3];
  const float* dain_Wg = (const float*)d_in[4];
  const float* dain_bg = (const float*)d_in[5];
  const float* memb_W = (const float*)d_in[6];
  const float* memb_b = (const float*)d_in[7];
  const float* t_w0 = (const float*)d_in[8];
  const float* t_b0 = (const float*)d_in[9];
  const float* t_w = (const float*)d_in[10];
  const float* t_b = (const float*)d_in[11];
  const float* tproj_W = (const float*)d_in[12];
  const float* tproj_b = (const float*)d_in[13];
  const float* ffn_W1 = (const float*)d_in[14];
  const float* ffn_b1 = (const float*)d_in[15];
  const float* ffn_W2 = (const float*)d_in[16];
  const float* ffn_b2 = (const float*)d_in[17];
  const float* n1_w = (const float*)d_in[18];
  const float* n1_b = (const float*)d_in[19];
  const float* inproj_W = (const float*)d_in[20];
  const float* conv_w = (const float*)d_in[21];
  const float* conv_b = (const float*)d_in[22];
  const float* xproj_W = (const float*)d_in[23];
  const float* dtproj_W = (const float*)d_in[24];
  const float* dt_bias = (const float*)d_in[25];
  const float* A_log = (const float*)d_in[26];
  const float* D_p = (const float*)d_in[27];
  const float* outproj_W = (const float*)d_in[28];
  const float* n2_w = (const float*)d_in[29];
  const float* n2_b = (const float*)d_in[30];
  const float* mlp_W1 = (const float*)d_in[31];
  const float* mlp_W2 = (const float*)d_in[32];
  const float* nf_w = (const float*)d_in[33];
  const float* nf_b = (const float*)d_in[34];
  const float* vW1 = (const float*)d_in[35]; const float* vb1 = (const float*)d_in[36];
  const float* vl1w = (const float*)d_in[37]; const float* vl1b = (const float*)d_in[38];
  const float* vW2 = (const float*)d_in[39]; const float* vb2 = (const float*)d_in[40];
  const float* vl2w = (const float*)d_in[41]; const float* vl2b = (const float*)d_in[42];
  const float* vW3 = (const float*)d_in[43]; const float* vb3 = (const float*)d_in[44];
  const float* aW1 = (const float*)d_in[45]; const float* ab1 = (const float*)d_in[46];
  const float* al1w = (const float*)d_in[47]; const float* al1b = (const float*)d_in[48];
  const float* aW2 = (const float*)d_in[49]; const float* ab2 = (const float*)d_in[50];
  const float* al2w = (const float*)d_in[51]; const float* al2b = (const float*)d_in[52];
  const float* aW3 = (const float*)d_in[53]; const float* ab3 = (const float*)d_in[54];
  float* out = (float*)d_out;

  float* ws = (float*)d_ws;
  float* dstats = ws;                      // 256
  float* h    = dstats + 256;              // BL*256
  float* big  = h + (size_t)BL * DMOD;     // BL*1408
  float* ucv  = big + (size_t)BL * 1408;   // BL*512
  float* xd   = ucv + (size_t)BL * DIN;    // BL*48
  float* dt   = xd + (size_t)BL * 48;      // BL*512
  float* fh   = dt + (size_t)BL * DIN;     // 1024
  float* a1   = fh + 1024;                 // 4096
  float* t1   = a1 + 4096;                 // 4096
  float* a2   = t1 + 4096;                 // 2048
  float* t2   = a2 + 2048;                 // 2048
  float* fp_end = t2 + 2048;
  _Float16* h_hf    = (_Float16*)fp_end;            // BL*256
  _Float16* hn_hf   = h_hf + (size_t)BL * DMOD;     // BL*256
  _Float16* mid_hf  = hn_hf + (size_t)BL * DMOD;    // BL*704
  _Float16* gout_hf = mid_hf + (size_t)BL * 704;    // BL*512
  _Float16* ffn1T   = gout_hf + (size_t)BL * DIN;   // 1408*256
  _Float16* ffn2T   = ffn1T + (size_t)1408 * 256;   // 256*704
  _Float16* inprojT = ffn2T + (size_t)256 * 704;    // 8*1024*256
  _Float16* outprojT = inprojT + (size_t)8 * 1024 * 256;
  _Float16* mlp1T   = outprojT + (size_t)8 * 256 * 512;
  _Float16* mlp2T   = mlp1T + (size_t)8 * 512 * 256;

  convall_k<<<20544, 256, 0, stream>>>(ffn_W1, ffn_W2, inproj_W, outproj_W, mlp_W1, mlp_W2,
                                       ffn1T, ffn2T, inprojT, outprojT, mlp1T, mlp2T);
  dain_k<<<1, 1024, 0, stream>>>(src, dain_Wm, dain_Ws, dain_Wg, dain_bg, dstats);
  embed_k<<<BL, 256, 0, stream>>>(src, tau, dstats, memb_W, memb_b, t_w0, t_b0, t_w, t_b, tproj_W, tproj_b, h_hf);
  gemm_hf_k<<<dim3(22, 32), 256, 0, stream>>>(h_hf, ffn1T, ffn_b1, big, BL, 1364, 256, 1364, 0);
  glugelu_k<<<BL * 704 / 256, 256, 0, stream>>>(big, mid_hf);
  gemm_hf_k<<<dim3(4, 32), 256, 0, stream>>>(mid_hf, ffn2T, ffn_b2, h, BL, 256, 704, 256, 0);

  for (int i = 0; i < 8; i++) {
    ln4_k<<<BL / 4, 256, 0, stream>>>(h, n1_w + i * 256, n1_b + i * 256, hn_hf);
    gemm_hf_k<<<dim3(16, 32), 256, 0, stream>>>(hn_hf, inprojT + (size_t)i * 1024 * 256, nullptr, big,
                                                BL, 1024, 256, 1024, 0);
    convxdt_k<<<BL, 256, 0, stream>>>(big, conv_w + (size_t)i * 512 * 4, conv_b + i * 512,
                                      xproj_W + (size_t)i * 512 * 48, dtproj_W + (size_t)i * 16 * 512,
                                      dt_bias + i * 512, ucv, xd, dt);
    scan_k<<<256, 256, 0, stream>>>(dt, ucv, xd, big, A_log + (size_t)i * 512 * 16, D_p + i * 512, gout_hf);
    gemm_hf_k<<<dim3(4, 32), 256, 0, stream>>>(gout_hf, outprojT + (size_t)i * 256 * 512, nullptr, h,
                                               BL, 256, 512, 256, 1);
    ln4_k<<<BL / 4, 256, 0, stream>>>(h, n2_w + i * 256, n2_b + i * 256, hn_hf);
    gemm_hf_k<<<dim3(8, 32), 256, 0, stream>>>(hn_hf, mlp1T + (size_t)i * 512 * 256, nullptr, big,
                                               BL, 512, 256, 512, 0);
    silumul_k<<<BL, 256, 0, stream>>>(big, mid_hf);
    gemm_hf_k<<<dim3(4, 32), 256, 0, stream>>>(mid_hf, mlp2T + (size_t)i * 256 * 256, nullptr, h,
                                               BL, 256, 256, 256, 1);
  }

  lnf_k<<<NB, 256, 0, stream>>>(h, nf_w, nf_b, fh);
  hgemm1_k<<<dim3(8, 4, 2), 256, 0, stream>>>(fh, vW1, vb1, aW1, ab1, a1);
  hln1_k<<<dim3(4, 2), 512, 0, stream>>>(a1, vl1w, vl1b, al1w, al1b, t1);
  hgemm2_k<<<dim3(4, 4, 2), 256, 0, stream>>>(t1, vW2, vb2, aW2, ab2, a2);
  hln2_k<<<dim3(4, 2), 256, 0, stream>>>(a2, vl2w, vl2b, al2w, al2b, t2);
  hfinal_k<<<1, 256, 0, stream>>>(t2, vW3, vb3, aW3, ab3, out);
  (void)in_sizes; (void)n_in; (void)out_size; (void)ws_size;
}

// Round 15
// 878.459 us; speedup vs baseline: 1.6221x; 1.0163x over previous
//
#include <hip/hip_runtime.h>
#include <math.h>

// Model constants
#define BL   2048   // B*L = 4*512
#define LSEQ 512
#define NB   4
#define DMOD 256
#define DIN  512
#define NCH  (NB * DIN)

typedef __attribute__((ext_vector_type(4))) float f32x4;
typedef __attribute__((ext_vector_type(8))) _Float16 f16x8;
typedef __attribute__((ext_vector_type(4))) _Float16 f16x4;

__device__ __forceinline__ float sigmoidf_(float x) { return 1.f / (1.f + __expf(-x)); }
__device__ __forceinline__ float siluf_(float x) { return x / (1.f + __expf(-x)); }

// ---------------- DAIN stats (single block) ----------------
__global__ __launch_bounds__(1024) void dain_k(
    const float* __restrict__ src, const float* __restrict__ Wm,
    const float* __restrict__ Ws, const float* __restrict__ Wg,
    const float* __restrict__ bg, float* __restrict__ stats) {
  __shared__ float part[1024];
  __shared__ float avg_s[128], sub_s[128], std_s[128], mn_s[128], inv_s[128];
  int tid = threadIdx.x;
  int p = tid >> 3, j = tid & 7;
  int b = p >> 5, f = p & 31;
  float s = 0.f;
  for (int l = j * 64; l < j * 64 + 64; ++l) s += src[((size_t)b * LSEQ + l) * 32 + f];
  part[tid] = s;
  __syncthreads();
  if (tid < 128) { float a = 0; for (int k = 0; k < 8; k++) a += part[tid * 8 + k]; avg_s[tid] = a * (1.f / 512.f); }
  __syncthreads();
  if (tid < 128) {
    int bb = tid >> 5, ff = tid & 31;
    float a = 0; for (int g = 0; g < 32; g++) a += avg_s[bb * 32 + g] * Wm[ff * 32 + g];
    sub_s[tid] = a;
  }
  __syncthreads();
  float sub = sub_s[p];
  s = 0.f;
  for (int l = j * 64; l < j * 64 + 64; ++l) {
    float v = src[((size_t)b * LSEQ + l) * 32 + f] - sub; s += v * v;
  }
  part[tid] = s;
  __syncthreads();
  if (tid < 128) { float a = 0; for (int k = 0; k < 8; k++) a += part[tid * 8 + k]; std_s[tid] = sqrtf(a * (1.f / 512.f)); }
  __syncthreads();
  if (tid < 128) {
    int bb = tid >> 5, ff = tid & 31;
    float a = 0; for (int g = 0; g < 32; g++) a += std_s[bb * 32 + g] * Ws[ff * 32 + g];
    if (a <= 1e-8f) a = 1.f;
    inv_s[tid] = 1.f / a;
    mn_s[tid] = (avg_s[tid] - sub_s[tid]) / a;
  }
  __syncthreads();
  if (tid < 128) {
    int bb = tid >> 5, ff = tid & 31;
    float a = bg[ff]; for (int g = 0; g < 32; g++) a += mn_s[bb * 32 + g] * Wg[ff * 32 + g];
    float gate = sigmoidf_(a);
    float scl = gate * inv_s[tid];
    stats[tid] = scl;
    stats[128 + tid] = sub_s[tid] * scl;
  }
}

// ---------------- embed -> h_hf (f16) ----------------
__global__ __launch_bounds__(256) void embed_k(
    const float* __restrict__ src, const float* __restrict__ tau,
    const float* __restrict__ stats, const float* __restrict__ membW,
    const float* __restrict__ membB, const float* __restrict__ tw0,
    const float* __restrict__ tb0, const float* __restrict__ tw,
    const float* __restrict__ tb, const float* __restrict__ tprojW,
    const float* __restrict__ tprojB, _Float16* __restrict__ h_hf) {
  int token = blockIdx.x;
  int b = token >> 9;
  int t = threadIdx.x;
  __shared__ float xs[32], te[32];
  if (t < 32) {
    float scl = stats[b * 32 + t], shf = stats[128 + b * 32 + t];
    xs[t] = src[(size_t)token * 32 + t] * scl - shf;
  } else if (t < 64) {
    int j = t - 32;
    const float* tr = tau + (size_t)token * 8;
    float a;
    if (j < 31) { a = tb[j]; for (int k = 0; k < 8; k++) a += tr[k] * tw[k * 31 + j]; a = sinf(a); }
    else        { a = tb0[0]; for (int k = 0; k < 8; k++) a += tr[k] * tw0[k]; }
    te[j] = a;
  }
  __syncthreads();
  float acc;
  if (t < 128) {
    acc = membB[t];
    for (int f = 0; f < 32; f++) acc += xs[f] * membW[f * 128 + t];
  } else {
    int d = t - 128;
    acc = tprojB[d];
    for (int j = 0; j < 32; j++) acc += te[j] * tprojW[j * 128 + d];
  }
  h_hf[(size_t)token * DMOD + t] = (_Float16)acc;
}

// ---------------- all weight transpose-converts in ONE launch ----------------
__device__ __forceinline__ void convT_one(const float* __restrict__ W, _Float16* __restrict__ WT,
                                          int K, int N, int Kout, int Nout, int idx) {
  int per = Nout * Kout;
  int l = idx / per; int rem = idx - l * per;
  int n = rem / Kout; int k = rem - n * Kout;
  const float* Wl = W + (size_t)l * K * N;
  float v = (k < K && n < N) ? Wl[(size_t)k * N + n] : 0.f;
  WT[(size_t)l * per + rem] = (_Float16)v;
}

__global__ __launch_bounds__(256) void convall_k(
    const float* ffn_W1, const float* ffn_W2, const float* inproj_W,
    const float* outproj_W, const float* mlp_W1, const float* mlp_W2,
    _Float16* ffn1T, _Float16* ffn2T, _Float16* inprojT,
    _Float16* outprojT, _Float16* mlp1T, _Float16* mlp2T) {
  int g = blockIdx.x, t = threadIdx.x;
  if (g < 1408)            convT_one(ffn_W1, ffn1T, 256, 1364, 256, 1408, g * 256 + t);
  else if (g < 2112)       convT_one(ffn_W2, ffn2T, 682, 256, 704, 256, (g - 1408) * 256 + t);
  else if (g < 10304)      convT_one(inproj_W, inprojT, 256, 1024, 256, 1024, (g - 2112) * 256 + t);
  else if (g < 14400)      convT_one(outproj_W, outprojT, 512, 256, 512, 256, (g - 10304) * 256 + t);
  else if (g < 18496)      convT_one(mlp_W1, mlp1T, 256, 512, 256, 512, (g - 14400) * 256 + t);
  else                     convT_one(mlp_W2, mlp2T, 256, 256, 256, 256, (g - 18496) * 256 + t);
}

// ---------------- plain f16 MFMA GEMM 64x64 tile (A stride == K) ----------------
__global__ __launch_bounds__(256) void gemm_hf_k(
    const _Float16* __restrict__ A, const _Float16* __restrict__ WT,
    const float* __restrict__ bias, float* __restrict__ C,
    int M, int Nstore, int K, int ldc, int flags) {
  __shared__ _Float16 As[64][40];
  __shared__ _Float16 Bs[64][40];
  int bm = blockIdx.y * 64, bn = blockIdx.x * 64;
  int t = threadIdx.x;
  int w = t >> 6, l = t & 63;
  int wm = w >> 1, wn = w & 1;
  int srow = t >> 2, sk = (t & 3) * 8;
  f32x4 acc[2][2] = {};
  int lr = l & 15, lk = (l >> 4) * 8;
  for (int k0 = 0; k0 < K; k0 += 32) {
    *(uint4*)&As[srow][sk] = *(const uint4*)&A[(size_t)(bm + srow) * K + k0 + sk];
    *(uint4*)&Bs[srow][sk] = *(const uint4*)&WT[(size_t)(bn + srow) * K + k0 + sk];
    __syncthreads();
    f16x8 a0 = *(const f16x8*)&As[wm * 32 + lr][lk];
    f16x8 a1 = *(const f16x8*)&As[wm * 32 + 16 + lr][lk];
    f16x8 b0 = *(const f16x8*)&Bs[wn * 32 + lr][lk];
    f16x8 b1 = *(const f16x8*)&Bs[wn * 32 + 16 + lr][lk];
    acc[0][0] = __builtin_amdgcn_mfma_f32_16x16x32_f16(a0, b0, acc[0][0], 0, 0, 0);
    acc[0][1] = __builtin_amdgcn_mfma_f32_16x16x32_f16(a0, b1, acc[0][1], 0, 0, 0);
    acc[1][0] = __builtin_amdgcn_mfma_f32_16x16x32_f16(a1, b0, acc[1][0], 0, 0, 0);
    acc[1][1] = __builtin_amdgcn_mfma_f32_16x16x32_f16(a1, b1, acc[1][1], 0, 0, 0);
    __syncthreads();
  }
  int lq = l >> 4;
#pragma unroll
  for (int i = 0; i < 2; i++) {
#pragma unroll
    for (int j = 0; j < 2; j++) {
      int col = bn + wn * 32 + j * 16 + lr;
      if (col >= Nstore) continue;
      float bv = bias ? bias[col] : 0.f;
#pragma unroll
      for (int r = 0; r < 4; r++) {
        int row = bm + wm * 32 + i * 16 + lq * 4 + r;
        float v = acc[i][j][r] + bv;
        size_t idx = (size_t)row * ldc + col;
        if (flags & 1) v += C[idx];
        C[idx] = v;
      }
    }
  }
}

// ---------------- f16 MFMA GEMM 32x64 tile (2x the blocks for small-N gemms) ----------------
// grid (N/64, M/32). 4 waves: wave w -> rows (w>>1)*16, cols (w&1)*32. acc[2].
__global__ __launch_bounds__(256) void gemm_hf32_k(
    const _Float16* __restrict__ A, const _Float16* __restrict__ WT,
    const float* __restrict__ bias, float* __restrict__ C,
    int Nstore, int K, int ldc, int flags) {
  __shared__ _Float16 As[32][40];
  __shared__ _Float16 Bs[64][40];
  int bm = blockIdx.y * 32, bn = blockIdx.x * 64;
  int t = threadIdx.x;
  int w = t >> 6, l = t & 63;
  int wr = w >> 1, wc = w & 1;
  int srow = t >> 2, sk = (t & 3) * 8;
  f32x4 acc[2] = {};
  int lr = l & 15, lq = l >> 4, lk = lq * 8;
  for (int k0 = 0; k0 < K; k0 += 32) {
    if (t < 128)
      *(uint4*)&As[srow][sk] = *(const uint4*)&A[(size_t)(bm + srow) * K + k0 + sk];
    *(uint4*)&Bs[srow][sk] = *(const uint4*)&WT[(size_t)(bn + srow) * K + k0 + sk];
    __syncthreads();
    f16x8 a0 = *(const f16x8*)&As[wr * 16 + lr][lk];
    f16x8 b0 = *(const f16x8*)&Bs[wc * 32 + lr][lk];
    f16x8 b1 = *(const f16x8*)&Bs[wc * 32 + 16 + lr][lk];
    acc[0] = __builtin_amdgcn_mfma_f32_16x16x32_f16(a0, b0, acc[0], 0, 0, 0);
    acc[1] = __builtin_amdgcn_mfma_f32_16x16x32_f16(a0, b1, acc[1], 0, 0, 0);
    __syncthreads();
  }
#pragma unroll
  for (int j = 0; j < 2; j++) {
    int col = bn + wc * 32 + j * 16 + lr;
    if (col >= Nstore) continue;
    float bv = bias ? bias[col] : 0.f;
#pragma unroll
    for (int r = 0; r < 4; r++) {
      int row = bm + wr * 16 + lq * 4 + r;
      float v = acc[j][r] + bv;
      size_t idx = (size_t)row * ldc + col;
      if (flags & 1) v += C[idx];
      C[idx] = v;
    }
  }
}

// ---------------- FFN GLU (a * gelu_exact(g)) -> f16 padded to 704 ----------------
__global__ __launch_bounds__(256) void glugelu_k(const float* __restrict__ big, _Float16* __restrict__ out) {
  int i = blockIdx.x * 256 + threadIdx.x; // BL*704
  int token = i / 704, j = i - token * 704;
  float r = 0.f;
  if (j < 682) {
    float a = big[(size_t)token * 1364 + j];
    float g = big[(size_t)token * 1364 + 682 + j];
    r = a * 0.5f * g * (1.f + erff(g * 0.70710678118654752f));
  }
  out[i] = (_Float16)r;
}

// ---------------- LayerNorm, 4 rows/block (wave per row) -> f16 ----------------
__global__ __launch_bounds__(256) void ln4_k(const float* __restrict__ x, const float* __restrict__ w,
                                             const float* __restrict__ b, _Float16* __restrict__ out) {
  int row = blockIdx.x * 4 + (threadIdx.x >> 6), lane = threadIdx.x & 63;
  const float* rp = x + (size_t)row * 256;
  float4 v = *(const float4*)&rp[lane * 4];
  float s = v.x + v.y + v.z + v.w;
  float ss = v.x * v.x + v.y * v.y + v.z * v.z + v.w * v.w;
#pragma unroll
  for (int o = 32; o; o >>= 1) { s += __shfl_xor(s, o, 64); ss += __shfl_xor(ss, o, 64); }
  float mu = s * (1.f / 256.f);
  float var = ss * (1.f / 256.f) - mu * mu;
  float rs = rsqrtf(var + 1e-5f);
  float4 wv = *(const float4*)&w[lane * 4];
  float4 bv = *(const float4*)&b[lane * 4];
  f16x4 o4;
  o4[0] = (_Float16)((v.x - mu) * rs * wv.x + bv.x);
  o4[1] = (_Float16)((v.y - mu) * rs * wv.y + bv.y);
  o4[2] = (_Float16)((v.z - mu) * rs * wv.z + bv.z);
  o4[3] = (_Float16)((v.w - mu) * rs * wv.w + bv.w);
  *(f16x4*)&out[(size_t)row * 256 + lane * 4] = o4;
}

// ---------------- fused conv4+silu -> xproj -> dtproj+softplus (256 threads) ----------------
__global__ __launch_bounds__(256) void convxdt_k(
    const float* __restrict__ big, const float* __restrict__ cw, const float* __restrict__ cb,
    const float* __restrict__ xW, const float* __restrict__ dW, const float* __restrict__ dbias,
    float* __restrict__ ucv, float* __restrict__ xd, float* __restrict__ dt) {
  __shared__ float us[512];
  __shared__ float xs[48];
  int token = ((blockIdx.x & 7) << 8) | (blockIdx.x >> 3);
  int b = token >> 9, l = token & 511;
  int t = threadIdx.x;
#pragma unroll
  for (int e = 0; e < 2; e++) {
    int c = t + e * 256;
    float acc = cb[c];
#pragma unroll
    for (int k = 0; k < 4; k++) {
      int l2 = l - 3 + k;
      if (l2 >= 0) acc += big[((size_t)(b * LSEQ + l2)) * 1024 + c] * cw[c * 4 + k];
    }
    float u = siluf_(acc);
    us[c] = u;
    ucv[(size_t)token * 512 + c] = u;
  }
  __syncthreads();
  if (t < 192) {
    int j = t >> 2, p = t & 3;
    float part = 0.f;
#pragma unroll 8
    for (int c = p * 128; c < p * 128 + 128; c++) part += us[c] * xW[c * 48 + j];
    part += __shfl_xor(part, 1, 64);
    part += __shfl_xor(part, 2, 64);
    if (p == 0) {
      xs[j] = part;
      xd[(size_t)token * 48 + j] = part;
    }
  }
  __syncthreads();
#pragma unroll
  for (int e = 0; e < 2; e++) {
    int c = t + e * 256;
    float acc = dbias[c];
#pragma unroll
    for (int r = 0; r < 16; r++) acc += xs[r] * dW[r * 512 + c];
    dt[(size_t)token * 512 + c] = (acc > 20.f) ? acc : log1pf(__expf(acc));
  }
}

// ---------------- scan v3: thread = (chunk, channel), states in regs, 256 blocks ----------------
__global__ __launch_bounds__(256) void scan_k(
    const float* __restrict__ dt, const float* __restrict__ ucv, const float* __restrict__ xd,
    const float* __restrict__ zbuf, const float* __restrict__ A_log, const float* __restrict__ D_p,
    _Float16* __restrict__ gout) {
  __shared__ float PsL[32][8][17];   // [c][dl][n] (+pad)
  __shared__ float HsL[32][8][17];
  __shared__ float BnS[32][16];
  __shared__ float CnS[32][16];
  int bid = blockIdx.x;
  int b = bid >> 6, dg = bid & 63;
  int t = threadIdx.x;
  int c = t >> 3, dl = t & 7;
  int d = dg * 8 + dl;
  float An[16];
#pragma unroll
  for (int n = 0; n < 16; n++) An[n] = -__expf(A_log[(size_t)d * 16 + n]);
  float P[16], H[16];
#pragma unroll
  for (int n = 0; n < 16; n++) { P[n] = 1.f; H[n] = 0.f; }
  int t0 = b * LSEQ + c * 16;
  for (int tt = 0; tt < 16; tt++) {
    int token = t0 + tt;
    float dtv = dt[(size_t)token * 512 + d];
    float uv = ucv[(size_t)token * 512 + d];
    BnS[c][dl] = xd[(size_t)token * 48 + 16 + dl];
    BnS[c][8 + dl] = xd[(size_t)token * 48 + 24 + dl];
    float x = dtv * uv;
#pragma unroll
    for (int n = 0; n < 16; n++) {
      float dA = __expf(dtv * An[n]);
      P[n] *= dA;
      H[n] = dA * H[n] + x * BnS[c][n];
    }
  }
#pragma unroll
  for (int n = 0; n < 16; n++) { PsL[c][dl][n] = P[n]; HsL[c][dl][n] = H[n]; }
  __syncthreads();
  if (t < 128) {
    int n2 = t >> 3, dl2 = t & 7;
    float hc = 0.f;
#pragma unroll
    for (int c2 = 0; c2 < 32; c2++) {
      float Pv = PsL[c2][dl2][n2];
      float Hv = HsL[c2][dl2][n2];
      PsL[c2][dl2][n2] = hc;
      hc = Pv * hc + Hv;
    }
  }
  __syncthreads();
  float h[16];
#pragma unroll
  for (int n = 0; n < 16; n++) h[n] = PsL[c][dl][n];
  float Dd = D_p[d];
  for (int tt = 0; tt < 16; tt++) {
    int token = t0 + tt;
    float dtv = dt[(size_t)token * 512 + d];
    float uv = ucv[(size_t)token * 512 + d];
    float zv = zbuf[(size_t)token * 1024 + 512 + d];
    BnS[c][dl] = xd[(size_t)token * 48 + 16 + dl];
    BnS[c][8 + dl] = xd[(size_t)token * 48 + 24 + dl];
    CnS[c][dl] = xd[(size_t)token * 48 + 32 + dl];
    CnS[c][8 + dl] = xd[(size_t)token * 48 + 40 + dl];
    float x = dtv * uv;
    float y = 0.f;
#pragma unroll
    for (int n = 0; n < 16; n++) {
      float dA = __expf(dtv * An[n]);
      h[n] = dA * h[n] + x * BnS[c][n];
      y += h[n] * CnS[c][n];
    }
    gout[(size_t)token * 512 + d] = (_Float16)((y + uv * Dd) * siluf_(zv));
  }
}

// ---------------- SwiGLU for mlp: silu(g1)*g2 -> f16 ----------------
__global__ __launch_bounds__(256) void silumul_k(const float* __restrict__ big, _Float16* __restrict__ out) {
  int i = blockIdx.x * 256 + threadIdx.x; // BL*256
  int token = i >> 8, j = i & 255;
  float g1 = big[(size_t)token * 512 + j];
  float g2 = big[(size_t)token * 512 + 256 + j];
  out[i] = (_Float16)(siluf_(g1) * g2);
}

// ---------------- head: wide kernels with K-split GEMMs ----------------
__global__ __launch_bounds__(256) void lnf_k(const float* __restrict__ h, const float* __restrict__ nfw,
                                             const float* __restrict__ nfb, float* __restrict__ f) {
  __shared__ float red[4];
  int b = blockIdx.x, t = threadIdx.x;
  int lane = t & 63, wid = t >> 6;
  float v = h[((size_t)b * LSEQ + (LSEQ - 1)) * DMOD + t];
  float s = v;
#pragma unroll
  for (int o = 32; o; o >>= 1) s += __shfl_xor(s, o, 64);
  if (lane == 0) red[wid] = s;
  __syncthreads();
  float mu = (red[0] + red[1] + red[2] + red[3]) * (1.f / 256.f);
  float dv = v - mu;
  s = dv * dv;
#pragma unroll
  for (int o = 32; o; o >>= 1) s += __shfl_xor(s, o, 64);
  __syncthreads();
  if (lane == 0) red[wid] = s;
  __syncthreads();
  float var = (red[0] + red[1] + red[2] + red[3]) * (1.f / 256.f);
  f[b * 256 + t] = dv * rsqrtf(var + 1e-5f) * nfw[t] + nfb[t];
}

__global__ __launch_bounds__(256) void hgemm1_k(const float* __restrict__ f,
    const float* vW1, const float* vb1, const float* aW1, const float* ab1,
    float* __restrict__ a1) {
  int cb = blockIdx.x, b = blockIdx.y, p = blockIdx.z;
  const float* W1 = p ? aW1 : vW1;
  const float* b1 = p ? ab1 : vb1;
  __shared__ float fs[256];
  __shared__ float part[4][64];
  int t = threadIdx.x;
  fs[t] = f[b * 256 + t];
  __syncthreads();
  int col = cb * 64 + (t & 63);
  int kp = t >> 6;
  float acc = 0.f;
#pragma unroll 8
  for (int k = 0; k < 64; k++) acc += fs[kp * 64 + k] * W1[(size_t)(kp * 64 + k) * 512 + col];
  part[kp][t & 63] = acc;
  __syncthreads();
  if (t < 64) {
    float v = part[0][t] + part[1][t] + part[2][t] + part[3][t] + b1[cb * 64 + t];
    a1[((b * 2 + p) * 512) + cb * 64 + t] = v;
  }
}

__global__ __launch_bounds__(512) void hln1_k(const float* __restrict__ a1,
    const float* vl1w, const float* vl1b, const float* al1w, const float* al1b,
    float* __restrict__ t1) {
  __shared__ float red[8];
  int b = blockIdx.x, p = blockIdx.y, t = threadIdx.x;
  const float* lw = p ? al1w : vl1w;
  const float* lb = p ? al1b : vl1b;
  int lane = t & 63, wid = t >> 6;
  int idx = (b * 2 + p) * 512 + t;
  float v = a1[idx];
  float s = v;
#pragma unroll
  for (int o = 32; o; o >>= 1) s += __shfl_xor(s, o, 64);
  if (lane == 0) red[wid] = s;
  __syncthreads();
  float S = 0.f;
#pragma unroll
  for (int k = 0; k < 8; k++) S += red[k];
  float mu = S * (1.f / 512.f);
  float dv = v - mu;
  s = dv * dv;
#pragma unroll
  for (int o = 32; o; o >>= 1) s += __shfl_xor(s, o, 64);
  __syncthreads();
  if (lane == 0) red[wid] = s;
  __syncthreads();
  S = 0.f;
#pragma unroll
  for (int k = 0; k < 8; k++) S += red[k];
  float var = S * (1.f / 512.f);
  t1[idx] = fmaxf(dv * rsqrtf(var + 1e-5f) * lw[t] + lb[t], 0.f);
}

__global__ __launch_bounds__(256) void hgemm2_k(const float* __restrict__ t1,
    const float* vW2, const float* vb2, const float* aW2, const float* ab2,
    float* __restrict__ a2) {
  int cb = blockIdx.x, b = blockIdx.y, p = blockIdx.z;
  const float* W2 = p ? aW2 : vW2;
  const float* b2 = p ? ab2 : vb2;
  __shared__ float ts[512];
  __shared__ float part[4][64];
  int t = threadIdx.x;
  ts[t] = t1[(b * 2 + p) * 512 + t];
  ts[256 + t] = t1[(b * 2 + p) * 512 + 256 + t];
  __syncthreads();
  int col = cb * 64 + (t & 63);
  int kp = t >> 6;
  float acc = 0.f;
#pragma unroll 8
  for (int k = 0; k < 128; k++) acc += ts[kp * 128 + k] * W2[(size_t)(kp * 128 + k) * 256 + col];
  part[kp][t & 63] = acc;
  __syncthreads();
  if (t < 64) {
    float v = part[0][t] + part[1][t] + part[2][t] + part[3][t] + b2[cb * 64 + t];
    a2[(b * 2 + p) * 256 + cb * 64 + t] = v;
  }
}

__global__ __launch_bounds__(256) void hln2_k(const float* __restrict__ a2,
    const float* vl2w, const float* vl2b, const float* al2w, const float* al2b,
    float* __restrict__ t2) {
  __shared__ float red[4];
  int b = blockIdx.x, p = blockIdx.y, t = threadIdx.x;
  const float* lw = p ? al2w : vl2w;
  const float* lb = p ? al2b : vl2b;
  int lane = t & 63, wid = t >> 6;
  int idx = (b * 2 + p) * 256 + t;
  float v = a2[idx];
  float s = v;
#pragma unroll
  for (int o = 32; o; o >>= 1) s += __shfl_xor(s, o, 64);
  if (lane == 0) red[wid] = s;
  __syncthreads();
  float mu = (red[0] + red[1] + red[2] + red[3]) * (1.f / 256.f);
  float dv = v - mu;
  s = dv * dv;
#pragma unroll
  for (int o = 32; o; o >>= 1) s += __shfl_xor(s, o, 64);
  __syncthreads();
  if (lane == 0) red[wid] = s;
  __syncthreads();
  float var = (red[0] + red[1] + red[2] + red[3]) * (1.f / 256.f);
  t2[idx] = fmaxf(dv * rsqrtf(var + 1e-5f) * lw[t] + lb[t], 0.f);
}

__global__ __launch_bounds__(256) void hfinal_k(const float* __restrict__ t2,
    const float* vW3, const float* vb3, const float* aW3, const float* ab3,
    float* __restrict__ q) {
  __shared__ float a3s[24];
  int t = threadIdx.x;
  int g = t >> 3, ln8 = t & 7;
  if (g < 24) {
    int b = g / 6, r = g - b * 6;
    int p = r ? 1 : 0;
    int o = r ? r - 1 : 0;
    const float* W3 = p ? aW3 : vW3;
    const float* b3 = p ? ab3 : vb3;
    int nout = p ? 5 : 1;
    const float* t2r = t2 + (b * 2 + p) * 256;
    float acc = 0.f;
    for (int k = ln8; k < 256; k += 8) acc += t2r[k] * W3[k * nout + o];
    acc += __shfl_xor(acc, 1, 64);
    acc += __shfl_xor(acc, 2, 64);
    acc += __shfl_xor(acc, 4, 64);
    if (ln8 == 0) a3s[g] = acc + b3[o];
  }
  __syncthreads();
  if (t < 20) {
    int b = t / 5, a = t - b * 5;
    float val = a3s[b * 6];
    float m = 0.f;
#pragma unroll
    for (int j = 0; j < 5; j++) m += a3s[b * 6 + 1 + j];
    m *= 0.2f;
    q[b * 5 + a] = val + a3s[b * 6 + 1 + a] - m;
  }
}

extern "C" void kernel_launch(void* const* d_in, const int* in_sizes, int n_in,
                              void* d_out, int out_size, void* d_ws, size_t ws_size,
                              hipStream_t stream) {
  const float* src = (const float*)d_in[0];
  const float* tau = (const float*)d_in[1];
  const float* dain_Wm = (const float*)d_in[2];
  const float* dain_Ws = (const float*)d_in[3];
  const float* dain_Wg = (const float*)d_in[4];
  const float* dain_bg = (const float*)d_in[5];
  const float* memb_W = (const float*)d_in[6];
  const float* memb_b = (const float*)d_in[7];
  const float* t_w0 = (const float*)d_in[8];
  const float* t_b0 = (const float*)d_in[9];
  const float* t_w = (const float*)d_in[10];
  const float* t_b = (const float*)d_in[11];
  const float* tproj_W = (const float*)d_in[12];
  const float* tproj_b = (const float*)d_in[13];
  const float* ffn_W1 = (const float*)d_in[14];
  const float* ffn_b1 = (const float*)d_in[15];
  const float* ffn_W2 = (const float*)d_in[16];
  const float* ffn_b2 = (const float*)d_in[17];
  const float* n1_w = (const float*)d_in[18];
  const float* n1_b = (const float*)d_in[19];
  const float* inproj_W = (const float*)d_in[20];
  const float* conv_w = (const float*)d_in[21];
  const float* conv_b = (const float*)d_in[22];
  const float* xproj_W = (const float*)d_in[23];
  const float* dtproj_W = (const float*)d_in[24];
  const float* dt_bias = (const float*)d_in[25];
  const float* A_log = (const float*)d_in[26];
  const float* D_p = (const float*)d_in[27];
  const float* outproj_W = (const float*)d_in[28];
  const float* n2_w = (const float*)d_in[29];
  const float* n2_b = (const float*)d_in[30];
  const float* mlp_W1 = (const float*)d_in[31];
  const float* mlp_W2 = (const float*)d_in[32];
  const float* nf_w = (const float*)d_in[33];
  const float* nf_b = (const float*)d_in[34];
  const float* vW1 = (const float*)d_in[35]; const float* vb1 = (const float*)d_in[36];
  const float* vl1w = (const float*)d_in[37]; const float* vl1b = (const float*)d_in[38];
  const float* vW2 = (const float*)d_in[39]; const float* vb2 = (const float*)d_in[40];
  const float* vl2w = (const float*)d_in[41]; const float* vl2b = (const float*)d_in[42];
  const float* vW3 = (const float*)d_in[43]; const float* vb3 = (const float*)d_in[44];
  const float* aW1 = (const float*)d_in[45]; const float* ab1 = (const float*)d_in[46];
  const float* al1w = (const float*)d_in[47]; const float* al1b = (const float*)d_in[48];
  const float* aW2 = (const float*)d_in[49]; const float* ab2 = (const float*)d_in[50];
  const float* al2w = (const float*)d_in[51]; const float* al2b = (const float*)d_in[52];
  const float* aW3 = (const float*)d_in[53]; const float* ab3 = (const float*)d_in[54];
  float* out = (float*)d_out;

  float* ws = (float*)d_ws;
  float* dstats = ws;                      // 256
  float* h    = dstats + 256;              // BL*256
  float* big  = h + (size_t)BL * DMOD;     // BL*1408
  float* ucv  = big + (size_t)BL * 1408;   // BL*512
  float* xd   = ucv + (size_t)BL * DIN;    // BL*48
  float* dt   = xd + (size_t)BL * 48;      // BL*512
  float* fh   = dt + (size_t)BL * DIN;     // 1024
  float* a1   = fh + 1024;                 // 4096
  float* t1   = a1 + 4096;                 // 4096
  float* a2   = t1 + 4096;                 // 2048
  float* t2   = a2 + 2048;                 // 2048
  float* fp_end = t2 + 2048;
  _Float16* h_hf    = (_Float16*)fp_end;            // BL*256
  _Float16* hn_hf   = h_hf + (size_t)BL * DMOD;     // BL*256
  _Float16* mid_hf  = hn_hf + (size_t)BL * DMOD;    // BL*704
  _Float16* gout_hf = mid_hf + (size_t)BL * 704;    // BL*512
  _Float16* ffn1T   = gout_hf + (size_t)BL * DIN;   // 1408*256
  _Float16* ffn2T   = ffn1T + (size_t)1408 * 256;   // 256*704
  _Float16* inprojT = ffn2T + (size_t)256 * 704;    // 8*1024*256
  _Float16* outprojT = inprojT + (size_t)8 * 1024 * 256;
  _Float16* mlp1T   = outprojT + (size_t)8 * 256 * 512;
  _Float16* mlp2T   = mlp1T + (size_t)8 * 512 * 256;

  convall_k<<<20544, 256, 0, stream>>>(ffn_W1, ffn_W2, inproj_W, outproj_W, mlp_W1, mlp_W2,
                                       ffn1T, ffn2T, inprojT, outprojT, mlp1T, mlp2T);
  dain_k<<<1, 1024, 0, stream>>>(src, dain_Wm, dain_Ws, dain_Wg, dain_bg, dstats);
  embed_k<<<BL, 256, 0, stream>>>(src, tau, dstats, memb_W, memb_b, t_w0, t_b0, t_w, t_b, tproj_W, tproj_b, h_hf);
  gemm_hf_k<<<dim3(22, 32), 256, 0, stream>>>(h_hf, ffn1T, ffn_b1, big, BL, 1364, 256, 1364, 0);
  glugelu_k<<<BL * 704 / 256, 256, 0, stream>>>(big, mid_hf);
  gemm_hf32_k<<<dim3(4, 64), 256, 0, stream>>>(mid_hf, ffn2T, ffn_b2, h, 256, 704, 256, 0);

  for (int i = 0; i < 8; i++) {
    ln4_k<<<BL / 4, 256, 0, stream>>>(h, n1_w + i * 256, n1_b + i * 256, hn_hf);
    gemm_hf_k<<<dim3(16, 32), 256, 0, stream>>>(hn_hf, inprojT + (size_t)i * 1024 * 256, nullptr, big,
                                                BL, 1024, 256, 1024, 0);
    convxdt_k<<<BL, 256, 0, stream>>>(big, conv_w + (size_t)i * 512 * 4, conv_b + i * 512,
                                      xproj_W + (size_t)i * 512 * 48, dtproj_W + (size_t)i * 16 * 512,
                                      dt_bias + i * 512, ucv, xd, dt);
    scan_k<<<256, 256, 0, stream>>>(dt, ucv, xd, big, A_log + (size_t)i * 512 * 16, D_p + i * 512, gout_hf);
    gemm_hf32_k<<<dim3(4, 64), 256, 0, stream>>>(gout_hf, outprojT + (size_t)i * 256 * 512, nullptr, h,
                                                 256, 512, 256, 1);
    ln4_k<<<BL / 4, 256, 0, stream>>>(h, n2_w + i * 256, n2_b + i * 256, hn_hf);
    gemm_hf32_k<<<dim3(8, 64), 256, 0, stream>>>(hn_hf, mlp1T + (size_t)i * 512 * 256, nullptr, big,
                                                 512, 256, 512, 0);
    silumul_k<<<BL, 256, 0, stream>>>(big, mid_hf);
    gemm_hf32_k<<<dim3(4, 64), 256, 0, stream>>>(mid_hf, mlp2T + (size_t)i * 256 * 256, nullptr, h,
                                                 256, 256, 256, 1);
  }

  lnf_k<<<NB, 256, 0, stream>>>(h, nf_w, nf_b, fh);
  hgemm1_k<<<dim3(8, 4, 2), 256, 0, stream>>>(fh, vW1, vb1, aW1, ab1, a1);
  hln1_k<<<dim3(4, 2), 512, 0, stream>>>(a1, vl1w, vl1b, al1w, al1b, t1);
  hgemm2_k<<<dim3(4, 4, 2), 256, 0, stream>>>(t1, vW2, vb2, aW2, ab2, a2);
  hln2_k<<<dim3(4, 2), 256, 0, stream>>>(a2, vl2w, vl2b, al2w, al2b, t2);
  hfinal_k<<<1, 256, 0, stream>>>(t2, vW3, vb3, aW3, ab3, out);
  (void)in_sizes; (void)n_in; (void)out_size; (void)ws_size;
}